// Round 9
// baseline (1741.068 us; speedup 1.0000x reference)
//
#include <hip/hip_runtime.h>

// dims: L=64, CH=16, PIX=256, PAT=64, RC=32, BD=64, OUT=10, B=256
// inputs: 0=x(256,64,256,16) 1=chi_first(32,16) 2=chi_mid(62,32,32,16)
// 3=chi_last(32,16,10) 4=psi_first(64,256) 5=psi_mid(62,64,64,256)
// 6=psi_last(64,256) 7=phi_first(64,64) 8=phi_mid(62,64,64,64) 9=phi_last(64,64)

static inline int imin(int a, int b) { return a < b ? a : b; }

typedef __attribute__((ext_vector_type(8))) short bf16x8;          // 8 bf16 (4 VGPR)
typedef __attribute__((ext_vector_type(8))) unsigned short us8;
typedef __attribute__((ext_vector_type(4))) float f32x4;

__device__ __forceinline__ unsigned short f2bf(float v) {
  union { float f; unsigned int u; } c; c.f = v;
  unsigned int u = c.u;
  unsigned int r = (u + 0x7fffu + ((u >> 16) & 1u)) >> 16;  // RTN-even
  return (unsigned short)r;
}
__device__ __forceinline__ float bf2f(unsigned short h) {
  union { unsigned int u; float f; } c; c.u = ((unsigned int)h) << 16;
  return c.f;
}

// ---------------------------------------------------------------------------
// K1: vpx means + bf16 hi/lo fragment emit. Fused: blocks >= 16384 do the
// phi slice gather (slices[i][l*64+r] = phi_mid[i][l][r][i+1]).
__global__ __launch_bounds__(256) void k_reduce_x(const float* __restrict__ x,
                                                  float* __restrict__ vch,
                                                  float* __restrict__ vpx,
                                                  unsigned short* __restrict__ vpxf_hi,
                                                  unsigned short* __restrict__ vpxf_lo,
                                                  const float* __restrict__ phi_mid,
                                                  float* __restrict__ slices) {
  if (blockIdx.x >= 16384) {                 // phi gather block
    int i = blockIdx.x - 16384;              // 0..61
    int t = threadIdx.x;
    #pragma unroll
    for (int k = 0; k < 16; ++k) {
      int idx = t + k * 256;                 // l*64 + r
      slices[(size_t)i * 4096 + idx] = phi_mid[((size_t)i * 4096 + idx) * 64 + (i + 1)];
    }
    return;
  }
  int bp = blockIdx.x;             // b*64 + s
  int b = bp >> 6, s = bp & 63;
  int q = threadIdx.x;             // = p
  const float* row = x + ((size_t)bp << 12) + q * 16;
  float4 r0 = *(const float4*)(row);
  float4 r1 = *(const float4*)(row + 4);
  float4 r2 = *(const float4*)(row + 8);
  float4 r3 = *(const float4*)(row + 12);
  float csum = r0.x + r0.y + r0.z + r0.w + r1.x + r1.y + r1.z + r1.w
             + r2.x + r2.y + r2.z + r2.w + r3.x + r3.y + r3.z + r3.w;
  float val = csum * (1.0f / 16.0f);
  if (vpx && (s == 0 || s == 63)) vpx[((size_t)s * 256 + b) * 256 + q] = val;
  if (vpxf_hi && s >= 1 && s <= 62) {
    unsigned short hb = f2bf(val);
    unsigned short lb = f2bf(val - bf2f(hb));
    size_t fa = (size_t)s * 65536
              + (((size_t)(q >> 5) * 16 + (b >> 4)) * 64 + (((q >> 3) & 3) * 16 + (b & 15))) * 8
              + (q & 7);
    vpxf_hi[fa] = hb;
    vpxf_lo[fa] = lb;
  }

  __shared__ float sc[256][20];
  *(float4*)&sc[q][0]  = r0;
  *(float4*)&sc[q][4]  = r1;
  *(float4*)&sc[q][8]  = r2;
  *(float4*)&sc[q][12] = r3;
  __syncthreads();
  int c = q & 15, g = q >> 4;
  float ps = 0.f;
  #pragma unroll
  for (int k = 0; k < 16; ++k) ps += sc[g * 16 + k][c];
  __shared__ float p2[16][17];
  p2[g][c] = ps;
  __syncthreads();
  if (q < 16) {
    float s2 = 0.f;
    #pragma unroll
    for (int k = 0; k < 16; ++k) s2 += p2[k][q];
    vch[((size_t)s * 256 + b) * 16 + q] = s2 * (1.0f / 256.0f);
  }
}

// ---------------------------------------------------------------------------
// MEGA GEMM (512 threads): bx<3968 psi MFMA gemm; 3968<=bx<4464 chi gemm;
// bx==4464 phi chain.
__global__ __launch_bounds__(512) void k_mega_gemm(const float* __restrict__ psi_mid,
                                                   const unsigned short* __restrict__ vpxf_hi,
                                                   const unsigned short* __restrict__ vpxf_lo,
                                                   float* __restrict__ M,
                                                   const float* __restrict__ chi_mid,
                                                   const float* __restrict__ vch,
                                                   float* __restrict__ Tc,
                                                   const float* __restrict__ slices,
                                                   const float* __restrict__ phi_first,
                                                   const float* __restrict__ phi_last,
                                                   float* __restrict__ phiv) {
  int bx = blockIdx.x;
  int t = threadIdx.x;
  if (bx < 3968) {
    // ---------------- psi MFMA gemm: site z, lr-block ----------------
    int z = bx >> 6;
    int lr0 = (bx & 63) * 64;
    const float* W = psi_mid + (size_t)z * 4096 * 256;
    const unsigned short* Ahg = vpxf_hi + (size_t)(z + 1) * 65536;
    const unsigned short* Alg = vpxf_lo + (size_t)(z + 1) * 65536;
    __shared__ unsigned short Bh[2][2][4][64][8];   // 16 KB
    __shared__ unsigned short Bl[2][2][4][64][8];   // 16 KB
    int lane = t & 63, w = t >> 6;
    int row = t >> 3, kg = t & 7;
    float4 sv0, sv1;

    #define LOADP(p) do {                                                      \
      const float* src = W + (size_t)(lr0 + row) * 256 + ((p) << 6) + kg * 8;  \
      sv0 = *(const float4*)src;                                               \
      sv1 = *(const float4*)(src + 4);                                         \
    } while (0)
    #define WRITEP(d) do {                                                     \
      float xs[8] = {sv0.x, sv0.y, sv0.z, sv0.w, sv1.x, sv1.y, sv1.z, sv1.w};  \
      us8 hv, lv;                                                              \
      _Pragma("unroll")                                                        \
      for (int i = 0; i < 8; ++i) {                                            \
        unsigned short hb = f2bf(xs[i]);                                       \
        hv[i] = hb;                                                            \
        lv[i] = f2bf(xs[i] - bf2f(hb));                                        \
      }                                                                        \
      int ck = kg >> 2, nt = row >> 4, ln = ((kg & 3) << 4) | (row & 15);      \
      *(us8*)&Bh[d][ck][nt][ln][0] = hv;                                       \
      *(us8*)&Bl[d][ck][nt][ln][0] = lv;                                       \
    } while (0)
    #define LOADA(slot, chunk) do {                                            \
      _Pragma("unroll")                                                        \
      for (int mi = 0; mi < 2; ++mi) {                                         \
        size_t fo = ((size_t)(chunk) * 16 + (w * 2 + mi)) * 512 + (size_t)lane * 8; \
        Ah[slot][mi] = *(const bf16x8*)(Ahg + fo);                             \
        Al[slot][mi] = *(const bf16x8*)(Alg + fo);                             \
      }                                                                        \
    } while (0)

    f32x4 acc[2][4];
    #pragma unroll
    for (int i = 0; i < 2; ++i)
      #pragma unroll
      for (int j = 0; j < 4; ++j) acc[i][j] = (f32x4){0.f, 0.f, 0.f, 0.f};
    bf16x8 Ah[2][2], Al[2][2];

    LOADA(0, 0);
    LOADP(0);
    WRITEP(0);
    __syncthreads();
    #pragma unroll
    for (int p = 0; p < 4; ++p) {
      if (p < 3) LOADP(p + 1);
      #pragma unroll
      for (int c = 0; c < 2; ++c) {
        const int chunk = p * 2 + c;
        const int cur = chunk & 1, nxt = (chunk + 1) & 1;
        if (chunk < 7) LOADA(nxt, chunk + 1);
        #pragma unroll
        for (int n = 0; n < 4; ++n) {
          bf16x8 bh = *(const bf16x8*)&Bh[p & 1][c][n][lane][0];
          bf16x8 bl = *(const bf16x8*)&Bl[p & 1][c][n][lane][0];
          #pragma unroll
          for (int mi = 0; mi < 2; ++mi) {
            acc[mi][n] = __builtin_amdgcn_mfma_f32_16x16x32_bf16(Ah[cur][mi], bh, acc[mi][n], 0, 0, 0);
            acc[mi][n] = __builtin_amdgcn_mfma_f32_16x16x32_bf16(Al[cur][mi], bh, acc[mi][n], 0, 0, 0);
            acc[mi][n] = __builtin_amdgcn_mfma_f32_16x16x32_bf16(Ah[cur][mi], bl, acc[mi][n], 0, 0, 0);
          }
        }
      }
      if (p < 3) WRITEP((p + 1) & 1);
      __syncthreads();
    }
    #undef LOADP
    #undef WRITEP
    #undef LOADA

    int rg = lane >> 4, cidx = lane & 15;
    #pragma unroll
    for (int mi = 0; mi < 2; ++mi) {
      int bbase = (w * 2 + mi) * 16 + rg * 4;
      #pragma unroll
      for (int n = 0; n < 4; ++n) {
        #pragma unroll
        for (int r = 0; r < 4; ++r) {
          M[((size_t)z * 256 + bbase + r) * 4096 + lr0 + n * 16 + cidx] = acc[mi][n][r];
        }
      }
    }
  } else if (bx < 4464) {
    // ---------------- chi gemm: Tc[z][b][r*32+l] ----------------
    int i = bx - 3968;
    int z = i >> 3;                 // site 0..61
    int b0 = (i & 7) * 32;
    __shared__ float uv[32][16];
    if (t < 128) {
      int idx = t * 4;
      int b = idx >> 4, c = idx & 15;
      *(float4*)&uv[b][c] = *(const float4*)(vch + ((size_t)(z + 1) * 256 + b0 + b) * 16 + c);
    }
    __syncthreads();
    #pragma unroll
    for (int k = 0; k < 2; ++k) {
      int idx = t + k * 512;         // output index = r*32 + l
      int r = idx >> 5, l = idx & 31;
      const float* Wp = chi_mid + ((size_t)z * 1024 + l * 32 + r) * 16;
      float4 w0 = *(const float4*)(Wp);
      float4 w1 = *(const float4*)(Wp + 4);
      float4 w2 = *(const float4*)(Wp + 8);
      float4 w3 = *(const float4*)(Wp + 12);
      for (int b = 0; b < 32; ++b) {
        const float* u = uv[b];
        float d = w0.x * u[0] + w0.y * u[1] + w0.z * u[2] + w0.w * u[3]
                + w1.x * u[4] + w1.y * u[5] + w1.z * u[6] + w1.w * u[7]
                + w2.x * u[8] + w2.y * u[9] + w2.z * u[10] + w2.w * u[11]
                + w3.x * u[12] + w3.y * u[13] + w3.z * u[14] + w3.w * u[15];
        Tc[((size_t)z * 256 + b0 + b) * 1024 + idx] = d;
      }
    }
  } else {
    // ---------------- phi chain (512-thread version, barriered) ----------------
    int r = t & 63, g = t >> 6;      // g = 0..7, 8 l's each
    __shared__ float u[64];
    __shared__ float part[8][64];
    __shared__ float red[64];
    if (t < 64) u[t] = phi_first[t * 64];
    __syncthreads();
    for (int i2 = 0; i2 < 62; ++i2) {
      float sum = 0.f;
      #pragma unroll
      for (int j = 0; j < 8; ++j) {
        int l = g * 8 + j;
        sum += u[l] * slices[(size_t)i2 * 4096 + l * 64 + r];
      }
      part[g][r] = sum;
      __syncthreads();
      if (g == 0) u[r] = part[0][r] + part[1][r] + part[2][r] + part[3][r]
                       + part[4][r] + part[5][r] + part[6][r] + part[7][r];
      __syncthreads();
    }
    if (t < 64) red[t] = u[t] * phi_last[t * 64 + 63];
    __syncthreads();
    if (t == 0) {
      float s = 0.f;
      for (int l = 0; l < 64; ++l) s += red[l];
      *phiv = s;
    }
  }
}

// ---------------------------------------------------------------------------
// MEGA CHAIN (256 threads, grid 128): bx<64 psi chains, bx>=64 chi chains,
// 4 batches/block, one wave per batch. PURE REGISTER + __shfl chains — no LDS
// cross-lane state, so no barrier/fence needed and no compiler-UB (r8 lesson:
// barrier-free LDS lets the compiler legally cache LDS in registers).
__global__ __launch_bounds__(256) void k_mega_chain(const float* __restrict__ M,
                                                    const float* __restrict__ Tc,
                                                    const float* __restrict__ vpx,
                                                    const float* __restrict__ vch,
                                                    const float* __restrict__ psi_first,
                                                    const float* __restrict__ psi_last,
                                                    const float* __restrict__ chi_first,
                                                    const float* __restrict__ chi_last,
                                                    float* __restrict__ psiv,
                                                    float* __restrict__ chiout) {
  int bx = blockIdx.x;
  int t = threadIdx.x;
  int bl = t >> 6, lane = t & 63;
  if (bx < 64) {
    // -------- psi: lane holds v[lane]; 64 shfl-broadcasts per step --------
    int b = bx * 4 + bl;
    float v;
    {
      const float* u0 = vpx + (size_t)b * 256;   // site 0
      const float* pf = psi_first + lane * 256;
      float s0 = 0.f;
      for (int p = 0; p < 256; ++p) s0 += pf[p] * u0[p];
      v = s0;
    }
    for (int sc = 0; sc < 62; ++sc) {
      const float* Mb = M + ((size_t)sc * 256 + b) * 4096 + lane;
      float sum = 0.f;
      #pragma unroll
      for (int l = 0; l < 64; ++l) {
        float vl = __shfl(v, l);
        sum += vl * Mb[(size_t)l * 64];
      }
      v = sum;
    }
    // epilogue: psi_val[b] = sum_p (sum_l v[l] psi_last[l][p]) * vpx[63][b][p]
    float acc_p = 0.f;
    #pragma unroll
    for (int pp = 0; pp < 4; ++pp) {
      int p = pp * 64 + lane;
      float wv = 0.f;
      #pragma unroll
      for (int l = 0; l < 64; ++l) {
        float vl = __shfl(v, l);
        wv += vl * psi_last[l * 256 + p];
      }
      acc_p += wv * vpx[((size_t)63 * 256 + b) * 256 + p];
    }
    #pragma unroll
    for (int m = 32; m > 0; m >>= 1) acc_p += __shfl_xor(acc_p, m);
    if (lane == 0) psiv[b] = acc_p;
  } else {
    // -------- chi: lane (r,h) holds v[r] duplicated across halves --------
    int b = (bx - 64) * 4 + bl;
    int r = lane & 31, h = lane >> 5;
    float v;
    {
      const float* u0 = vch + (size_t)b * 16;    // site 0
      const float* cf = chi_first + r * 16;
      float s0 = 0.f;
      #pragma unroll
      for (int c = 0; c < 16; ++c) s0 += cf[c] * u0[c];
      v = s0;                                    // same in both halves
    }
    for (int sc = 0; sc < 62; ++sc) {
      const float* Mb = Tc + ((size_t)sc * 256 + b) * 1024 + r * 32 + h * 16;
      float4 m0 = *(const float4*)(Mb);
      float4 m1 = *(const float4*)(Mb + 4);
      float4 m2 = *(const float4*)(Mb + 8);
      float4 m3 = *(const float4*)(Mb + 12);
      float mj[16] = {m0.x, m0.y, m0.z, m0.w, m1.x, m1.y, m1.z, m1.w,
                      m2.x, m2.y, m2.z, m2.w, m3.x, m3.y, m3.z, m3.w};
      float sum = 0.f;
      #pragma unroll
      for (int j = 0; j < 16; ++j) {
        float vl = __shfl(v, h * 16 + j);        // lanes 0..31 hold v[0..31]
        sum += mj[j] * vl;
      }
      sum += __shfl_xor(sum, 32);                // merge halves -> full row sum
      v = sum;                                   // all lanes now hold v_new[r]
    }
    // epilogue: chiout[b][o] raw (psiv/phiv applied in k_combine)
    const float* u63 = vch + ((size_t)63 * 256 + b) * 16;
    float uc[16];
    #pragma unroll
    for (int c = 0; c < 16; ++c) uc[c] = u63[c];
    for (int o = 0; o < 10; ++o) {
      const float* cl = chi_last + r * 16 * 10 + o;
      float wv = 0.f;
      #pragma unroll
      for (int c = 0; c < 16; ++c) wv += cl[c * 10] * uc[c];
      float p = v * wv;                          // duplicated across halves
      #pragma unroll
      for (int m = 32; m > 0; m >>= 1) p += __shfl_xor(p, m);
      if (lane == 0) chiout[b * 10 + o] = p * 0.5f;
    }
  }
}

// ---------------------------------------------------------------------------
// K6: out[b][o] = chiout[b][o] * psiv[b] * phiv
__global__ __launch_bounds__(256) void k_combine(const float* __restrict__ chiout,
                                                 const float* __restrict__ psiv,
                                                 const float* __restrict__ phiv,
                                                 float* __restrict__ out) {
  int t = blockIdx.x * 256 + threadIdx.x;
  if (t < 2560) {
    int b = t / 10;
    out[t] = chiout[t] * psiv[b] * phiv[0];
  }
}

// ---------------------------------------------------------------------------
// ===== Fallback tier (smaller workspace): r7 chunked pipeline, barriered =====
__global__ __launch_bounds__(512) void k_psi_gemm(const float* __restrict__ psi_mid,
                                                  const unsigned short* __restrict__ vpxf_hi,
                                                  const unsigned short* __restrict__ vpxf_lo,
                                                  float* __restrict__ M, int s0) {
  int z = blockIdx.z;
  int s = s0 + z;
  int lr0 = blockIdx.x * 64;
  const float* W = psi_mid + (size_t)s * 4096 * 256;
  const unsigned short* Ahg = vpxf_hi + (size_t)(s + 1) * 65536;
  const unsigned short* Alg = vpxf_lo + (size_t)(s + 1) * 65536;
  __shared__ unsigned short Bh[2][2][4][64][8];
  __shared__ unsigned short Bl[2][2][4][64][8];
  int t = threadIdx.x;
  int lane = t & 63, w = t >> 6;
  int row = t >> 3, kg = t & 7;
  float4 sv0, sv1;
  #define LOADP(p) do {                                                        \
    const float* src = W + (size_t)(lr0 + row) * 256 + ((p) << 6) + kg * 8;    \
    sv0 = *(const float4*)src;                                                 \
    sv1 = *(const float4*)(src + 4);                                           \
  } while (0)
  #define WRITEP(d) do {                                                       \
    float xs[8] = {sv0.x, sv0.y, sv0.z, sv0.w, sv1.x, sv1.y, sv1.z, sv1.w};    \
    us8 hv, lv;                                                                \
    _Pragma("unroll")                                                          \
    for (int i = 0; i < 8; ++i) {                                              \
      unsigned short hb = f2bf(xs[i]);                                         \
      hv[i] = hb;                                                              \
      lv[i] = f2bf(xs[i] - bf2f(hb));                                          \
    }                                                                          \
    int ck = kg >> 2, nt = row >> 4, ln = ((kg & 3) << 4) | (row & 15);        \
    *(us8*)&Bh[d][ck][nt][ln][0] = hv;                                         \
    *(us8*)&Bl[d][ck][nt][ln][0] = lv;                                         \
  } while (0)
  #define LOADA(slot, chunk) do {                                              \
    _Pragma("unroll")                                                          \
    for (int mi = 0; mi < 2; ++mi) {                                           \
      size_t fo = ((size_t)(chunk) * 16 + (w * 2 + mi)) * 512 + (size_t)lane * 8; \
      Ah[slot][mi] = *(const bf16x8*)(Ahg + fo);                               \
      Al[slot][mi] = *(const bf16x8*)(Alg + fo);                               \
    }                                                                          \
  } while (0)
  f32x4 acc[2][4];
  #pragma unroll
  for (int i = 0; i < 2; ++i)
    #pragma unroll
    for (int j = 0; j < 4; ++j) acc[i][j] = (f32x4){0.f, 0.f, 0.f, 0.f};
  bf16x8 Ah[2][2], Al[2][2];
  LOADA(0, 0);
  LOADP(0);
  WRITEP(0);
  __syncthreads();
  #pragma unroll
  for (int p = 0; p < 4; ++p) {
    if (p < 3) LOADP(p + 1);
    #pragma unroll
    for (int c = 0; c < 2; ++c) {
      const int chunk = p * 2 + c;
      const int cur = chunk & 1, nxt = (chunk + 1) & 1;
      if (chunk < 7) LOADA(nxt, chunk + 1);
      #pragma unroll
      for (int n = 0; n < 4; ++n) {
        bf16x8 bh = *(const bf16x8*)&Bh[p & 1][c][n][lane][0];
        bf16x8 bl = *(const bf16x8*)&Bl[p & 1][c][n][lane][0];
        #pragma unroll
        for (int mi = 0; mi < 2; ++mi) {
          acc[mi][n] = __builtin_amdgcn_mfma_f32_16x16x32_bf16(Ah[cur][mi], bh, acc[mi][n], 0, 0, 0);
          acc[mi][n] = __builtin_amdgcn_mfma_f32_16x16x32_bf16(Al[cur][mi], bh, acc[mi][n], 0, 0, 0);
          acc[mi][n] = __builtin_amdgcn_mfma_f32_16x16x32_bf16(Ah[cur][mi], bl, acc[mi][n], 0, 0, 0);
        }
      }
    }
    if (p < 3) WRITEP((p + 1) & 1);
    __syncthreads();
  }
  #undef LOADP
  #undef WRITEP
  #undef LOADA
  int rg = lane >> 4, cidx = lane & 15;
  #pragma unroll
  for (int mi = 0; mi < 2; ++mi) {
    int bbase = (w * 2 + mi) * 16 + rg * 4;
    #pragma unroll
    for (int n = 0; n < 4; ++n) {
      #pragma unroll
      for (int r = 0; r < 4; ++r) {
        M[((size_t)z * 256 + bbase + r) * 4096 + lr0 + n * 16 + cidx] = acc[mi][n][r];
      }
    }
  }
}

__global__ __launch_bounds__(256) void k_psi_chain(const float* __restrict__ M,
                                                   const float* __restrict__ vpx,
                                                   const float* __restrict__ psi_first,
                                                   const float* __restrict__ psi_last,
                                                   float* __restrict__ vpsi,
                                                   float* __restrict__ psiv,
                                                   int nS, int isFirst, int isLast) {
  int b = blockIdx.x;
  int t = threadIdx.x;
  int r = t & 63, g = t >> 6;
  __shared__ float v[64];
  __shared__ float part[4][64];
  __shared__ float red[256];
  if (isFirst) {
    const float* u0 = vpx + (size_t)b * 256;
    float s0 = 0.f;
    for (int p = g * 64; p < g * 64 + 64; ++p) s0 += psi_first[r * 256 + p] * u0[p];
    part[g][r] = s0;
    __syncthreads();
    if (g == 0) v[r] = part[0][r] + part[1][r] + part[2][r] + part[3][r];
    __syncthreads();
  } else {
    if (g == 0) v[r] = vpsi[b * 64 + r];
    __syncthreads();
  }
  for (int sc = 0; sc < nS; ++sc) {
    const float* Mb = M + ((size_t)sc * 256 + b) * 4096;
    float sum = 0.f;
    #pragma unroll
    for (int j = 0; j < 16; ++j) {
      int l = g * 16 + j;
      sum += v[l] * Mb[l * 64 + r];
    }
    part[g][r] = sum;
    __syncthreads();
    if (g == 0) v[r] = part[0][r] + part[1][r] + part[2][r] + part[3][r];
    __syncthreads();
  }
  if (isLast) {
    float qv = 0.f;
    for (int l = 0; l < 64; ++l) qv += v[l] * psi_last[l * 256 + t];
    red[t] = qv * vpx[((size_t)63 * 256 + b) * 256 + t];
    __syncthreads();
    for (int off = 128; off > 0; off >>= 1) {
      if (t < off) red[t] += red[t + off];
      __syncthreads();
    }
    if (t == 0) psiv[b] = red[0];
  } else {
    if (g == 0) vpsi[b * 64 + r] = v[r];
  }
}

__device__ __forceinline__ void phi_chain_body(const float* __restrict__ slices,
                                               const float* __restrict__ phi_first,
                                               const float* __restrict__ phi_last,
                                               float* __restrict__ phiv) {
  int t = threadIdx.x;
  int r = t & 63, g = t >> 6;
  __shared__ float u[64];
  __shared__ float part[4][64];
  __shared__ float red[64];
  if (t < 64) u[t] = phi_first[t * 64];
  __syncthreads();
  for (int i = 0; i < 62; ++i) {
    float sum = 0.f;
    #pragma unroll
    for (int j = 0; j < 16; ++j) {
      int l = g * 16 + j;
      sum += u[l] * slices[(size_t)i * 4096 + l * 64 + r];
    }
    part[g][r] = sum;
    __syncthreads();
    if (g == 0) u[r] = part[0][r] + part[1][r] + part[2][r] + part[3][r];
    __syncthreads();
  }
  if (t < 64) red[t] = u[t] * phi_last[t * 64 + 63];
  __syncthreads();
  if (t == 0) {
    float s = 0.f;
    for (int l = 0; l < 64; ++l) s += red[l];
    *phiv = s;
  }
}

__global__ __launch_bounds__(256) void k_phi_chain(const float* __restrict__ slices,
                                                   const float* __restrict__ phi_first,
                                                   const float* __restrict__ phi_last,
                                                   float* __restrict__ phiv) {
  phi_chain_body(slices, phi_first, phi_last, phiv);
}

__global__ __launch_bounds__(256) void k_chi_gemm(const float* __restrict__ chi_mid,
                                                  const float* __restrict__ vch,
                                                  float* __restrict__ Tc, int s0,
                                                  int phiBlock,
                                                  const float* __restrict__ slices,
                                                  const float* __restrict__ phi_first,
                                                  const float* __restrict__ phi_last,
                                                  float* __restrict__ phiv) {
  if ((int)blockIdx.x == phiBlock) {
    if (blockIdx.y == 0) phi_chain_body(slices, phi_first, phi_last, phiv);
    return;
  }
  int z = blockIdx.x;
  int s = s0 + z;
  int b0 = blockIdx.y * 32;
  int t = threadIdx.x;
  __shared__ float uv[32][16];
  if (t < 128) {
    int idx = t * 4;
    int b = idx >> 4, c = idx & 15;
    *(float4*)&uv[b][c] = *(const float4*)(vch + ((size_t)(s + 1) * 256 + b0 + b) * 16 + c);
  }
  __syncthreads();
  #pragma unroll
  for (int k = 0; k < 4; ++k) {
    int idx = t + k * 256;
    int r = idx >> 5, l = idx & 31;
    const float* Wp = chi_mid + ((size_t)s * 1024 + l * 32 + r) * 16;
    float4 w0 = *(const float4*)(Wp);
    float4 w1 = *(const float4*)(Wp + 4);
    float4 w2 = *(const float4*)(Wp + 8);
    float4 w3 = *(const float4*)(Wp + 12);
    for (int b = 0; b < 32; ++b) {
      const float* u = uv[b];
      float d = w0.x * u[0] + w0.y * u[1] + w0.z * u[2] + w0.w * u[3]
              + w1.x * u[4] + w1.y * u[5] + w1.z * u[6] + w1.w * u[7]
              + w2.x * u[8] + w2.y * u[9] + w2.z * u[10] + w2.w * u[11]
              + w3.x * u[12] + w3.y * u[13] + w3.z * u[14] + w3.w * u[15];
      Tc[((size_t)z * 256 + b0 + b) * 1024 + idx] = d;
    }
  }
}

__global__ __launch_bounds__(64) void k_chi_chain(const float* __restrict__ Tc,
                                                  const float* __restrict__ chi_first,
                                                  const float* __restrict__ chi_last,
                                                  const float* __restrict__ vch,
                                                  const float* __restrict__ psiv,
                                                  const float* __restrict__ phiv,
                                                  float* __restrict__ vchi,
                                                  float* __restrict__ out,
                                                  int nS, int isFirst, int isLast) {
  int b = blockIdx.x;
  int lane = threadIdx.x;
  int r = lane & 31, h = lane >> 5;
  __shared__ float v[32];
  if (isFirst) {
    if (h == 0) {
      const float* u0 = vch + (size_t)b * 16;
      const float* cf = chi_first + r * 16;
      float s0 = 0.f;
      #pragma unroll
      for (int c = 0; c < 16; ++c) s0 += cf[c] * u0[c];
      v[r] = s0;
    }
  } else {
    if (h == 0) v[r] = vchi[b * 32 + r];
  }
  __syncthreads();
  for (int sc = 0; sc < nS; ++sc) {
    const float* Mb = Tc + ((size_t)sc * 256 + b) * 1024 + r * 32 + h * 16;
    float4 m0 = *(const float4*)(Mb);
    float4 m1 = *(const float4*)(Mb + 4);
    float4 m2 = *(const float4*)(Mb + 8);
    float4 m3 = *(const float4*)(Mb + 12);
    const float* vv = &v[h * 16];
    float sum = m0.x * vv[0] + m0.y * vv[1] + m0.z * vv[2] + m0.w * vv[3]
              + m1.x * vv[4] + m1.y * vv[5] + m1.z * vv[6] + m1.w * vv[7]
              + m2.x * vv[8] + m2.y * vv[9] + m2.z * vv[10] + m2.w * vv[11]
              + m3.x * vv[12] + m3.y * vv[13] + m3.z * vv[14] + m3.w * vv[15];
    sum += __shfl_xor(sum, 32);
    __syncthreads();
    if (h == 0) v[r] = sum;
    __syncthreads();
  }
  if (isLast) {
    const float* u63 = vch + ((size_t)63 * 256 + b) * 16;
    float uc[16];
    #pragma unroll
    for (int c = 0; c < 16; ++c) uc[c] = u63[c];
    float scale = 0.5f * psiv[b] * phiv[0];
    for (int o = 0; o < 10; ++o) {
      const float* cl = chi_last + r * 16 * 10 + o;
      float w = 0.f;
      #pragma unroll
      for (int c = 0; c < 16; ++c) w += cl[c * 10] * uc[c];
      float p = v[r] * w;
      #pragma unroll
      for (int m = 32; m > 0; m >>= 1) p += __shfl_xor(p, m);
      if (lane == 0) out[b * 10 + o] = p * scale;
    }
  } else {
    if (h == 0) vchi[b * 32 + r] = v[r];
  }
}

__global__ __launch_bounds__(256) void k_chi_fused(const float* __restrict__ chi_first,
                                                   const float* __restrict__ chi_mid,
                                                   const float* __restrict__ chi_last,
                                                   const float* __restrict__ vch,
                                                   const float* __restrict__ psiv,
                                                   const float* __restrict__ phiv,
                                                   float* __restrict__ out) {
  int t = threadIdx.x;
  int bl = t >> 6, lg = (t >> 5) & 1, r = t & 31;
  int b = blockIdx.x * 4 + bl;
  __shared__ float v[4][32];
  __shared__ float part[4][2][32];
  if (lg == 0) {
    const float* u0 = vch + (size_t)b * 16;
    float s0 = 0.f;
    #pragma unroll
    for (int c = 0; c < 16; ++c) s0 += chi_first[r * 16 + c] * u0[c];
    v[bl][r] = s0;
  }
  __syncthreads();
  for (int s = 0; s < 62; ++s) {
    const float* u = vch + ((size_t)(s + 1) * 256 + b) * 16;
    float uc[16];
    #pragma unroll
    for (int c = 0; c < 16; ++c) uc[c] = u[c];
    const float* W = chi_mid + (size_t)s * 32 * 32 * 16;
    float sum = 0.f;
    #pragma unroll
    for (int j = 0; j < 16; ++j) {
      int l = lg * 16 + j;
      const float* Wl = W + ((size_t)l * 32 + r) * 16;
      float tt = 0.f;
      #pragma unroll
      for (int c = 0; c < 16; ++c) tt += Wl[c] * uc[c];
      sum += v[bl][l] * tt;
    }
    part[bl][lg][r] = sum;
    __syncthreads();
    if (lg == 0) v[bl][r] = part[bl][0][r] + part[bl][1][r];
    __syncthreads();
  }
  const float* u63 = vch + ((size_t)63 * 256 + b) * 16;
  float uc[16];
  #pragma unroll
  for (int c = 0; c < 16; ++c) uc[c] = u63[c];
  if (r < 10) {
    float acc = 0.f;
    #pragma unroll
    for (int j = 0; j < 16; ++j) {
      int l = lg * 16 + j;
      const float* cl = chi_last + (size_t)l * 16 * 10;
      float tt = 0.f;
      #pragma unroll
      for (int c = 0; c < 16; ++c) tt += cl[c * 10 + r] * uc[c];
      acc += v[bl][l] * tt;
    }
    part[bl][lg][r] = acc;
  }
  __syncthreads();
  if (lg == 0 && r < 10)
    out[b * 10 + r] = (part[bl][0][r] + part[bl][1][r]) * psiv[b] * phiv[0];
}

__global__ __launch_bounds__(256) void k_psi_direct(const float* __restrict__ x,
                                                    const float* __restrict__ psi_mid,
                                                    const float* __restrict__ psi_first,
                                                    const float* __restrict__ psi_last,
                                                    float* __restrict__ psiv) {
  int b = blockIdx.x;
  int t = threadIdx.x;
  int r = t & 63, g = t >> 6;
  __shared__ float u[256];
  __shared__ float v[64];
  __shared__ float part[4][64];
  __shared__ float red[256];
  const float* xb = x + ((size_t)b << 18);
  {
    const float* rw = xb + (size_t)0 * 4096 + t * 16;
    float sm = 0.f;
    #pragma unroll
    for (int c = 0; c < 16; ++c) sm += rw[c];
    u[t] = sm * (1.0f / 16.0f);
  }
  __syncthreads();
  {
    float s0 = 0.f;
    for (int p = g * 64; p < g * 64 + 64; ++p) s0 += psi_first[r * 256 + p] * u[p];
    part[g][r] = s0;
    __syncthreads();
    if (g == 0) v[r] = part[0][r] + part[1][r] + part[2][r] + part[3][r];
  }
  __syncthreads();
  for (int s = 0; s < 62; ++s) {
    __syncthreads();
    {
      const float* rw = xb + (size_t)(s + 1) * 4096 + t * 16;
      float sm = 0.f;
      #pragma unroll
      for (int c = 0; c < 16; ++c) sm += rw[c];
      u[t] = sm * (1.0f / 16.0f);
    }
    __syncthreads();
    const float* W = psi_mid + (size_t)s * 4096 * 256;
    float sum = 0.f;
    for (int l = 0; l < 64; ++l) {
      const float* Wl = W + ((size_t)(l * 64 + r)) * 256 + g * 64;
      float tt = 0.f;
      #pragma unroll 8
      for (int k = 0; k < 64; ++k) tt += Wl[k] * u[g * 64 + k];
      sum += v[l] * tt;
    }
    part[g][r] = sum;
    __syncthreads();
    if (g == 0) v[r] = part[0][r] + part[1][r] + part[2][r] + part[3][r];
    __syncthreads();
  }
  __syncthreads();
  {
    const float* rw = xb + (size_t)63 * 4096 + t * 16;
    float sm = 0.f;
    #pragma unroll
    for (int c = 0; c < 16; ++c) sm += rw[c];
    u[t] = sm * (1.0f / 16.0f);
  }
  __syncthreads();
  float qv = 0.f;
  for (int l = 0; l < 64; ++l) qv += v[l] * psi_last[l * 256 + t];
  red[t] = qv * u[t];
  __syncthreads();
  for (int off = 128; off > 0; off >>= 1) {
    if (t < off) red[t] += red[t + off];
    __syncthreads();
  }
  if (t == 0) psiv[b] = red[0];
}

// ---------------------------------------------------------------------------
extern "C" void kernel_launch(void* const* d_in, const int* in_sizes, int n_in,
                              void* d_out, int out_size, void* d_ws, size_t ws_size,
                              hipStream_t stream) {
  const float* x         = (const float*)d_in[0];
  const float* chi_first = (const float*)d_in[1];
  const float* chi_mid   = (const float*)d_in[2];
  const float* chi_last  = (const float*)d_in[3];
  const float* psi_first = (const float*)d_in[4];
  const float* psi_mid   = (const float*)d_in[5];
  const float* psi_last  = (const float*)d_in[6];
  const float* phi_first = (const float*)d_in[7];
  const float* phi_mid   = (const float*)d_in[8];
  const float* phi_last  = (const float*)d_in[9];
  float* out = (float*)d_out;
  float* ws  = (float*)d_ws;

  size_t wsf = ws_size / 4;
  size_t off = 0;
  float* vch    = ws + off; off += (size_t)64 * 256 * 16;     // 262144
  float* psiv   = ws + off; off += 256;
  float* chiout = ws + off; off += 2560;
  float* phisl  = ws + off; off += (size_t)62 * 64 * 64;      // 253952
  float* phiv   = ws + off; off += 16;
  float* vpsi   = ws + off; off += (size_t)64 * 256;          // 16384
  float* vchi   = ws + off; off += (size_t)32 * 256;          // 8192
  float* vpx    = ws + off; off += (size_t)64 * 256 * 256;    // 4194304
  unsigned short* vpxf_hi = (unsigned short*)(ws + off); off += (size_t)64 * 65536 / 2;
  unsigned short* vpxf_lo = (unsigned short*)(ws + off); off += (size_t)64 * 65536 / 2;
  float* Mbuf   = ws + off;
  size_t mfloats = (wsf > off) ? (wsf - off) : 0;
  size_t needM  = (size_t)62 * 256 * 4096;                    // 65,011,712
  size_t needTc = (size_t)62 * 256 * 1024;                    // 16,252,928
  float* Tcbuf  = Mbuf + needM;

  if (mfloats >= needM + needTc) {
    // ===== Overlapped path: 4 dispatches =====
    k_reduce_x<<<16384 + 62, 256, 0, stream>>>(x, vch, vpx, vpxf_hi, vpxf_lo,
                                               phi_mid, phisl);
    k_mega_gemm<<<4465, 512, 0, stream>>>(psi_mid, vpxf_hi, vpxf_lo, Mbuf,
                                          chi_mid, vch, Tcbuf,
                                          phisl, phi_first, phi_last, phiv);
    k_mega_chain<<<128, 256, 0, stream>>>(Mbuf, Tcbuf, vpx, vch,
                                          psi_first, psi_last,
                                          chi_first, chi_last, psiv, chiout);
    k_combine<<<10, 256, 0, stream>>>(chiout, psiv, phiv, out);
  } else {
    int C = (int)(mfloats / ((size_t)256 * 4096));
    if (C > 62) C = 62;
    int Cc = (int)(mfloats / ((size_t)256 * 1024));
    if (Cc > 62) Cc = 62;
    if (C >= 1) {
      k_reduce_x<<<16384 + 62, 256, 0, stream>>>(x, vch, vpx, vpxf_hi, vpxf_lo,
                                                 phi_mid, phisl);
      int done = 0;
      while (done < 62) {
        int c = imin(C, 62 - done);
        k_psi_gemm<<<dim3(64, 1, c), 512, 0, stream>>>(psi_mid, vpxf_hi, vpxf_lo, Mbuf, done);
        k_psi_chain<<<256, 256, 0, stream>>>(Mbuf, vpx, psi_first, psi_last,
                                             vpsi, psiv, c, (done == 0) ? 1 : 0,
                                             (done + c == 62) ? 1 : 0);
        done += c;
      }
      done = 0;
      while (done < 62) {
        int c = imin(Cc, 62 - done);
        int phiBlk = (done == 0) ? c : -1;
        int gx = (done == 0) ? (c + 1) : c;
        k_chi_gemm<<<dim3(gx, 8), 256, 0, stream>>>(chi_mid, vch, Mbuf, done, phiBlk,
                                                    phisl, phi_first, phi_last, phiv);
        k_chi_chain<<<256, 64, 0, stream>>>(Mbuf, chi_first, chi_last, vch,
                                            psiv, phiv, vchi, out, c,
                                            (done == 0) ? 1 : 0,
                                            (done + c == 62) ? 1 : 0);
        done += c;
      }
    } else {
      k_reduce_x<<<16384 + 62, 256, 0, stream>>>(x, vch, nullptr, nullptr, nullptr,
                                                 phi_mid, phisl);
      k_psi_direct<<<256, 256, 0, stream>>>(x, psi_mid, psi_first, psi_last, psiv);
      k_phi_chain<<<1, 256, 0, stream>>>(phisl, phi_first, phi_last, phiv);
      k_chi_fused<<<64, 256, 0, stream>>>(chi_first, chi_mid, chi_last, vch, psiv, phiv, out);
    }
  }
}

// Round 10
// 386.600 us; speedup vs baseline: 4.5035x; 4.5035x over previous
//
#include <hip/hip_runtime.h>

// dims: L=64, CH=16, PIX=256, PAT=64, RC=32, BD=64, OUT=10, B=256
// inputs: 0=x(256,64,256,16) 1=chi_first(32,16) 2=chi_mid(62,32,32,16)
// 3=chi_last(32,16,10) 4=psi_first(64,256) 5=psi_mid(62,64,64,256)
// 6=psi_last(64,256) 7=phi_first(64,64) 8=phi_mid(62,64,64,64) 9=phi_last(64,64)

static inline int imin(int a, int b) { return a < b ? a : b; }

typedef __attribute__((ext_vector_type(8))) short bf16x8;          // 8 bf16 (4 VGPR)
typedef __attribute__((ext_vector_type(8))) unsigned short us8;
typedef __attribute__((ext_vector_type(4))) float f32x4;

__device__ __forceinline__ unsigned short f2bf(float v) {
  union { float f; unsigned int u; } c; c.f = v;
  unsigned int u = c.u;
  unsigned int r = (u + 0x7fffu + ((u >> 16) & 1u)) >> 16;  // RTN-even
  return (unsigned short)r;
}
__device__ __forceinline__ float bf2f(unsigned short h) {
  union { unsigned int u; float f; } c; c.u = ((unsigned int)h) << 16;
  return c.f;
}

// ---------------------------------------------------------------------------
// K1: vpx means + bf16 hi/lo fragment emit. Fused: blocks >= 16384 do the
// phi slice gather (slices[i][l*64+r] = phi_mid[i][l][r][i+1]).
__global__ __launch_bounds__(256) void k_reduce_x(const float* __restrict__ x,
                                                  float* __restrict__ vch,
                                                  float* __restrict__ vpx,
                                                  unsigned short* __restrict__ vpxf_hi,
                                                  unsigned short* __restrict__ vpxf_lo,
                                                  const float* __restrict__ phi_mid,
                                                  float* __restrict__ slices) {
  if (blockIdx.x >= 16384) {                 // phi gather block
    int i = blockIdx.x - 16384;              // 0..61
    int t = threadIdx.x;
    #pragma unroll
    for (int k = 0; k < 16; ++k) {
      int idx = t + k * 256;                 // l*64 + r
      slices[(size_t)i * 4096 + idx] = phi_mid[((size_t)i * 4096 + idx) * 64 + (i + 1)];
    }
    return;
  }
  int bp = blockIdx.x;             // b*64 + s
  int b = bp >> 6, s = bp & 63;
  int q = threadIdx.x;             // = p
  const float* row = x + ((size_t)bp << 12) + q * 16;
  float4 r0 = *(const float4*)(row);
  float4 r1 = *(const float4*)(row + 4);
  float4 r2 = *(const float4*)(row + 8);
  float4 r3 = *(const float4*)(row + 12);
  float csum = r0.x + r0.y + r0.z + r0.w + r1.x + r1.y + r1.z + r1.w
             + r2.x + r2.y + r2.z + r2.w + r3.x + r3.y + r3.z + r3.w;
  float val = csum * (1.0f / 16.0f);
  if (vpx && (s == 0 || s == 63)) vpx[((size_t)s * 256 + b) * 256 + q] = val;
  if (vpxf_hi && s >= 1 && s <= 62) {
    unsigned short hb = f2bf(val);
    unsigned short lb = f2bf(val - bf2f(hb));
    size_t fa = (size_t)s * 65536
              + (((size_t)(q >> 5) * 16 + (b >> 4)) * 64 + (((q >> 3) & 3) * 16 + (b & 15))) * 8
              + (q & 7);
    vpxf_hi[fa] = hb;
    vpxf_lo[fa] = lb;
  }

  __shared__ float sc[256][20];
  *(float4*)&sc[q][0]  = r0;
  *(float4*)&sc[q][4]  = r1;
  *(float4*)&sc[q][8]  = r2;
  *(float4*)&sc[q][12] = r3;
  __syncthreads();
  int c = q & 15, g = q >> 4;
  float ps = 0.f;
  #pragma unroll
  for (int k = 0; k < 16; ++k) ps += sc[g * 16 + k][c];
  __shared__ float p2[16][17];
  p2[g][c] = ps;
  __syncthreads();
  if (q < 16) {
    float s2 = 0.f;
    #pragma unroll
    for (int k = 0; k < 16; ++k) s2 += p2[k][q];
    vch[((size_t)s * 256 + b) * 16 + q] = s2 * (1.0f / 256.0f);
  }
}

// ---------------------------------------------------------------------------
// MEGA GEMM (512 threads): bx<3968 psi MFMA gemm; 3968<=bx<4464 chi gemm;
// bx==4464 phi chain.
__global__ __launch_bounds__(512) void k_mega_gemm(const float* __restrict__ psi_mid,
                                                   const unsigned short* __restrict__ vpxf_hi,
                                                   const unsigned short* __restrict__ vpxf_lo,
                                                   float* __restrict__ M,
                                                   const float* __restrict__ chi_mid,
                                                   const float* __restrict__ vch,
                                                   float* __restrict__ Tc,
                                                   const float* __restrict__ slices,
                                                   const float* __restrict__ phi_first,
                                                   const float* __restrict__ phi_last,
                                                   float* __restrict__ phiv) {
  int bx = blockIdx.x;
  int t = threadIdx.x;
  if (bx < 3968) {
    // ---------------- psi MFMA gemm: site z, lr-block ----------------
    int z = bx >> 6;
    int lr0 = (bx & 63) * 64;
    const float* W = psi_mid + (size_t)z * 4096 * 256;
    const unsigned short* Ahg = vpxf_hi + (size_t)(z + 1) * 65536;
    const unsigned short* Alg = vpxf_lo + (size_t)(z + 1) * 65536;
    __shared__ unsigned short Bh[2][2][4][64][8];   // 16 KB
    __shared__ unsigned short Bl[2][2][4][64][8];   // 16 KB
    int lane = t & 63, w = t >> 6;
    int row = t >> 3, kg = t & 7;
    float4 sv0, sv1;

    #define LOADP(p) do {                                                      \
      const float* src = W + (size_t)(lr0 + row) * 256 + ((p) << 6) + kg * 8;  \
      sv0 = *(const float4*)src;                                               \
      sv1 = *(const float4*)(src + 4);                                         \
    } while (0)
    #define WRITEP(d) do {                                                     \
      float xs[8] = {sv0.x, sv0.y, sv0.z, sv0.w, sv1.x, sv1.y, sv1.z, sv1.w};  \
      us8 hv, lv;                                                              \
      _Pragma("unroll")                                                        \
      for (int i = 0; i < 8; ++i) {                                            \
        unsigned short hb = f2bf(xs[i]);                                       \
        hv[i] = hb;                                                            \
        lv[i] = f2bf(xs[i] - bf2f(hb));                                        \
      }                                                                        \
      int ck = kg >> 2, nt = row >> 4, ln = ((kg & 3) << 4) | (row & 15);      \
      *(us8*)&Bh[d][ck][nt][ln][0] = hv;                                       \
      *(us8*)&Bl[d][ck][nt][ln][0] = lv;                                       \
    } while (0)
    #define LOADA(slot, chunk) do {                                            \
      _Pragma("unroll")                                                        \
      for (int mi = 0; mi < 2; ++mi) {                                         \
        size_t fo = ((size_t)(chunk) * 16 + (w * 2 + mi)) * 512 + (size_t)lane * 8; \
        Ah[slot][mi] = *(const bf16x8*)(Ahg + fo);                             \
        Al[slot][mi] = *(const bf16x8*)(Alg + fo);                             \
      }                                                                        \
    } while (0)

    f32x4 acc[2][4];
    #pragma unroll
    for (int i = 0; i < 2; ++i)
      #pragma unroll
      for (int j = 0; j < 4; ++j) acc[i][j] = (f32x4){0.f, 0.f, 0.f, 0.f};
    bf16x8 Ah[2][2], Al[2][2];

    LOADA(0, 0);
    LOADP(0);
    WRITEP(0);
    __syncthreads();
    #pragma unroll
    for (int p = 0; p < 4; ++p) {
      if (p < 3) LOADP(p + 1);
      #pragma unroll
      for (int c = 0; c < 2; ++c) {
        const int chunk = p * 2 + c;
        const int cur = chunk & 1, nxt = (chunk + 1) & 1;
        if (chunk < 7) LOADA(nxt, chunk + 1);
        #pragma unroll
        for (int n = 0; n < 4; ++n) {
          bf16x8 bh = *(const bf16x8*)&Bh[p & 1][c][n][lane][0];
          bf16x8 bl = *(const bf16x8*)&Bl[p & 1][c][n][lane][0];
          #pragma unroll
          for (int mi = 0; mi < 2; ++mi) {
            acc[mi][n] = __builtin_amdgcn_mfma_f32_16x16x32_bf16(Ah[cur][mi], bh, acc[mi][n], 0, 0, 0);
            acc[mi][n] = __builtin_amdgcn_mfma_f32_16x16x32_bf16(Al[cur][mi], bh, acc[mi][n], 0, 0, 0);
            acc[mi][n] = __builtin_amdgcn_mfma_f32_16x16x32_bf16(Ah[cur][mi], bl, acc[mi][n], 0, 0, 0);
          }
        }
      }
      if (p < 3) WRITEP((p + 1) & 1);
      __syncthreads();
    }
    #undef LOADP
    #undef WRITEP
    #undef LOADA

    int rg = lane >> 4, cidx = lane & 15;
    #pragma unroll
    for (int mi = 0; mi < 2; ++mi) {
      int bbase = (w * 2 + mi) * 16 + rg * 4;
      #pragma unroll
      for (int n = 0; n < 4; ++n) {
        #pragma unroll
        for (int r = 0; r < 4; ++r) {
          M[((size_t)z * 256 + bbase + r) * 4096 + lr0 + n * 16 + cidx] = acc[mi][n][r];
        }
      }
    }
  } else if (bx < 4464) {
    // ---------------- chi gemm: Tc[z][b][r*32+l] ----------------
    int i = bx - 3968;
    int z = i >> 3;                 // site 0..61
    int b0 = (i & 7) * 32;
    __shared__ float uv[32][16];
    if (t < 128) {
      int idx = t * 4;
      int b = idx >> 4, c = idx & 15;
      *(float4*)&uv[b][c] = *(const float4*)(vch + ((size_t)(z + 1) * 256 + b0 + b) * 16 + c);
    }
    __syncthreads();
    #pragma unroll
    for (int k = 0; k < 2; ++k) {
      int idx = t + k * 512;         // output index = r*32 + l
      int r = idx >> 5, l = idx & 31;
      const float* Wp = chi_mid + ((size_t)z * 1024 + l * 32 + r) * 16;
      float4 w0 = *(const float4*)(Wp);
      float4 w1 = *(const float4*)(Wp + 4);
      float4 w2 = *(const float4*)(Wp + 8);
      float4 w3 = *(const float4*)(Wp + 12);
      for (int b = 0; b < 32; ++b) {
        const float* u = uv[b];
        float d = w0.x * u[0] + w0.y * u[1] + w0.z * u[2] + w0.w * u[3]
                + w1.x * u[4] + w1.y * u[5] + w1.z * u[6] + w1.w * u[7]
                + w2.x * u[8] + w2.y * u[9] + w2.z * u[10] + w2.w * u[11]
                + w3.x * u[12] + w3.y * u[13] + w3.z * u[14] + w3.w * u[15];
        Tc[((size_t)z * 256 + b0 + b) * 1024 + idx] = d;
      }
    }
  } else {
    // ---------------- phi chain (512-thread version, barriered) ----------------
    int r = t & 63, g = t >> 6;      // g = 0..7, 8 l's each
    __shared__ float u[64];
    __shared__ float part[8][64];
    __shared__ float red[64];
    if (t < 64) u[t] = phi_first[t * 64];
    __syncthreads();
    for (int i2 = 0; i2 < 62; ++i2) {
      float sum = 0.f;
      #pragma unroll
      for (int j = 0; j < 8; ++j) {
        int l = g * 8 + j;
        sum += u[l] * slices[(size_t)i2 * 4096 + l * 64 + r];
      }
      part[g][r] = sum;
      __syncthreads();
      if (g == 0) u[r] = part[0][r] + part[1][r] + part[2][r] + part[3][r]
                       + part[4][r] + part[5][r] + part[6][r] + part[7][r];
      __syncthreads();
    }
    if (t < 64) red[t] = u[t] * phi_last[t * 64 + 63];
    __syncthreads();
    if (t == 0) {
      float s = 0.f;
      for (int l = 0; l < 64; ++l) s += red[l];
      *phiv = s;
    }
  }
}

// ---------------------------------------------------------------------------
// MEGA CHAIN (256 threads, grid 128): bx<64 psi chains, bx>=64 chi chains,
// 4 batches/block, one wave per batch. Pure register+shfl chains; r9 lesson:
// loads MUST be batch-issued into named register arrays separated from the
// serial shfl-FMA chain (interleaved loads serialize on HBM latency: 1478us).
// 2-deep prefetch: next site's batch flies during current compute.
__global__ __launch_bounds__(256) void k_mega_chain(const float* __restrict__ M,
                                                    const float* __restrict__ Tc,
                                                    const float* __restrict__ vpx,
                                                    const float* __restrict__ vch,
                                                    const float* __restrict__ psi_first,
                                                    const float* __restrict__ psi_last,
                                                    const float* __restrict__ chi_first,
                                                    const float* __restrict__ chi_last,
                                                    float* __restrict__ psiv,
                                                    float* __restrict__ chiout) {
  int bx = blockIdx.x;
  int t = threadIdx.x;
  int bl = t >> 6, lane = t & 63;
  if (bx < 64) {
    // -------- psi: lane holds v[lane]; batch-load + shfl-reduce steps --------
    int b = bx * 4 + bl;
    float v;
    {
      const float* u0 = vpx + (size_t)b * 256;   // site 0
      const float* pf = psi_first + lane * 256;
      float s0 = 0.f, s1 = 0.f, s2 = 0.f, s3 = 0.f;
      for (int p = 0; p < 256; p += 4) {
        s0 += pf[p] * u0[p];   s1 += pf[p + 1] * u0[p + 1];
        s2 += pf[p + 2] * u0[p + 2]; s3 += pf[p + 3] * u0[p + 3];
      }
      v = (s0 + s1) + (s2 + s3);
    }
    #define MLOAD(buf, sc) do {                                                \
      const float* Mb = M + ((size_t)(sc) * 256 + b) * 4096 + lane;            \
      _Pragma("unroll")                                                        \
      for (int l = 0; l < 64; ++l) buf[l] = Mb[(size_t)l * 64];                \
    } while (0)
    #define MSTEP(buf) do {                                                    \
      float s0 = 0.f, s1 = 0.f, s2 = 0.f, s3 = 0.f;                            \
      _Pragma("unroll")                                                        \
      for (int l = 0; l < 16; ++l) {                                           \
        s0 += __shfl(v, 4 * l + 0) * buf[4 * l + 0];                           \
        s1 += __shfl(v, 4 * l + 1) * buf[4 * l + 1];                           \
        s2 += __shfl(v, 4 * l + 2) * buf[4 * l + 2];                           \
        s3 += __shfl(v, 4 * l + 3) * buf[4 * l + 3];                           \
      }                                                                        \
      v = (s0 + s1) + (s2 + s3);                                               \
    } while (0)
    {
      float mvA[64], mvB[64];
      MLOAD(mvA, 0);
      #pragma unroll 1
      for (int sc = 0; sc < 62; sc += 2) {      // 62 even: pairs complete
        MLOAD(mvB, sc + 1);
        MSTEP(mvA);
        if (sc + 2 < 62) MLOAD(mvA, sc + 2);
        MSTEP(mvB);
      }
    }
    #undef MLOAD
    #undef MSTEP
    // epilogue: psi_val[b] = sum_p (sum_l v[l] psi_last[l][p]) * vpx[63][b][p]
    float acc_p = 0.f;
    #pragma unroll
    for (int pp = 0; pp < 4; ++pp) {
      int p = pp * 64 + lane;
      float pl[64];
      #pragma unroll
      for (int l = 0; l < 64; ++l) pl[l] = psi_last[l * 256 + p];
      float s0 = 0.f, s1 = 0.f, s2 = 0.f, s3 = 0.f;
      #pragma unroll
      for (int l = 0; l < 16; ++l) {
        s0 += __shfl(v, 4 * l + 0) * pl[4 * l + 0];
        s1 += __shfl(v, 4 * l + 1) * pl[4 * l + 1];
        s2 += __shfl(v, 4 * l + 2) * pl[4 * l + 2];
        s3 += __shfl(v, 4 * l + 3) * pl[4 * l + 3];
      }
      float wv = (s0 + s1) + (s2 + s3);
      acc_p += wv * vpx[((size_t)63 * 256 + b) * 256 + p];
    }
    #pragma unroll
    for (int m = 32; m > 0; m >>= 1) acc_p += __shfl_xor(acc_p, m);
    if (lane == 0) psiv[b] = acc_p;
  } else {
    // -------- chi: lane (r,h) holds v[r] duplicated across halves --------
    int b = (bx - 64) * 4 + bl;
    int r = lane & 31, h = lane >> 5;
    float v;
    {
      const float* u0 = vch + (size_t)b * 16;    // site 0
      const float* cf = chi_first + r * 16;
      float s0 = 0.f;
      #pragma unroll
      for (int c = 0; c < 16; ++c) s0 += cf[c] * u0[c];
      v = s0;                                    // same in both halves
    }
    #define CLOADX(buf, sc) do {                                               \
      const float* Mb = Tc + ((size_t)(sc) * 256 + b) * 1024 + r * 32 + h * 16; \
      *(float4*)&buf[0]  = *(const float4*)(Mb);                               \
      *(float4*)&buf[4]  = *(const float4*)(Mb + 4);                           \
      *(float4*)&buf[8]  = *(const float4*)(Mb + 8);                           \
      *(float4*)&buf[12] = *(const float4*)(Mb + 12);                          \
    } while (0)
    #define CSTEPX(buf) do {                                                   \
      float s0 = 0.f, s1 = 0.f;                                                \
      _Pragma("unroll")                                                        \
      for (int j = 0; j < 8; ++j) {                                            \
        s0 += __shfl(v, h * 16 + 2 * j)     * buf[2 * j];                      \
        s1 += __shfl(v, h * 16 + 2 * j + 1) * buf[2 * j + 1];                  \
      }                                                                        \
      float sum = s0 + s1;                                                     \
      sum += __shfl_xor(sum, 32);                                              \
      v = sum;                                                                 \
    } while (0)
    {
      float mjA[16], mjB[16];
      CLOADX(mjA, 0);
      #pragma unroll 1
      for (int sc = 0; sc < 62; sc += 2) {
        CLOADX(mjB, sc + 1);
        CSTEPX(mjA);
        if (sc + 2 < 62) CLOADX(mjA, sc + 2);
        CSTEPX(mjB);
      }
    }
    #undef CLOADX
    #undef CSTEPX
    // epilogue: chiout[b][o] raw (psiv/phiv applied in k_combine)
    const float* u63 = vch + ((size_t)63 * 256 + b) * 16;
    float uc[16];
    #pragma unroll
    for (int c = 0; c < 16; ++c) uc[c] = u63[c];
    for (int o = 0; o < 10; ++o) {
      const float* cl = chi_last + r * 16 * 10 + o;
      float wv = 0.f;
      #pragma unroll
      for (int c = 0; c < 16; ++c) wv += cl[c * 10] * uc[c];
      float p = v * wv;                          // duplicated across halves
      #pragma unroll
      for (int m = 32; m > 0; m >>= 1) p += __shfl_xor(p, m);
      if (lane == 0) chiout[b * 10 + o] = p * 0.5f;
    }
  }
}

// ---------------------------------------------------------------------------
// K6: out[b][o] = chiout[b][o] * psiv[b] * phiv
__global__ __launch_bounds__(256) void k_combine(const float* __restrict__ chiout,
                                                 const float* __restrict__ psiv,
                                                 const float* __restrict__ phiv,
                                                 float* __restrict__ out) {
  int t = blockIdx.x * 256 + threadIdx.x;
  if (t < 2560) {
    int b = t / 10;
    out[t] = chiout[t] * psiv[b] * phiv[0];
  }
}

// ---------------------------------------------------------------------------
// ===== Fallback tier (smaller workspace): r7 chunked pipeline, barriered =====
__global__ __launch_bounds__(512) void k_psi_gemm(const float* __restrict__ psi_mid,
                                                  const unsigned short* __restrict__ vpxf_hi,
                                                  const unsigned short* __restrict__ vpxf_lo,
                                                  float* __restrict__ M, int s0) {
  int z = blockIdx.z;
  int s = s0 + z;
  int lr0 = blockIdx.x * 64;
  const float* W = psi_mid + (size_t)s * 4096 * 256;
  const unsigned short* Ahg = vpxf_hi + (size_t)(s + 1) * 65536;
  const unsigned short* Alg = vpxf_lo + (size_t)(s + 1) * 65536;
  __shared__ unsigned short Bh[2][2][4][64][8];
  __shared__ unsigned short Bl[2][2][4][64][8];
  int t = threadIdx.x;
  int lane = t & 63, w = t >> 6;
  int row = t >> 3, kg = t & 7;
  float4 sv0, sv1;
  #define LOADP(p) do {                                                        \
    const float* src = W + (size_t)(lr0 + row) * 256 + ((p) << 6) + kg * 8;    \
    sv0 = *(const float4*)src;                                                 \
    sv1 = *(const float4*)(src + 4);                                           \
  } while (0)
  #define WRITEP(d) do {                                                       \
    float xs[8] = {sv0.x, sv0.y, sv0.z, sv0.w, sv1.x, sv1.y, sv1.z, sv1.w};    \
    us8 hv, lv;                                                                \
    _Pragma("unroll")                                                          \
    for (int i = 0; i < 8; ++i) {                                              \
      unsigned short hb = f2bf(xs[i]);                                         \
      hv[i] = hb;                                                              \
      lv[i] = f2bf(xs[i] - bf2f(hb));                                          \
    }                                                                          \
    int ck = kg >> 2, nt = row >> 4, ln = ((kg & 3) << 4) | (row & 15);        \
    *(us8*)&Bh[d][ck][nt][ln][0] = hv;                                         \
    *(us8*)&Bl[d][ck][nt][ln][0] = lv;                                         \
  } while (0)
  #define LOADA(slot, chunk) do {                                              \
    _Pragma("unroll")                                                          \
    for (int mi = 0; mi < 2; ++mi) {                                           \
      size_t fo = ((size_t)(chunk) * 16 + (w * 2 + mi)) * 512 + (size_t)lane * 8; \
      Ah[slot][mi] = *(const bf16x8*)(Ahg + fo);                               \
      Al[slot][mi] = *(const bf16x8*)(Alg + fo);                               \
    }                                                                          \
  } while (0)
  f32x4 acc[2][4];
  #pragma unroll
  for (int i = 0; i < 2; ++i)
    #pragma unroll
    for (int j = 0; j < 4; ++j) acc[i][j] = (f32x4){0.f, 0.f, 0.f, 0.f};
  bf16x8 Ah[2][2], Al[2][2];
  LOADA(0, 0);
  LOADP(0);
  WRITEP(0);
  __syncthreads();
  #pragma unroll
  for (int p = 0; p < 4; ++p) {
    if (p < 3) LOADP(p + 1);
    #pragma unroll
    for (int c = 0; c < 2; ++c) {
      const int chunk = p * 2 + c;
      const int cur = chunk & 1, nxt = (chunk + 1) & 1;
      if (chunk < 7) LOADA(nxt, chunk + 1);
      #pragma unroll
      for (int n = 0; n < 4; ++n) {
        bf16x8 bh = *(const bf16x8*)&Bh[p & 1][c][n][lane][0];
        bf16x8 bl = *(const bf16x8*)&Bl[p & 1][c][n][lane][0];
        #pragma unroll
        for (int mi = 0; mi < 2; ++mi) {
          acc[mi][n] = __builtin_amdgcn_mfma_f32_16x16x32_bf16(Ah[cur][mi], bh, acc[mi][n], 0, 0, 0);
          acc[mi][n] = __builtin_amdgcn_mfma_f32_16x16x32_bf16(Al[cur][mi], bh, acc[mi][n], 0, 0, 0);
          acc[mi][n] = __builtin_amdgcn_mfma_f32_16x16x32_bf16(Ah[cur][mi], bl, acc[mi][n], 0, 0, 0);
        }
      }
    }
    if (p < 3) WRITEP((p + 1) & 1);
    __syncthreads();
  }
  #undef LOADP
  #undef WRITEP
  #undef LOADA
  int rg = lane >> 4, cidx = lane & 15;
  #pragma unroll
  for (int mi = 0; mi < 2; ++mi) {
    int bbase = (w * 2 + mi) * 16 + rg * 4;
    #pragma unroll
    for (int n = 0; n < 4; ++n) {
      #pragma unroll
      for (int r = 0; r < 4; ++r) {
        M[((size_t)z * 256 + bbase + r) * 4096 + lr0 + n * 16 + cidx] = acc[mi][n][r];
      }
    }
  }
}

__global__ __launch_bounds__(256) void k_psi_chain(const float* __restrict__ M,
                                                   const float* __restrict__ vpx,
                                                   const float* __restrict__ psi_first,
                                                   const float* __restrict__ psi_last,
                                                   float* __restrict__ vpsi,
                                                   float* __restrict__ psiv,
                                                   int nS, int isFirst, int isLast) {
  int b = blockIdx.x;
  int t = threadIdx.x;
  int r = t & 63, g = t >> 6;
  __shared__ float v[64];
  __shared__ float part[4][64];
  __shared__ float red[256];
  if (isFirst) {
    const float* u0 = vpx + (size_t)b * 256;
    float s0 = 0.f;
    for (int p = g * 64; p < g * 64 + 64; ++p) s0 += psi_first[r * 256 + p] * u0[p];
    part[g][r] = s0;
    __syncthreads();
    if (g == 0) v[r] = part[0][r] + part[1][r] + part[2][r] + part[3][r];
    __syncthreads();
  } else {
    if (g == 0) v[r] = vpsi[b * 64 + r];
    __syncthreads();
  }
  for (int sc = 0; sc < nS; ++sc) {
    const float* Mb = M + ((size_t)sc * 256 + b) * 4096;
    float sum = 0.f;
    #pragma unroll
    for (int j = 0; j < 16; ++j) {
      int l = g * 16 + j;
      sum += v[l] * Mb[l * 64 + r];
    }
    part[g][r] = sum;
    __syncthreads();
    if (g == 0) v[r] = part[0][r] + part[1][r] + part[2][r] + part[3][r];
    __syncthreads();
  }
  if (isLast) {
    float qv = 0.f;
    for (int l = 0; l < 64; ++l) qv += v[l] * psi_last[l * 256 + t];
    red[t] = qv * vpx[((size_t)63 * 256 + b) * 256 + t];
    __syncthreads();
    for (int off = 128; off > 0; off >>= 1) {
      if (t < off) red[t] += red[t + off];
      __syncthreads();
    }
    if (t == 0) psiv[b] = red[0];
  } else {
    if (g == 0) vpsi[b * 64 + r] = v[r];
  }
}

__device__ __forceinline__ void phi_chain_body(const float* __restrict__ slices,
                                               const float* __restrict__ phi_first,
                                               const float* __restrict__ phi_last,
                                               float* __restrict__ phiv) {
  int t = threadIdx.x;
  int r = t & 63, g = t >> 6;
  __shared__ float u[64];
  __shared__ float part[4][64];
  __shared__ float red[64];
  if (t < 64) u[t] = phi_first[t * 64];
  __syncthreads();
  for (int i = 0; i < 62; ++i) {
    float sum = 0.f;
    #pragma unroll
    for (int j = 0; j < 16; ++j) {
      int l = g * 16 + j;
      sum += u[l] * slices[(size_t)i * 4096 + l * 64 + r];
    }
    part[g][r] = sum;
    __syncthreads();
    if (g == 0) u[r] = part[0][r] + part[1][r] + part[2][r] + part[3][r];
    __syncthreads();
  }
  if (t < 64) red[t] = u[t] * phi_last[t * 64 + 63];
  __syncthreads();
  if (t == 0) {
    float s = 0.f;
    for (int l = 0; l < 64; ++l) s += red[l];
    *phiv = s;
  }
}

__global__ __launch_bounds__(256) void k_phi_chain(const float* __restrict__ slices,
                                                   const float* __restrict__ phi_first,
                                                   const float* __restrict__ phi_last,
                                                   float* __restrict__ phiv) {
  phi_chain_body(slices, phi_first, phi_last, phiv);
}

__global__ __launch_bounds__(256) void k_chi_gemm(const float* __restrict__ chi_mid,
                                                  const float* __restrict__ vch,
                                                  float* __restrict__ Tc, int s0,
                                                  int phiBlock,
                                                  const float* __restrict__ slices,
                                                  const float* __restrict__ phi_first,
                                                  const float* __restrict__ phi_last,
                                                  float* __restrict__ phiv) {
  if ((int)blockIdx.x == phiBlock) {
    if (blockIdx.y == 0) phi_chain_body(slices, phi_first, phi_last, phiv);
    return;
  }
  int z = blockIdx.x;
  int s = s0 + z;
  int b0 = blockIdx.y * 32;
  int t = threadIdx.x;
  __shared__ float uv[32][16];
  if (t < 128) {
    int idx = t * 4;
    int b = idx >> 4, c = idx & 15;
    *(float4*)&uv[b][c] = *(const float4*)(vch + ((size_t)(s + 1) * 256 + b0 + b) * 16 + c);
  }
  __syncthreads();
  #pragma unroll
  for (int k = 0; k < 4; ++k) {
    int idx = t + k * 256;
    int r = idx >> 5, l = idx & 31;
    const float* Wp = chi_mid + ((size_t)s * 1024 + l * 32 + r) * 16;
    float4 w0 = *(const float4*)(Wp);
    float4 w1 = *(const float4*)(Wp + 4);
    float4 w2 = *(const float4*)(Wp + 8);
    float4 w3 = *(const float4*)(Wp + 12);
    for (int b = 0; b < 32; ++b) {
      const float* u = uv[b];
      float d = w0.x * u[0] + w0.y * u[1] + w0.z * u[2] + w0.w * u[3]
              + w1.x * u[4] + w1.y * u[5] + w1.z * u[6] + w1.w * u[7]
              + w2.x * u[8] + w2.y * u[9] + w2.z * u[10] + w2.w * u[11]
              + w3.x * u[12] + w3.y * u[13] + w3.z * u[14] + w3.w * u[15];
      Tc[((size_t)z * 256 + b0 + b) * 1024 + idx] = d;
    }
  }
}

__global__ __launch_bounds__(64) void k_chi_chain(const float* __restrict__ Tc,
                                                  const float* __restrict__ chi_first,
                                                  const float* __restrict__ chi_last,
                                                  const float* __restrict__ vch,
                                                  const float* __restrict__ psiv,
                                                  const float* __restrict__ phiv,
                                                  float* __restrict__ vchi,
                                                  float* __restrict__ out,
                                                  int nS, int isFirst, int isLast) {
  int b = blockIdx.x;
  int lane = threadIdx.x;
  int r = lane & 31, h = lane >> 5;
  __shared__ float v[32];
  if (isFirst) {
    if (h == 0) {
      const float* u0 = vch + (size_t)b * 16;
      const float* cf = chi_first + r * 16;
      float s0 = 0.f;
      #pragma unroll
      for (int c = 0; c < 16; ++c) s0 += cf[c] * u0[c];
      v[r] = s0;
    }
  } else {
    if (h == 0) v[r] = vchi[b * 32 + r];
  }
  __syncthreads();
  for (int sc = 0; sc < nS; ++sc) {
    const float* Mb = Tc + ((size_t)sc * 256 + b) * 1024 + r * 32 + h * 16;
    float4 m0 = *(const float4*)(Mb);
    float4 m1 = *(const float4*)(Mb + 4);
    float4 m2 = *(const float4*)(Mb + 8);
    float4 m3 = *(const float4*)(Mb + 12);
    const float* vv = &v[h * 16];
    float sum = m0.x * vv[0] + m0.y * vv[1] + m0.z * vv[2] + m0.w * vv[3]
              + m1.x * vv[4] + m1.y * vv[5] + m1.z * vv[6] + m1.w * vv[7]
              + m2.x * vv[8] + m2.y * vv[9] + m2.z * vv[10] + m2.w * vv[11]
              + m3.x * vv[12] + m3.y * vv[13] + m3.z * vv[14] + m3.w * vv[15];
    sum += __shfl_xor(sum, 32);
    __syncthreads();
    if (h == 0) v[r] = sum;
    __syncthreads();
  }
  if (isLast) {
    const float* u63 = vch + ((size_t)63 * 256 + b) * 16;
    float uc[16];
    #pragma unroll
    for (int c = 0; c < 16; ++c) uc[c] = u63[c];
    float scale = 0.5f * psiv[b] * phiv[0];
    for (int o = 0; o < 10; ++o) {
      const float* cl = chi_last + r * 16 * 10 + o;
      float w = 0.f;
      #pragma unroll
      for (int c = 0; c < 16; ++c) w += cl[c * 10] * uc[c];
      float p = v[r] * w;
      #pragma unroll
      for (int m = 32; m > 0; m >>= 1) p += __shfl_xor(p, m);
      if (lane == 0) out[b * 10 + o] = p * scale;
    }
  } else {
    if (h == 0) vchi[b * 32 + r] = v[r];
  }
}

__global__ __launch_bounds__(256) void k_chi_fused(const float* __restrict__ chi_first,
                                                   const float* __restrict__ chi_mid,
                                                   const float* __restrict__ chi_last,
                                                   const float* __restrict__ vch,
                                                   const float* __restrict__ psiv,
                                                   const float* __restrict__ phiv,
                                                   float* __restrict__ out) {
  int t = threadIdx.x;
  int bl = t >> 6, lg = (t >> 5) & 1, r = t & 31;
  int b = blockIdx.x * 4 + bl;
  __shared__ float v[4][32];
  __shared__ float part[4][2][32];
  if (lg == 0) {
    const float* u0 = vch + (size_t)b * 16;
    float s0 = 0.f;
    #pragma unroll
    for (int c = 0; c < 16; ++c) s0 += chi_first[r * 16 + c] * u0[c];
    v[bl][r] = s0;
  }
  __syncthreads();
  for (int s = 0; s < 62; ++s) {
    const float* u = vch + ((size_t)(s + 1) * 256 + b) * 16;
    float uc[16];
    #pragma unroll
    for (int c = 0; c < 16; ++c) uc[c] = u[c];
    const float* W = chi_mid + (size_t)s * 32 * 32 * 16;
    float sum = 0.f;
    #pragma unroll
    for (int j = 0; j < 16; ++j) {
      int l = lg * 16 + j;
      const float* Wl = W + ((size_t)l * 32 + r) * 16;
      float tt = 0.f;
      #pragma unroll
      for (int c = 0; c < 16; ++c) tt += Wl[c] * uc[c];
      sum += v[bl][l] * tt;
    }
    part[bl][lg][r] = sum;
    __syncthreads();
    if (lg == 0) v[bl][r] = part[bl][0][r] + part[bl][1][r];
    __syncthreads();
  }
  const float* u63 = vch + ((size_t)63 * 256 + b) * 16;
  float uc[16];
  #pragma unroll
  for (int c = 0; c < 16; ++c) uc[c] = u63[c];
  if (r < 10) {
    float acc = 0.f;
    #pragma unroll
    for (int j = 0; j < 16; ++j) {
      int l = lg * 16 + j;
      const float* cl = chi_last + (size_t)l * 16 * 10;
      float tt = 0.f;
      #pragma unroll
      for (int c = 0; c < 16; ++c) tt += cl[c * 10 + r] * uc[c];
      acc += v[bl][l] * tt;
    }
    part[bl][lg][r] = acc;
  }
  __syncthreads();
  if (lg == 0 && r < 10)
    out[b * 10 + r] = (part[bl][0][r] + part[bl][1][r]) * psiv[b] * phiv[0];
}

__global__ __launch_bounds__(256) void k_psi_direct(const float* __restrict__ x,
                                                    const float* __restrict__ psi_mid,
                                                    const float* __restrict__ psi_first,
                                                    const float* __restrict__ psi_last,
                                                    float* __restrict__ psiv) {
  int b = blockIdx.x;
  int t = threadIdx.x;
  int r = t & 63, g = t >> 6;
  __shared__ float u[256];
  __shared__ float v[64];
  __shared__ float part[4][64];
  __shared__ float red[256];
  const float* xb = x + ((size_t)b << 18);
  {
    const float* rw = xb + (size_t)0 * 4096 + t * 16;
    float sm = 0.f;
    #pragma unroll
    for (int c = 0; c < 16; ++c) sm += rw[c];
    u[t] = sm * (1.0f / 16.0f);
  }
  __syncthreads();
  {
    float s0 = 0.f;
    for (int p = g * 64; p < g * 64 + 64; ++p) s0 += psi_first[r * 256 + p] * u[p];
    part[g][r] = s0;
    __syncthreads();
    if (g == 0) v[r] = part[0][r] + part[1][r] + part[2][r] + part[3][r];
  }
  __syncthreads();
  for (int s = 0; s < 62; ++s) {
    __syncthreads();
    {
      const float* rw = xb + (size_t)(s + 1) * 4096 + t * 16;
      float sm = 0.f;
      #pragma unroll
      for (int c = 0; c < 16; ++c) sm += rw[c];
      u[t] = sm * (1.0f / 16.0f);
    }
    __syncthreads();
    const float* W = psi_mid + (size_t)s * 4096 * 256;
    float sum = 0.f;
    for (int l = 0; l < 64; ++l) {
      const float* Wl = W + ((size_t)(l * 64 + r)) * 256 + g * 64;
      float tt = 0.f;
      #pragma unroll 8
      for (int k = 0; k < 64; ++k) tt += Wl[k] * u[g * 64 + k];
      sum += v[l] * tt;
    }
    part[g][r] = sum;
    __syncthreads();
    if (g == 0) v[r] = part[0][r] + part[1][r] + part[2][r] + part[3][r];
    __syncthreads();
  }
  __syncthreads();
  {
    const float* rw = xb + (size_t)63 * 4096 + t * 16;
    float sm = 0.f;
    #pragma unroll
    for (int c = 0; c < 16; ++c) sm += rw[c];
    u[t] = sm * (1.0f / 16.0f);
  }
  __syncthreads();
  float qv = 0.f;
  for (int l = 0; l < 64; ++l) qv += v[l] * psi_last[l * 256 + t];
  red[t] = qv * u[t];
  __syncthreads();
  for (int off = 128; off > 0; off >>= 1) {
    if (t < off) red[t] += red[t + off];
    __syncthreads();
  }
  if (t == 0) psiv[b] = red[0];
}

// ---------------------------------------------------------------------------
extern "C" void kernel_launch(void* const* d_in, const int* in_sizes, int n_in,
                              void* d_out, int out_size, void* d_ws, size_t ws_size,
                              hipStream_t stream) {
  const float* x         = (const float*)d_in[0];
  const float* chi_first = (const float*)d_in[1];
  const float* chi_mid   = (const float*)d_in[2];
  const float* chi_last  = (const float*)d_in[3];
  const float* psi_first = (const float*)d_in[4];
  const float* psi_mid   = (const float*)d_in[5];
  const float* psi_last  = (const float*)d_in[6];
  const float* phi_first = (const float*)d_in[7];
  const float* phi_mid   = (const float*)d_in[8];
  const float* phi_last  = (const float*)d_in[9];
  float* out = (float*)d_out;
  float* ws  = (float*)d_ws;

  size_t wsf = ws_size / 4;
  size_t off = 0;
  float* vch    = ws + off; off += (size_t)64 * 256 * 16;     // 262144
  float* psiv   = ws + off; off += 256;
  float* chiout = ws + off; off += 2560;
  float* phisl  = ws + off; off += (size_t)62 * 64 * 64;      // 253952
  float* phiv   = ws + off; off += 16;
  float* vpsi   = ws + off; off += (size_t)64 * 256;          // 16384
  float* vchi   = ws + off; off += (size_t)32 * 256;          // 8192
  float* vpx    = ws + off; off += (size_t)64 * 256 * 256;    // 4194304
  unsigned short* vpxf_hi = (unsigned short*)(ws + off); off += (size_t)64 * 65536 / 2;
  unsigned short* vpxf_lo = (unsigned short*)(ws + off); off += (size_t)64 * 65536 / 2;
  float* Mbuf   = ws + off;
  size_t mfloats = (wsf > off) ? (wsf - off) : 0;
  size_t needM  = (size_t)62 * 256 * 4096;                    // 65,011,712
  size_t needTc = (size_t)62 * 256 * 1024;                    // 16,252,928
  float* Tcbuf  = Mbuf + needM;

  if (mfloats >= needM + needTc) {
    // ===== Overlapped path: 4 dispatches =====
    k_reduce_x<<<16384 + 62, 256, 0, stream>>>(x, vch, vpx, vpxf_hi, vpxf_lo,
                                               phi_mid, phisl);
    k_mega_gemm<<<4465, 512, 0, stream>>>(psi_mid, vpxf_hi, vpxf_lo, Mbuf,
                                          chi_mid, vch, Tcbuf,
                                          phisl, phi_first, phi_last, phiv);
    k_mega_chain<<<128, 256, 0, stream>>>(Mbuf, Tcbuf, vpx, vch,
                                          psi_first, psi_last,
                                          chi_first, chi_last, psiv, chiout);
    k_combine<<<10, 256, 0, stream>>>(chiout, psiv, phiv, out);
  } else {
    int C = (int)(mfloats / ((size_t)256 * 4096));
    if (C > 62) C = 62;
    int Cc = (int)(mfloats / ((size_t)256 * 1024));
    if (Cc > 62) Cc = 62;
    if (C >= 1) {
      k_reduce_x<<<16384 + 62, 256, 0, stream>>>(x, vch, vpx, vpxf_hi, vpxf_lo,
                                                 phi_mid, phisl);
      int done = 0;
      while (done < 62) {
        int c = imin(C, 62 - done);
        k_psi_gemm<<<dim3(64, 1, c), 512, 0, stream>>>(psi_mid, vpxf_hi, vpxf_lo, Mbuf, done);
        k_psi_chain<<<256, 256, 0, stream>>>(Mbuf, vpx, psi_first, psi_last,
                                             vpsi, psiv, c, (done == 0) ? 1 : 0,
                                             (done + c == 62) ? 1 : 0);
        done += c;
      }
      done = 0;
      while (done < 62) {
        int c = imin(Cc, 62 - done);
        int phiBlk = (done == 0) ? c : -1;
        int gx = (done == 0) ? (c + 1) : c;
        k_chi_gemm<<<dim3(gx, 8), 256, 0, stream>>>(chi_mid, vch, Mbuf, done, phiBlk,
                                                    phisl, phi_first, phi_last, phiv);
        k_chi_chain<<<256, 64, 0, stream>>>(Mbuf, chi_first, chi_last, vch,
                                            psiv, phiv, vchi, out, c,
                                            (done == 0) ? 1 : 0,
                                            (done + c == 62) ? 1 : 0);
        done += c;
      }
    } else {
      k_reduce_x<<<16384 + 62, 256, 0, stream>>>(x, vch, nullptr, nullptr, nullptr,
                                                 phi_mid, phisl);
      k_psi_direct<<<256, 256, 0, stream>>>(x, psi_mid, psi_first, psi_last, psiv);
      k_phi_chain<<<1, 256, 0, stream>>>(phisl, phi_first, phi_last, phiv);
      k_chi_fused<<<64, 256, 0, stream>>>(chi_first, chi_mid, chi_last, vch, psiv, phiv, out);
    }
  }
}

// Round 11
// 362.834 us; speedup vs baseline: 4.7985x; 1.0655x over previous
//
#include <hip/hip_runtime.h>

// dims: L=64, CH=16, PIX=256, PAT=64, RC=32, BD=64, OUT=10, B=256
// inputs: 0=x(256,64,256,16) 1=chi_first(32,16) 2=chi_mid(62,32,32,16)
// 3=chi_last(32,16,10) 4=psi_first(64,256) 5=psi_mid(62,64,64,256)
// 6=psi_last(64,256) 7=phi_first(64,64) 8=phi_mid(62,64,64,64) 9=phi_last(64,64)

static inline int imin(int a, int b) { return a < b ? a : b; }

typedef __attribute__((ext_vector_type(8))) short bf16x8;          // 8 bf16 (4 VGPR)
typedef __attribute__((ext_vector_type(8))) unsigned short us8;
typedef __attribute__((ext_vector_type(4))) float f32x4;

__device__ __forceinline__ unsigned short f2bf(float v) {
  union { float f; unsigned int u; } c; c.f = v;
  unsigned int u = c.u;
  unsigned int r = (u + 0x7fffu + ((u >> 16) & 1u)) >> 16;  // RTN-even
  return (unsigned short)r;
}
__device__ __forceinline__ float bf2f(unsigned short h) {
  union { unsigned int u; float f; } c; c.u = ((unsigned int)h) << 16;
  return c.f;
}

// ---------------------------------------------------------------------------
// K1: vpx means + bf16 hi/lo fragment emit. Fused: blocks >= 16384 do the
// phi slice gather (slices[i][l*64+r] = phi_mid[i][l][r][i+1]).
__global__ __launch_bounds__(256) void k_reduce_x(const float* __restrict__ x,
                                                  float* __restrict__ vch,
                                                  float* __restrict__ vpx,
                                                  unsigned short* __restrict__ vpxf_hi,
                                                  unsigned short* __restrict__ vpxf_lo,
                                                  const float* __restrict__ phi_mid,
                                                  float* __restrict__ slices) {
  if (blockIdx.x >= 16384) {                 // phi gather block
    int i = blockIdx.x - 16384;              // 0..61
    int t = threadIdx.x;
    #pragma unroll
    for (int k = 0; k < 16; ++k) {
      int idx = t + k * 256;                 // l*64 + r
      slices[(size_t)i * 4096 + idx] = phi_mid[((size_t)i * 4096 + idx) * 64 + (i + 1)];
    }
    return;
  }
  int bp = blockIdx.x;             // b*64 + s
  int b = bp >> 6, s = bp & 63;
  int q = threadIdx.x;             // = p
  const float* row = x + ((size_t)bp << 12) + q * 16;
  float4 r0 = *(const float4*)(row);
  float4 r1 = *(const float4*)(row + 4);
  float4 r2 = *(const float4*)(row + 8);
  float4 r3 = *(const float4*)(row + 12);
  float csum = r0.x + r0.y + r0.z + r0.w + r1.x + r1.y + r1.z + r1.w
             + r2.x + r2.y + r2.z + r2.w + r3.x + r3.y + r3.z + r3.w;
  float val = csum * (1.0f / 16.0f);
  if (vpx && (s == 0 || s == 63)) vpx[((size_t)s * 256 + b) * 256 + q] = val;
  if (vpxf_hi && s >= 1 && s <= 62) {
    unsigned short hb = f2bf(val);
    unsigned short lb = f2bf(val - bf2f(hb));
    size_t fa = (size_t)s * 65536
              + (((size_t)(q >> 5) * 16 + (b >> 4)) * 64 + (((q >> 3) & 3) * 16 + (b & 15))) * 8
              + (q & 7);
    vpxf_hi[fa] = hb;
    vpxf_lo[fa] = lb;
  }

  __shared__ float sc[256][20];
  *(float4*)&sc[q][0]  = r0;
  *(float4*)&sc[q][4]  = r1;
  *(float4*)&sc[q][8]  = r2;
  *(float4*)&sc[q][12] = r3;
  __syncthreads();
  int c = q & 15, g = q >> 4;
  float ps = 0.f;
  #pragma unroll
  for (int k = 0; k < 16; ++k) ps += sc[g * 16 + k][c];
  __shared__ float p2[16][17];
  p2[g][c] = ps;
  __syncthreads();
  if (q < 16) {
    float s2 = 0.f;
    #pragma unroll
    for (int k = 0; k < 16; ++k) s2 += p2[k][q];
    vch[((size_t)s * 256 + b) * 16 + q] = s2 * (1.0f / 256.0f);
  }
}

// ---------------------------------------------------------------------------
// MEGA GEMM (512 threads): bx<3968 psi MFMA gemm; 3968<=bx<4464 chi gemm;
// bx==4464 phi chain. r11: LDS transpose epilogue for 256B-coalesced M stores
// (aliases the dead Bh/Bl 32 KB, no LDS growth -> occupancy preserved).
__global__ __launch_bounds__(512) void k_mega_gemm(const float* __restrict__ psi_mid,
                                                   const unsigned short* __restrict__ vpxf_hi,
                                                   const unsigned short* __restrict__ vpxf_lo,
                                                   float* __restrict__ M,
                                                   const float* __restrict__ chi_mid,
                                                   const float* __restrict__ vch,
                                                   float* __restrict__ Tc,
                                                   const float* __restrict__ slices,
                                                   const float* __restrict__ phi_first,
                                                   const float* __restrict__ phi_last,
                                                   float* __restrict__ phiv) {
  int bx = blockIdx.x;
  int t = threadIdx.x;
  if (bx < 3968) {
    // ---------------- psi MFMA gemm: site z, lr-block ----------------
    int z = bx >> 6;
    int lr0 = (bx & 63) * 64;
    const float* W = psi_mid + (size_t)z * 4096 * 256;
    const unsigned short* Ahg = vpxf_hi + (size_t)(z + 1) * 65536;
    const unsigned short* Alg = vpxf_lo + (size_t)(z + 1) * 65536;
    __shared__ __align__(16) unsigned char smem[32768];   // Bh+Bl, reused as T
    typedef unsigned short BArr[2][2][4][64][8];          // 16 KB each
    BArr& Bh = *reinterpret_cast<BArr*>(smem);
    BArr& Bl = *reinterpret_cast<BArr*>(smem + 16384);
    int lane = t & 63, w = t >> 6;
    int row = t >> 3, kg = t & 7;
    float4 sv0, sv1;

    #define LOADP(p) do {                                                      \
      const float* src = W + (size_t)(lr0 + row) * 256 + ((p) << 6) + kg * 8;  \
      sv0 = *(const float4*)src;                                               \
      sv1 = *(const float4*)(src + 4);                                         \
    } while (0)
    #define WRITEP(d) do {                                                     \
      float xs[8] = {sv0.x, sv0.y, sv0.z, sv0.w, sv1.x, sv1.y, sv1.z, sv1.w};  \
      us8 hv, lv;                                                              \
      _Pragma("unroll")                                                        \
      for (int i = 0; i < 8; ++i) {                                            \
        unsigned short hb = f2bf(xs[i]);                                       \
        hv[i] = hb;                                                            \
        lv[i] = f2bf(xs[i] - bf2f(hb));                                        \
      }                                                                        \
      int ck = kg >> 2, nt = row >> 4, ln = ((kg & 3) << 4) | (row & 15);      \
      *(us8*)&Bh[d][ck][nt][ln][0] = hv;                                       \
      *(us8*)&Bl[d][ck][nt][ln][0] = lv;                                       \
    } while (0)
    #define LOADA(slot, chunk) do {                                            \
      _Pragma("unroll")                                                        \
      for (int mi = 0; mi < 2; ++mi) {                                         \
        size_t fo = ((size_t)(chunk) * 16 + (w * 2 + mi)) * 512 + (size_t)lane * 8; \
        Ah[slot][mi] = *(const bf16x8*)(Ahg + fo);                             \
        Al[slot][mi] = *(const bf16x8*)(Alg + fo);                             \
      }                                                                        \
    } while (0)

    f32x4 acc[2][4];
    #pragma unroll
    for (int i = 0; i < 2; ++i)
      #pragma unroll
      for (int j = 0; j < 4; ++j) acc[i][j] = (f32x4){0.f, 0.f, 0.f, 0.f};
    bf16x8 Ah[2][2], Al[2][2];

    LOADA(0, 0);
    LOADP(0);
    WRITEP(0);
    __syncthreads();
    #pragma unroll
    for (int p = 0; p < 4; ++p) {
      if (p < 3) LOADP(p + 1);
      #pragma unroll
      for (int c = 0; c < 2; ++c) {
        const int chunk = p * 2 + c;
        const int cur = chunk & 1, nxt = (chunk + 1) & 1;
        if (chunk < 7) LOADA(nxt, chunk + 1);
        #pragma unroll
        for (int n = 0; n < 4; ++n) {
          bf16x8 bh = *(const bf16x8*)&Bh[p & 1][c][n][lane][0];
          bf16x8 bl = *(const bf16x8*)&Bl[p & 1][c][n][lane][0];
          #pragma unroll
          for (int mi = 0; mi < 2; ++mi) {
            acc[mi][n] = __builtin_amdgcn_mfma_f32_16x16x32_bf16(Ah[cur][mi], bh, acc[mi][n], 0, 0, 0);
            acc[mi][n] = __builtin_amdgcn_mfma_f32_16x16x32_bf16(Al[cur][mi], bh, acc[mi][n], 0, 0, 0);
            acc[mi][n] = __builtin_amdgcn_mfma_f32_16x16x32_bf16(Ah[cur][mi], bl, acc[mi][n], 0, 0, 0);
          }
        }
      }
      if (p < 3) WRITEP((p + 1) & 1);
      __syncthreads();
    }
    #undef LOADP
    #undef WRITEP
    #undef LOADA

    // ---- transpose epilogue: acc -> LDS T[128][64] -> 256B-coalesced stores
    // pass 0: waves 0-3 (b 0..127); pass 1: waves 4-7 (b 128..255).
    int rg = lane >> 4, cidx = lane & 15;
    float (*T)[64] = reinterpret_cast<float (*)[64]>(smem);   // 32 KB
    #pragma unroll
    for (int pass = 0; pass < 2; ++pass) {
      if ((w >> 2) == pass) {
        #pragma unroll
        for (int mi = 0; mi < 2; ++mi) {
          int rowb = (((w & 3) * 2 + mi) * 16) + rg * 4;
          #pragma unroll
          for (int n = 0; n < 4; ++n) {
            #pragma unroll
            for (int r = 0; r < 4; ++r) {
              T[rowb + r][n * 16 + cidx] = acc[mi][n][r];
            }
          }
        }
      }
      __syncthreads();
      int boff = pass * 128;
      #pragma unroll
      for (int k = 0; k < 4; ++k) {
        int f = t + k * 512;            // float4 unit 0..2047
        int b2 = f >> 4;                // 0..127
        int l4 = (f & 15) * 4;          // 0..60
        *(float4*)(M + ((size_t)z * 256 + boff + b2) * 4096 + lr0 + l4) =
            *(const float4*)&T[b2][l4];
      }
      __syncthreads();
    }
  } else if (bx < 4464) {
    // ---------------- chi gemm: Tc[z][b][r*32+l] ----------------
    int i = bx - 3968;
    int z = i >> 3;                 // site 0..61
    int b0 = (i & 7) * 32;
    __shared__ float uv[32][16];
    if (t < 128) {
      int idx = t * 4;
      int b = idx >> 4, c = idx & 15;
      *(float4*)&uv[b][c] = *(const float4*)(vch + ((size_t)(z + 1) * 256 + b0 + b) * 16 + c);
    }
    __syncthreads();
    #pragma unroll
    for (int k = 0; k < 2; ++k) {
      int idx = t + k * 512;         // output index = r*32 + l
      int r = idx >> 5, l = idx & 31;
      const float* Wp = chi_mid + ((size_t)z * 1024 + l * 32 + r) * 16;
      float4 w0 = *(const float4*)(Wp);
      float4 w1 = *(const float4*)(Wp + 4);
      float4 w2 = *(const float4*)(Wp + 8);
      float4 w3 = *(const float4*)(Wp + 12);
      for (int b = 0; b < 32; ++b) {
        const float* u = uv[b];
        float d = w0.x * u[0] + w0.y * u[1] + w0.z * u[2] + w0.w * u[3]
                + w1.x * u[4] + w1.y * u[5] + w1.z * u[6] + w1.w * u[7]
                + w2.x * u[8] + w2.y * u[9] + w2.z * u[10] + w2.w * u[11]
                + w3.x * u[12] + w3.y * u[13] + w3.z * u[14] + w3.w * u[15];
        Tc[((size_t)z * 256 + b0 + b) * 1024 + idx] = d;
      }
    }
  } else {
    // ---------------- phi chain (512-thread version, barriered) ----------------
    int r = t & 63, g = t >> 6;      // g = 0..7, 8 l's each
    __shared__ float u[64];
    __shared__ float part[8][64];
    __shared__ float red[64];
    if (t < 64) u[t] = phi_first[t * 64];
    __syncthreads();
    for (int i2 = 0; i2 < 62; ++i2) {
      float sum = 0.f;
      #pragma unroll
      for (int j = 0; j < 8; ++j) {
        int l = g * 8 + j;
        sum += u[l] * slices[(size_t)i2 * 4096 + l * 64 + r];
      }
      part[g][r] = sum;
      __syncthreads();
      if (g == 0) u[r] = part[0][r] + part[1][r] + part[2][r] + part[3][r]
                       + part[4][r] + part[5][r] + part[6][r] + part[7][r];
      __syncthreads();
    }
    if (t < 64) red[t] = u[t] * phi_last[t * 64 + 63];
    __syncthreads();
    if (t == 0) {
      float s = 0.f;
      for (int l = 0; l < 64; ++l) s += red[l];
      *phiv = s;
    }
  }
}

// ---------------------------------------------------------------------------
// MEGA CHAIN r11: grid 512 x 64 threads, ONE b per block (full-CU spread;
// r10 used 128 blocks = half the CUs). bx<256 psi chains; bx>=256 chi chains.
// Pure register+shfl chains with batch-load/compute split + 2-deep prefetch
// (r9 lesson: interleaved loads serialize on HBM latency).
__global__ __launch_bounds__(64) void k_mega_chain(const float* __restrict__ M,
                                                   const float* __restrict__ Tc,
                                                   const float* __restrict__ vpx,
                                                   const float* __restrict__ vch,
                                                   const float* __restrict__ psi_first,
                                                   const float* __restrict__ psi_last,
                                                   const float* __restrict__ chi_first,
                                                   const float* __restrict__ chi_last,
                                                   float* __restrict__ psiv,
                                                   float* __restrict__ chiout) {
  int bx = blockIdx.x;
  int lane = threadIdx.x;
  if (bx < 256) {
    // -------- psi: lane holds v[lane]; batch-load + shfl-reduce steps --------
    int b = bx;
    float v;
    {
      const float* u0 = vpx + (size_t)b * 256;   // site 0
      const float* pf = psi_first + lane * 256;
      float s0 = 0.f, s1 = 0.f, s2 = 0.f, s3 = 0.f;
      for (int p = 0; p < 256; p += 4) {
        s0 += pf[p] * u0[p];   s1 += pf[p + 1] * u0[p + 1];
        s2 += pf[p + 2] * u0[p + 2]; s3 += pf[p + 3] * u0[p + 3];
      }
      v = (s0 + s1) + (s2 + s3);
    }
    #define MLOAD(buf, sc) do {                                                \
      const float* Mb = M + ((size_t)(sc) * 256 + b) * 4096 + lane;            \
      _Pragma("unroll")                                                        \
      for (int l = 0; l < 64; ++l) buf[l] = Mb[(size_t)l * 64];                \
    } while (0)
    #define MSTEP(buf) do {                                                    \
      float s0 = 0.f, s1 = 0.f, s2 = 0.f, s3 = 0.f;                            \
      _Pragma("unroll")                                                        \
      for (int l = 0; l < 16; ++l) {                                           \
        s0 += __shfl(v, 4 * l + 0) * buf[4 * l + 0];                           \
        s1 += __shfl(v, 4 * l + 1) * buf[4 * l + 1];                           \
        s2 += __shfl(v, 4 * l + 2) * buf[4 * l + 2];                           \
        s3 += __shfl(v, 4 * l + 3) * buf[4 * l + 3];                           \
      }                                                                        \
      v = (s0 + s1) + (s2 + s3);                                               \
    } while (0)
    {
      float mvA[64], mvB[64];
      MLOAD(mvA, 0);
      #pragma unroll 1
      for (int sc = 0; sc < 62; sc += 2) {      // 62 even: pairs complete
        MLOAD(mvB, sc + 1);
        MSTEP(mvA);
        if (sc + 2 < 62) MLOAD(mvA, sc + 2);
        MSTEP(mvB);
      }
    }
    #undef MLOAD
    #undef MSTEP
    // epilogue: psi_val[b] = sum_p (sum_l v[l] psi_last[l][p]) * vpx[63][b][p]
    float acc_p = 0.f;
    #pragma unroll
    for (int pp = 0; pp < 4; ++pp) {
      int p = pp * 64 + lane;
      float pl[64];
      #pragma unroll
      for (int l = 0; l < 64; ++l) pl[l] = psi_last[l * 256 + p];
      float s0 = 0.f, s1 = 0.f, s2 = 0.f, s3 = 0.f;
      #pragma unroll
      for (int l = 0; l < 16; ++l) {
        s0 += __shfl(v, 4 * l + 0) * pl[4 * l + 0];
        s1 += __shfl(v, 4 * l + 1) * pl[4 * l + 1];
        s2 += __shfl(v, 4 * l + 2) * pl[4 * l + 2];
        s3 += __shfl(v, 4 * l + 3) * pl[4 * l + 3];
      }
      float wv = (s0 + s1) + (s2 + s3);
      acc_p += wv * vpx[((size_t)63 * 256 + b) * 256 + p];
    }
    #pragma unroll
    for (int m = 32; m > 0; m >>= 1) acc_p += __shfl_xor(acc_p, m);
    if (lane == 0) psiv[b] = acc_p;
  } else {
    // -------- chi: lane (r,h) holds v[r] duplicated across halves --------
    int b = bx - 256;
    int r = lane & 31, h = lane >> 5;
    float v;
    {
      const float* u0 = vch + (size_t)b * 16;    // site 0
      const float* cf = chi_first + r * 16;
      float s0 = 0.f;
      #pragma unroll
      for (int c = 0; c < 16; ++c) s0 += cf[c] * u0[c];
      v = s0;                                    // same in both halves
    }
    #define CLOADX(buf, sc) do {                                               \
      const float* Mb = Tc + ((size_t)(sc) * 256 + b) * 1024 + r * 32 + h * 16; \
      *(float4*)&buf[0]  = *(const float4*)(Mb);                               \
      *(float4*)&buf[4]  = *(const float4*)(Mb + 4);                           \
      *(float4*)&buf[8]  = *(const float4*)(Mb + 8);                           \
      *(float4*)&buf[12] = *(const float4*)(Mb + 12);                          \
    } while (0)
    #define CSTEPX(buf) do {                                                   \
      float s0 = 0.f, s1 = 0.f;                                                \
      _Pragma("unroll")                                                        \
      for (int j = 0; j < 8; ++j) {                                            \
        s0 += __shfl(v, h * 16 + 2 * j)     * buf[2 * j];                      \
        s1 += __shfl(v, h * 16 + 2 * j + 1) * buf[2 * j + 1];                  \
      }                                                                        \
      float sum = s0 + s1;                                                     \
      sum += __shfl_xor(sum, 32);                                              \
      v = sum;                                                                 \
    } while (0)
    {
      float mjA[16], mjB[16];
      CLOADX(mjA, 0);
      #pragma unroll 1
      for (int sc = 0; sc < 62; sc += 2) {
        CLOADX(mjB, sc + 1);
        CSTEPX(mjA);
        if (sc + 2 < 62) CLOADX(mjA, sc + 2);
        CSTEPX(mjB);
      }
    }
    #undef CLOADX
    #undef CSTEPX
    // epilogue: chiout[b][o] raw (psiv/phiv applied in k_combine)
    const float* u63 = vch + ((size_t)63 * 256 + b) * 16;
    float uc[16];
    #pragma unroll
    for (int c = 0; c < 16; ++c) uc[c] = u63[c];
    for (int o = 0; o < 10; ++o) {
      const float* cl = chi_last + r * 16 * 10 + o;
      float wv = 0.f;
      #pragma unroll
      for (int c = 0; c < 16; ++c) wv += cl[c * 10] * uc[c];
      float p = v * wv;                          // duplicated across halves
      #pragma unroll
      for (int m = 32; m > 0; m >>= 1) p += __shfl_xor(p, m);
      if (lane == 0) chiout[b * 10 + o] = p * 0.5f;
    }
  }
}

// ---------------------------------------------------------------------------
// K6: out[b][o] = chiout[b][o] * psiv[b] * phiv
__global__ __launch_bounds__(256) void k_combine(const float* __restrict__ chiout,
                                                 const float* __restrict__ psiv,
                                                 const float* __restrict__ phiv,
                                                 float* __restrict__ out) {
  int t = blockIdx.x * 256 + threadIdx.x;
  if (t < 2560) {
    int b = t / 10;
    out[t] = chiout[t] * psiv[b] * phiv[0];
  }
}

// ---------------------------------------------------------------------------
// ===== Fallback tier (smaller workspace): r7 chunked pipeline, barriered =====
__global__ __launch_bounds__(512) void k_psi_gemm(const float* __restrict__ psi_mid,
                                                  const unsigned short* __restrict__ vpxf_hi,
                                                  const unsigned short* __restrict__ vpxf_lo,
                                                  float* __restrict__ M, int s0) {
  int z = blockIdx.z;
  int s = s0 + z;
  int lr0 = blockIdx.x * 64;
  const float* W = psi_mid + (size_t)s * 4096 * 256;
  const unsigned short* Ahg = vpxf_hi + (size_t)(s + 1) * 65536;
  const unsigned short* Alg = vpxf_lo + (size_t)(s + 1) * 65536;
  __shared__ unsigned short Bh[2][2][4][64][8];
  __shared__ unsigned short Bl[2][2][4][64][8];
  int t = threadIdx.x;
  int lane = t & 63, w = t >> 6;
  int row = t >> 3, kg = t & 7;
  float4 sv0, sv1;
  #define LOADP(p) do {                                                        \
    const float* src = W + (size_t)(lr0 + row) * 256 + ((p) << 6) + kg * 8;    \
    sv0 = *(const float4*)src;                                                 \
    sv1 = *(const float4*)(src + 4);                                           \
  } while (0)
  #define WRITEP(d) do {                                                       \
    float xs[8] = {sv0.x, sv0.y, sv0.z, sv0.w, sv1.x, sv1.y, sv1.z, sv1.w};    \
    us8 hv, lv;                                                                \
    _Pragma("unroll")                                                          \
    for (int i = 0; i < 8; ++i) {                                              \
      unsigned short hb = f2bf(xs[i]);                                         \
      hv[i] = hb;                                                              \
      lv[i] = f2bf(xs[i] - bf2f(hb));                                          \
    }                                                                          \
    int ck = kg >> 2, nt = row >> 4, ln = ((kg & 3) << 4) | (row & 15);        \
    *(us8*)&Bh[d][ck][nt][ln][0] = hv;                                         \
    *(us8*)&Bl[d][ck][nt][ln][0] = lv;                                         \
  } while (0)
  #define LOADA(slot, chunk) do {                                              \
    _Pragma("unroll")                                                          \
    for (int mi = 0; mi < 2; ++mi) {                                           \
      size_t fo = ((size_t)(chunk) * 16 + (w * 2 + mi)) * 512 + (size_t)lane * 8; \
      Ah[slot][mi] = *(const bf16x8*)(Ahg + fo);                               \
      Al[slot][mi] = *(const bf16x8*)(Alg + fo);                               \
    }                                                                          \
  } while (0)
  f32x4 acc[2][4];
  #pragma unroll
  for (int i = 0; i < 2; ++i)
    #pragma unroll
    for (int j = 0; j < 4; ++j) acc[i][j] = (f32x4){0.f, 0.f, 0.f, 0.f};
  bf16x8 Ah[2][2], Al[2][2];
  LOADA(0, 0);
  LOADP(0);
  WRITEP(0);
  __syncthreads();
  #pragma unroll
  for (int p = 0; p < 4; ++p) {
    if (p < 3) LOADP(p + 1);
    #pragma unroll
    for (int c = 0; c < 2; ++c) {
      const int chunk = p * 2 + c;
      const int cur = chunk & 1, nxt = (chunk + 1) & 1;
      if (chunk < 7) LOADA(nxt, chunk + 1);
      #pragma unroll
      for (int n = 0; n < 4; ++n) {
        bf16x8 bh = *(const bf16x8*)&Bh[p & 1][c][n][lane][0];
        bf16x8 bl = *(const bf16x8*)&Bl[p & 1][c][n][lane][0];
        #pragma unroll
        for (int mi = 0; mi < 2; ++mi) {
          acc[mi][n] = __builtin_amdgcn_mfma_f32_16x16x32_bf16(Ah[cur][mi], bh, acc[mi][n], 0, 0, 0);
          acc[mi][n] = __builtin_amdgcn_mfma_f32_16x16x32_bf16(Al[cur][mi], bh, acc[mi][n], 0, 0, 0);
          acc[mi][n] = __builtin_amdgcn_mfma_f32_16x16x32_bf16(Ah[cur][mi], bl, acc[mi][n], 0, 0, 0);
        }
      }
    }
    if (p < 3) WRITEP((p + 1) & 1);
    __syncthreads();
  }
  #undef LOADP
  #undef WRITEP
  #undef LOADA
  int rg = lane >> 4, cidx = lane & 15;
  #pragma unroll
  for (int mi = 0; mi < 2; ++mi) {
    int bbase = (w * 2 + mi) * 16 + rg * 4;
    #pragma unroll
    for (int n = 0; n < 4; ++n) {
      #pragma unroll
      for (int r = 0; r < 4; ++r) {
        M[((size_t)z * 256 + bbase + r) * 4096 + lr0 + n * 16 + cidx] = acc[mi][n][r];
      }
    }
  }
}

__global__ __launch_bounds__(256) void k_psi_chain(const float* __restrict__ M,
                                                   const float* __restrict__ vpx,
                                                   const float* __restrict__ psi_first,
                                                   const float* __restrict__ psi_last,
                                                   float* __restrict__ vpsi,
                                                   float* __restrict__ psiv,
                                                   int nS, int isFirst, int isLast) {
  int b = blockIdx.x;
  int t = threadIdx.x;
  int r = t & 63, g = t >> 6;
  __shared__ float v[64];
  __shared__ float part[4][64];
  __shared__ float red[256];
  if (isFirst) {
    const float* u0 = vpx + (size_t)b * 256;
    float s0 = 0.f;
    for (int p = g * 64; p < g * 64 + 64; ++p) s0 += psi_first[r * 256 + p] * u0[p];
    part[g][r] = s0;
    __syncthreads();
    if (g == 0) v[r] = part[0][r] + part[1][r] + part[2][r] + part[3][r];
    __syncthreads();
  } else {
    if (g == 0) v[r] = vpsi[b * 64 + r];
    __syncthreads();
  }
  for (int sc = 0; sc < nS; ++sc) {
    const float* Mb = M + ((size_t)sc * 256 + b) * 4096;
    float sum = 0.f;
    #pragma unroll
    for (int j = 0; j < 16; ++j) {
      int l = g * 16 + j;
      sum += v[l] * Mb[l * 64 + r];
    }
    part[g][r] = sum;
    __syncthreads();
    if (g == 0) v[r] = part[0][r] + part[1][r] + part[2][r] + part[3][r];
    __syncthreads();
  }
  if (isLast) {
    float qv = 0.f;
    for (int l = 0; l < 64; ++l) qv += v[l] * psi_last[l * 256 + t];
    red[t] = qv * vpx[((size_t)63 * 256 + b) * 256 + t];
    __syncthreads();
    for (int off = 128; off > 0; off >>= 1) {
      if (t < off) red[t] += red[t + off];
      __syncthreads();
    }
    if (t == 0) psiv[b] = red[0];
  } else {
    if (g == 0) vpsi[b * 64 + r] = v[r];
  }
}

__device__ __forceinline__ void phi_chain_body(const float* __restrict__ slices,
                                               const float* __restrict__ phi_first,
                                               const float* __restrict__ phi_last,
                                               float* __restrict__ phiv) {
  int t = threadIdx.x;
  int r = t & 63, g = t >> 6;
  __shared__ float u[64];
  __shared__ float part[4][64];
  __shared__ float red[64];
  if (t < 64) u[t] = phi_first[t * 64];
  __syncthreads();
  for (int i = 0; i < 62; ++i) {
    float sum = 0.f;
    #pragma unroll
    for (int j = 0; j < 16; ++j) {
      int l = g * 16 + j;
      sum += u[l] * slices[(size_t)i * 4096 + l * 64 + r];
    }
    part[g][r] = sum;
    __syncthreads();
    if (g == 0) u[r] = part[0][r] + part[1][r] + part[2][r] + part[3][r];
    __syncthreads();
  }
  if (t < 64) red[t] = u[t] * phi_last[t * 64 + 63];
  __syncthreads();
  if (t == 0) {
    float s = 0.f;
    for (int l = 0; l < 64; ++l) s += red[l];
    *phiv = s;
  }
}

__global__ __launch_bounds__(256) void k_phi_chain(const float* __restrict__ slices,
                                                   const float* __restrict__ phi_first,
                                                   const float* __restrict__ phi_last,
                                                   float* __restrict__ phiv) {
  phi_chain_body(slices, phi_first, phi_last, phiv);
}

__global__ __launch_bounds__(256) void k_chi_gemm(const float* __restrict__ chi_mid,
                                                  const float* __restrict__ vch,
                                                  float* __restrict__ Tc, int s0,
                                                  int phiBlock,
                                                  const float* __restrict__ slices,
                                                  const float* __restrict__ phi_first,
                                                  const float* __restrict__ phi_last,
                                                  float* __restrict__ phiv) {
  if ((int)blockIdx.x == phiBlock) {
    if (blockIdx.y == 0) phi_chain_body(slices, phi_first, phi_last, phiv);
    return;
  }
  int z = blockIdx.x;
  int s = s0 + z;
  int b0 = blockIdx.y * 32;
  int t = threadIdx.x;
  __shared__ float uv[32][16];
  if (t < 128) {
    int idx = t * 4;
    int b = idx >> 4, c = idx & 15;
    *(float4*)&uv[b][c] = *(const float4*)(vch + ((size_t)(s + 1) * 256 + b0 + b) * 16 + c);
  }
  __syncthreads();
  #pragma unroll
  for (int k = 0; k < 4; ++k) {
    int idx = t + k * 256;
    int r = idx >> 5, l = idx & 31;
    const float* Wp = chi_mid + ((size_t)s * 1024 + l * 32 + r) * 16;
    float4 w0 = *(const float4*)(Wp);
    float4 w1 = *(const float4*)(Wp + 4);
    float4 w2 = *(const float4*)(Wp + 8);
    float4 w3 = *(const float4*)(Wp + 12);
    for (int b = 0; b < 32; ++b) {
      const float* u = uv[b];
      float d = w0.x * u[0] + w0.y * u[1] + w0.z * u[2] + w0.w * u[3]
              + w1.x * u[4] + w1.y * u[5] + w1.z * u[6] + w1.w * u[7]
              + w2.x * u[8] + w2.y * u[9] + w2.z * u[10] + w2.w * u[11]
              + w3.x * u[12] + w3.y * u[13] + w3.z * u[14] + w3.w * u[15];
      Tc[((size_t)z * 256 + b0 + b) * 1024 + idx] = d;
    }
  }
}

__global__ __launch_bounds__(64) void k_chi_chain(const float* __restrict__ Tc,
                                                  const float* __restrict__ chi_first,
                                                  const float* __restrict__ chi_last,
                                                  const float* __restrict__ vch,
                                                  const float* __restrict__ psiv,
                                                  const float* __restrict__ phiv,
                                                  float* __restrict__ vchi,
                                                  float* __restrict__ out,
                                                  int nS, int isFirst, int isLast) {
  int b = blockIdx.x;
  int lane = threadIdx.x;
  int r = lane & 31, h = lane >> 5;
  __shared__ float v[32];
  if (isFirst) {
    if (h == 0) {
      const float* u0 = vch + (size_t)b * 16;
      const float* cf = chi_first + r * 16;
      float s0 = 0.f;
      #pragma unroll
      for (int c = 0; c < 16; ++c) s0 += cf[c] * u0[c];
      v[r] = s0;
    }
  } else {
    if (h == 0) v[r] = vchi[b * 32 + r];
  }
  __syncthreads();
  for (int sc = 0; sc < nS; ++sc) {
    const float* Mb = Tc + ((size_t)sc * 256 + b) * 1024 + r * 32 + h * 16;
    float4 m0 = *(const float4*)(Mb);
    float4 m1 = *(const float4*)(Mb + 4);
    float4 m2 = *(const float4*)(Mb + 8);
    float4 m3 = *(const float4*)(Mb + 12);
    const float* vv = &v[h * 16];
    float sum = m0.x * vv[0] + m0.y * vv[1] + m0.z * vv[2] + m0.w * vv[3]
              + m1.x * vv[4] + m1.y * vv[5] + m1.z * vv[6] + m1.w * vv[7]
              + m2.x * vv[8] + m2.y * vv[9] + m2.z * vv[10] + m2.w * vv[11]
              + m3.x * vv[12] + m3.y * vv[13] + m3.z * vv[14] + m3.w * vv[15];
    sum += __shfl_xor(sum, 32);
    __syncthreads();
    if (h == 0) v[r] = sum;
    __syncthreads();
  }
  if (isLast) {
    const float* u63 = vch + ((size_t)63 * 256 + b) * 16;
    float uc[16];
    #pragma unroll
    for (int c = 0; c < 16; ++c) uc[c] = u63[c];
    float scale = 0.5f * psiv[b] * phiv[0];
    for (int o = 0; o < 10; ++o) {
      const float* cl = chi_last + r * 16 * 10 + o;
      float w = 0.f;
      #pragma unroll
      for (int c = 0; c < 16; ++c) w += cl[c * 10] * uc[c];
      float p = v[r] * w;
      #pragma unroll
      for (int m = 32; m > 0; m >>= 1) p += __shfl_xor(p, m);
      if (lane == 0) out[b * 10 + o] = p * scale;
    }
  } else {
    if (h == 0) vchi[b * 32 + r] = v[r];
  }
}

__global__ __launch_bounds__(256) void k_chi_fused(const float* __restrict__ chi_first,
                                                   const float* __restrict__ chi_mid,
                                                   const float* __restrict__ chi_last,
                                                   const float* __restrict__ vch,
                                                   const float* __restrict__ psiv,
                                                   const float* __restrict__ phiv,
                                                   float* __restrict__ out) {
  int t = threadIdx.x;
  int bl = t >> 6, lg = (t >> 5) & 1, r = t & 31;
  int b = blockIdx.x * 4 + bl;
  __shared__ float v[4][32];
  __shared__ float part[4][2][32];
  if (lg == 0) {
    const float* u0 = vch + (size_t)b * 16;
    float s0 = 0.f;
    #pragma unroll
    for (int c = 0; c < 16; ++c) s0 += chi_first[r * 16 + c] * u0[c];
    v[bl][r] = s0;
  }
  __syncthreads();
  for (int s = 0; s < 62; ++s) {
    const float* u = vch + ((size_t)(s + 1) * 256 + b) * 16;
    float uc[16];
    #pragma unroll
    for (int c = 0; c < 16; ++c) uc[c] = u[c];
    const float* W = chi_mid + (size_t)s * 32 * 32 * 16;
    float sum = 0.f;
    #pragma unroll
    for (int j = 0; j < 16; ++j) {
      int l = lg * 16 + j;
      const float* Wl = W + ((size_t)l * 32 + r) * 16;
      float tt = 0.f;
      #pragma unroll
      for (int c = 0; c < 16; ++c) tt += Wl[c] * uc[c];
      sum += v[bl][l] * tt;
    }
    part[bl][lg][r] = sum;
    __syncthreads();
    if (lg == 0) v[bl][r] = part[bl][0][r] + part[bl][1][r];
    __syncthreads();
  }
  const float* u63 = vch + ((size_t)63 * 256 + b) * 16;
  float uc[16];
  #pragma unroll
  for (int c = 0; c < 16; ++c) uc[c] = u63[c];
  if (r < 10) {
    float acc = 0.f;
    #pragma unroll
    for (int j = 0; j < 16; ++j) {
      int l = lg * 16 + j;
      const float* cl = chi_last + (size_t)l * 16 * 10;
      float tt = 0.f;
      #pragma unroll
      for (int c = 0; c < 16; ++c) tt += cl[c * 10 + r] * uc[c];
      acc += v[bl][l] * tt;
    }
    part[bl][lg][r] = acc;
  }
  __syncthreads();
  if (lg == 0 && r < 10)
    out[b * 10 + r] = (part[bl][0][r] + part[bl][1][r]) * psiv[b] * phiv[0];
}

__global__ __launch_bounds__(256) void k_psi_direct(const float* __restrict__ x,
                                                    const float* __restrict__ psi_mid,
                                                    const float* __restrict__ psi_first,
                                                    const float* __restrict__ psi_last,
                                                    float* __restrict__ psiv) {
  int b = blockIdx.x;
  int t = threadIdx.x;
  int r = t & 63, g = t >> 6;
  __shared__ float u[256];
  __shared__ float v[64];
  __shared__ float part[4][64];
  __shared__ float red[256];
  const float* xb = x + ((size_t)b << 18);
  {
    const float* rw = xb + (size_t)0 * 4096 + t * 16;
    float sm = 0.f;
    #pragma unroll
    for (int c = 0; c < 16; ++c) sm += rw[c];
    u[t] = sm * (1.0f / 16.0f);
  }
  __syncthreads();
  {
    float s0 = 0.f;
    for (int p = g * 64; p < g * 64 + 64; ++p) s0 += psi_first[r * 256 + p] * u[p];
    part[g][r] = s0;
    __syncthreads();
    if (g == 0) v[r] = part[0][r] + part[1][r] + part[2][r] + part[3][r];
  }
  __syncthreads();
  for (int s = 0; s < 62; ++s) {
    __syncthreads();
    {
      const float* rw = xb + (size_t)(s + 1) * 4096 + t * 16;
      float sm = 0.f;
      #pragma unroll
      for (int c = 0; c < 16; ++c) sm += rw[c];
      u[t] = sm * (1.0f / 16.0f);
    }
    __syncthreads();
    const float* W = psi_mid + (size_t)s * 4096 * 256;
    float sum = 0.f;
    for (int l = 0; l < 64; ++l) {
      const float* Wl = W + ((size_t)(l * 64 + r)) * 256 + g * 64;
      float tt = 0.f;
      #pragma unroll 8
      for (int k = 0; k < 64; ++k) tt += Wl[k] * u[g * 64 + k];
      sum += v[l] * tt;
    }
    part[g][r] = sum;
    __syncthreads();
    if (g == 0) v[r] = part[0][r] + part[1][r] + part[2][r] + part[3][r];
    __syncthreads();
  }
  __syncthreads();
  {
    const float* rw = xb + (size_t)63 * 4096 + t * 16;
    float sm = 0.f;
    #pragma unroll
    for (int c = 0; c < 16; ++c) sm += rw[c];
    u[t] = sm * (1.0f / 16.0f);
  }
  __syncthreads();
  float qv = 0.f;
  for (int l = 0; l < 64; ++l) qv += v[l] * psi_last[l * 256 + t];
  red[t] = qv * u[t];
  __syncthreads();
  for (int off = 128; off > 0; off >>= 1) {
    if (t < off) red[t] += red[t + off];
    __syncthreads();
  }
  if (t == 0) psiv[b] = red[0];
}

// ---------------------------------------------------------------------------
extern "C" void kernel_launch(void* const* d_in, const int* in_sizes, int n_in,
                              void* d_out, int out_size, void* d_ws, size_t ws_size,
                              hipStream_t stream) {
  const float* x         = (const float*)d_in[0];
  const float* chi_first = (const float*)d_in[1];
  const float* chi_mid   = (const float*)d_in[2];
  const float* chi_last  = (const float*)d_in[3];
  const float* psi_first = (const float*)d_in[4];
  const float* psi_mid   = (const float*)d_in[5];
  const float* psi_last  = (const float*)d_in[6];
  const float* phi_first = (const float*)d_in[7];
  const float* phi_mid   = (const float*)d_in[8];
  const float* phi_last  = (const float*)d_in[9];
  float* out = (float*)d_out;
  float* ws  = (float*)d_ws;

  size_t wsf = ws_size / 4;
  size_t off = 0;
  float* vch    = ws + off; off += (size_t)64 * 256 * 16;     // 262144
  float* psiv   = ws + off; off += 256;
  float* chiout = ws + off; off += 2560;
  float* phisl  = ws + off; off += (size_t)62 * 64 * 64;      // 253952
  float* phiv   = ws + off; off += 16;
  float* vpsi   = ws + off; off += (size_t)64 * 256;          // 16384
  float* vchi   = ws + off; off += (size_t)32 * 256;          // 8192
  float* vpx    = ws + off; off += (size_t)64 * 256 * 256;    // 4194304
  unsigned short* vpxf_hi = (unsigned short*)(ws + off); off += (size_t)64 * 65536 / 2;
  unsigned short* vpxf_lo = (unsigned short*)(ws + off); off += (size_t)64 * 65536 / 2;
  float* Mbuf   = ws + off;
  size_t mfloats = (wsf > off) ? (wsf - off) : 0;
  size_t needM  = (size_t)62 * 256 * 4096;                    // 65,011,712
  size_t needTc = (size_t)62 * 256 * 1024;                    // 16,252,928
  float* Tcbuf  = Mbuf + needM;

  if (mfloats >= needM + needTc) {
    // ===== Overlapped path: 4 dispatches =====
    k_reduce_x<<<16384 + 62, 256, 0, stream>>>(x, vch, vpx, vpxf_hi, vpxf_lo,
                                               phi_mid, phisl);
    k_mega_gemm<<<4465, 512, 0, stream>>>(psi_mid, vpxf_hi, vpxf_lo, Mbuf,
                                          chi_mid, vch, Tcbuf,
                                          phisl, phi_first, phi_last, phiv);
    k_mega_chain<<<512, 64, 0, stream>>>(Mbuf, Tcbuf, vpx, vch,
                                         psi_first, psi_last,
                                         chi_first, chi_last, psiv, chiout);
    k_combine<<<10, 256, 0, stream>>>(chiout, psiv, phiv, out);
  } else {
    int C = (int)(mfloats / ((size_t)256 * 4096));
    if (C > 62) C = 62;
    int Cc = (int)(mfloats / ((size_t)256 * 1024));
    if (Cc > 62) Cc = 62;
    if (C >= 1) {
      k_reduce_x<<<16384 + 62, 256, 0, stream>>>(x, vch, vpx, vpxf_hi, vpxf_lo,
                                                 phi_mid, phisl);
      int done = 0;
      while (done < 62) {
        int c = imin(C, 62 - done);
        k_psi_gemm<<<dim3(64, 1, c), 512, 0, stream>>>(psi_mid, vpxf_hi, vpxf_lo, Mbuf, done);
        k_psi_chain<<<256, 256, 0, stream>>>(Mbuf, vpx, psi_first, psi_last,
                                             vpsi, psiv, c, (done == 0) ? 1 : 0,
                                             (done + c == 62) ? 1 : 0);
        done += c;
      }
      done = 0;
      while (done < 62) {
        int c = imin(Cc, 62 - done);
        int phiBlk = (done == 0) ? c : -1;
        int gx = (done == 0) ? (c + 1) : c;
        k_chi_gemm<<<dim3(gx, 8), 256, 0, stream>>>(chi_mid, vch, Mbuf, done, phiBlk,
                                                    phisl, phi_first, phi_last, phiv);
        k_chi_chain<<<256, 64, 0, stream>>>(Mbuf, chi_first, chi_last, vch,
                                            psiv, phiv, vchi, out, c,
                                            (done == 0) ? 1 : 0,
                                            (done + c == 62) ? 1 : 0);
        done += c;
      }
    } else {
      k_reduce_x<<<16384 + 62, 256, 0, stream>>>(x, vch, nullptr, nullptr, nullptr,
                                                 phi_mid, phisl);
      k_psi_direct<<<256, 256, 0, stream>>>(x, psi_mid, psi_first, psi_last, psiv);
      k_phi_chain<<<1, 256, 0, stream>>>(phisl, phi_first, phi_last, phiv);
      k_chi_fused<<<64, 256, 0, stream>>>(chi_first, chi_mid, chi_last, vch, psiv, phiv, out);
    }
  }
}

// Round 12
// 301.563 us; speedup vs baseline: 5.7735x; 1.2032x over previous
//
#include <hip/hip_runtime.h>

// dims: L=64, CH=16, PIX=256, PAT=64, RC=32, BD=64, OUT=10, B=256
// inputs: 0=x(256,64,256,16) 1=chi_first(32,16) 2=chi_mid(62,32,32,16)
// 3=chi_last(32,16,10) 4=psi_first(64,256) 5=psi_mid(62,64,64,256)
// 6=psi_last(64,256) 7=phi_first(64,64) 8=phi_mid(62,64,64,64) 9=phi_last(64,64)

static inline int imin(int a, int b) { return a < b ? a : b; }

typedef __attribute__((ext_vector_type(8))) short bf16x8;          // 8 bf16 (4 VGPR)
typedef __attribute__((ext_vector_type(8))) unsigned short us8;
typedef __attribute__((ext_vector_type(4))) float f32x4;

__device__ __forceinline__ unsigned short f2bf(float v) {
  union { float f; unsigned int u; } c; c.f = v;
  unsigned int u = c.u;
  unsigned int r = (u + 0x7fffu + ((u >> 16) & 1u)) >> 16;  // RTN-even
  return (unsigned short)r;
}
__device__ __forceinline__ float bf2f(unsigned short h) {
  union { unsigned int u; float f; } c; c.u = ((unsigned int)h) << 16;
  return c.f;
}

// ---------------------------------------------------------------------------
// K1: vpx means + bf16 hi/lo fragment emit + phi slice gather (bx >= 16384).
__global__ __launch_bounds__(256) void k_reduce_x(const float* __restrict__ x,
                                                  float* __restrict__ vch,
                                                  float* __restrict__ vpx,
                                                  unsigned short* __restrict__ vpxf_hi,
                                                  unsigned short* __restrict__ vpxf_lo,
                                                  const float* __restrict__ phi_mid,
                                                  float* __restrict__ slices) {
  if (blockIdx.x >= 16384) {                 // phi gather block
    int i = blockIdx.x - 16384;              // 0..61
    int t = threadIdx.x;
    #pragma unroll
    for (int k = 0; k < 16; ++k) {
      int idx = t + k * 256;                 // l*64 + r
      slices[(size_t)i * 4096 + idx] = phi_mid[((size_t)i * 4096 + idx) * 64 + (i + 1)];
    }
    return;
  }
  int bp = blockIdx.x;             // b*64 + s
  int b = bp >> 6, s = bp & 63;
  int q = threadIdx.x;             // = p
  const float* row = x + ((size_t)bp << 12) + q * 16;
  float4 r0 = *(const float4*)(row);
  float4 r1 = *(const float4*)(row + 4);
  float4 r2 = *(const float4*)(row + 8);
  float4 r3 = *(const float4*)(row + 12);
  float csum = r0.x + r0.y + r0.z + r0.w + r1.x + r1.y + r1.z + r1.w
             + r2.x + r2.y + r2.z + r2.w + r3.x + r3.y + r3.z + r3.w;
  float val = csum * (1.0f / 16.0f);
  if (vpx && (s == 0 || s == 63)) vpx[((size_t)s * 256 + b) * 256 + q] = val;
  if (vpxf_hi && s >= 1 && s <= 62) {
    unsigned short hb = f2bf(val);
    unsigned short lb = f2bf(val - bf2f(hb));
    size_t fa = (size_t)s * 65536
              + (((size_t)(q >> 5) * 16 + (b >> 4)) * 64 + (((q >> 3) & 3) * 16 + (b & 15))) * 8
              + (q & 7);
    vpxf_hi[fa] = hb;
    vpxf_lo[fa] = lb;
  }

  __shared__ float sc[256][20];
  *(float4*)&sc[q][0]  = r0;
  *(float4*)&sc[q][4]  = r1;
  *(float4*)&sc[q][8]  = r2;
  *(float4*)&sc[q][12] = r3;
  __syncthreads();
  int c = q & 15, g = q >> 4;
  float ps = 0.f;
  #pragma unroll
  for (int k = 0; k < 16; ++k) ps += sc[g * 16 + k][c];
  __shared__ float p2[16][17];
  p2[g][c] = ps;
  __syncthreads();
  if (q < 16) {
    float s2 = 0.f;
    #pragma unroll
    for (int k = 0; k < 16; ++k) s2 += p2[k][q];
    vch[((size_t)s * 256 + b) * 16 + q] = s2 * (1.0f / 256.0f);
  }
}

// ---------------------------------------------------------------------------
// psi gemm tile body (512 threads): site's W slab x A fragments -> M tile,
// LDS transpose epilogue for 256B-coalesced stores. smem = 32 KB scratch.
__device__ __forceinline__ void psi_gemm_tile(const float* __restrict__ W,
                                              const unsigned short* __restrict__ Ahg,
                                              const unsigned short* __restrict__ Alg,
                                              float* __restrict__ Mz,   // M + z*256*4096
                                              int lr0, int t,
                                              unsigned char* smem) {
  typedef unsigned short BArr[2][2][4][64][8];          // 16 KB each
  BArr& Bh = *reinterpret_cast<BArr*>(smem);
  BArr& Bl = *reinterpret_cast<BArr*>(smem + 16384);
  int lane = t & 63, w = t >> 6;
  int row = t >> 3, kg = t & 7;
  float4 sv0, sv1;

  #define LOADP(p) do {                                                      \
    const float* src = W + (size_t)(lr0 + row) * 256 + ((p) << 6) + kg * 8;  \
    sv0 = *(const float4*)src;                                               \
    sv1 = *(const float4*)(src + 4);                                         \
  } while (0)
  #define WRITEP(d) do {                                                     \
    float xs[8] = {sv0.x, sv0.y, sv0.z, sv0.w, sv1.x, sv1.y, sv1.z, sv1.w};  \
    us8 hv, lv;                                                              \
    _Pragma("unroll")                                                        \
    for (int i = 0; i < 8; ++i) {                                            \
      unsigned short hb = f2bf(xs[i]);                                       \
      hv[i] = hb;                                                            \
      lv[i] = f2bf(xs[i] - bf2f(hb));                                        \
    }                                                                        \
    int ck = kg >> 2, nt = row >> 4, ln = ((kg & 3) << 4) | (row & 15);      \
    *(us8*)&Bh[d][ck][nt][ln][0] = hv;                                       \
    *(us8*)&Bl[d][ck][nt][ln][0] = lv;                                       \
  } while (0)
  #define LOADA(slot, chunk) do {                                            \
    _Pragma("unroll")                                                        \
    for (int mi = 0; mi < 2; ++mi) {                                         \
      size_t fo = ((size_t)(chunk) * 16 + (w * 2 + mi)) * 512 + (size_t)lane * 8; \
      Ah[slot][mi] = *(const bf16x8*)(Ahg + fo);                             \
      Al[slot][mi] = *(const bf16x8*)(Alg + fo);                             \
    }                                                                        \
  } while (0)

  f32x4 acc[2][4];
  #pragma unroll
  for (int i = 0; i < 2; ++i)
    #pragma unroll
    for (int j = 0; j < 4; ++j) acc[i][j] = (f32x4){0.f, 0.f, 0.f, 0.f};
  bf16x8 Ah[2][2], Al[2][2];

  LOADA(0, 0);
  LOADP(0);
  WRITEP(0);
  __syncthreads();
  #pragma unroll
  for (int p = 0; p < 4; ++p) {
    if (p < 3) LOADP(p + 1);
    #pragma unroll
    for (int c = 0; c < 2; ++c) {
      const int chunk = p * 2 + c;
      const int cur = chunk & 1, nxt = (chunk + 1) & 1;
      if (chunk < 7) LOADA(nxt, chunk + 1);
      #pragma unroll
      for (int n = 0; n < 4; ++n) {
        bf16x8 bh = *(const bf16x8*)&Bh[p & 1][c][n][lane][0];
        bf16x8 bl = *(const bf16x8*)&Bl[p & 1][c][n][lane][0];
        #pragma unroll
        for (int mi = 0; mi < 2; ++mi) {
          acc[mi][n] = __builtin_amdgcn_mfma_f32_16x16x32_bf16(Ah[cur][mi], bh, acc[mi][n], 0, 0, 0);
          acc[mi][n] = __builtin_amdgcn_mfma_f32_16x16x32_bf16(Al[cur][mi], bh, acc[mi][n], 0, 0, 0);
          acc[mi][n] = __builtin_amdgcn_mfma_f32_16x16x32_bf16(Ah[cur][mi], bl, acc[mi][n], 0, 0, 0);
        }
      }
    }
    if (p < 3) WRITEP((p + 1) & 1);
    __syncthreads();
  }
  #undef LOADP
  #undef WRITEP
  #undef LOADA

  // transpose epilogue: acc -> LDS T[128][64] -> 256B-coalesced stores
  int rg = lane >> 4, cidx = lane & 15;
  float (*T)[64] = reinterpret_cast<float (*)[64]>(smem);   // 32 KB
  #pragma unroll
  for (int pass = 0; pass < 2; ++pass) {
    if ((w >> 2) == pass) {
      #pragma unroll
      for (int mi = 0; mi < 2; ++mi) {
        int rowb = (((w & 3) * 2 + mi) * 16) + rg * 4;
        #pragma unroll
        for (int n = 0; n < 4; ++n) {
          #pragma unroll
          for (int r = 0; r < 4; ++r) {
            T[rowb + r][n * 16 + cidx] = acc[mi][n][r];
          }
        }
      }
    }
    __syncthreads();
    int boff = pass * 128;
    #pragma unroll
    for (int k = 0; k < 4; ++k) {
      int f = t + k * 512;            // float4 unit 0..2047
      int b2 = f >> 4;                // 0..127
      int l4 = (f & 15) * 4;          // 0..60
      *(float4*)(Mz + ((size_t)(boff + b2)) * 4096 + lr0 + l4) =
          *(const float4*)&T[b2][l4];
    }
    __syncthreads();
  }
}

// ---------------------------------------------------------------------------
// K2 (mega_A): bx==0 phi chain; bx 1..496 chi gemm; bx>=497 psi gemm sites 0..31.
__global__ __launch_bounds__(512) void k_mega_A(const float* __restrict__ psi_mid,
                                                const unsigned short* __restrict__ vpxf_hi,
                                                const unsigned short* __restrict__ vpxf_lo,
                                                float* __restrict__ M,
                                                const float* __restrict__ chi_mid,
                                                const float* __restrict__ vch,
                                                float* __restrict__ Tc,
                                                const float* __restrict__ slices,
                                                const float* __restrict__ phi_first,
                                                const float* __restrict__ phi_last,
                                                float* __restrict__ phiv) {
  int bx = blockIdx.x;
  int t = threadIdx.x;
  if (bx == 0) {
    // phi chain (512-thread, barriered)
    int r = t & 63, g = t >> 6;
    __shared__ float u[64];
    __shared__ float part[8][64];
    __shared__ float red[64];
    if (t < 64) u[t] = phi_first[t * 64];
    __syncthreads();
    for (int i2 = 0; i2 < 62; ++i2) {
      float sum = 0.f;
      #pragma unroll
      for (int j = 0; j < 8; ++j) {
        int l = g * 8 + j;
        sum += u[l] * slices[(size_t)i2 * 4096 + l * 64 + r];
      }
      part[g][r] = sum;
      __syncthreads();
      if (g == 0) u[r] = part[0][r] + part[1][r] + part[2][r] + part[3][r]
                       + part[4][r] + part[5][r] + part[6][r] + part[7][r];
      __syncthreads();
    }
    if (t < 64) red[t] = u[t] * phi_last[t * 64 + 63];
    __syncthreads();
    if (t == 0) {
      float s = 0.f;
      for (int l = 0; l < 64; ++l) s += red[l];
      *phiv = s;
    }
  } else if (bx <= 496) {
    // chi gemm: Tc[z][b][r*32+l]
    int i = bx - 1;
    int z = i >> 3;                 // site 0..61
    int b0 = (i & 7) * 32;
    __shared__ float uv[32][16];
    if (t < 128) {
      int idx = t * 4;
      int b = idx >> 4, c = idx & 15;
      *(float4*)&uv[b][c] = *(const float4*)(vch + ((size_t)(z + 1) * 256 + b0 + b) * 16 + c);
    }
    __syncthreads();
    #pragma unroll
    for (int k = 0; k < 2; ++k) {
      int idx = t + k * 512;         // output index = r*32 + l
      int r = idx >> 5, l = idx & 31;
      const float* Wp = chi_mid + ((size_t)z * 1024 + l * 32 + r) * 16;
      float4 w0 = *(const float4*)(Wp);
      float4 w1 = *(const float4*)(Wp + 4);
      float4 w2 = *(const float4*)(Wp + 8);
      float4 w3 = *(const float4*)(Wp + 12);
      for (int b = 0; b < 32; ++b) {
        const float* u = uv[b];
        float d = w0.x * u[0] + w0.y * u[1] + w0.z * u[2] + w0.w * u[3]
                + w1.x * u[4] + w1.y * u[5] + w1.z * u[6] + w1.w * u[7]
                + w2.x * u[8] + w2.y * u[9] + w2.z * u[10] + w2.w * u[11]
                + w3.x * u[12] + w3.y * u[13] + w3.z * u[14] + w3.w * u[15];
        Tc[((size_t)z * 256 + b0 + b) * 1024 + idx] = d;
      }
    }
  } else {
    int idx = bx - 497;
    int z = idx >> 6;               // site 0..31
    int lr0 = (idx & 63) * 64;
    __shared__ __align__(16) unsigned char smem[32768];
    psi_gemm_tile(psi_mid + (size_t)z * 4096 * 256,
                  vpxf_hi + (size_t)(z + 1) * 65536,
                  vpxf_lo + (size_t)(z + 1) * 65536,
                  M + (size_t)z * 256 * 4096, lr0, t, smem);
  }
}

// ---------------------------------------------------------------------------
// K3 (mega_B): bx<256 psi chain part1 (sites 0..31, LDS-grouped, low-VGPR);
// bx 256..511 chi chain full; bx>=512 psi gemm sites 32..61.
// Chains are latency clients hidden under the gemm blocks' memory traffic.
__global__ __launch_bounds__(512) void k_mega_B(const float* __restrict__ psi_mid,
                                                const unsigned short* __restrict__ vpxf_hi,
                                                const unsigned short* __restrict__ vpxf_lo,
                                                float* __restrict__ M,
                                                const float* __restrict__ Tc,
                                                const float* __restrict__ vpx,
                                                const float* __restrict__ vch,
                                                const float* __restrict__ psi_first,
                                                const float* __restrict__ chi_first,
                                                const float* __restrict__ chi_last,
                                                float* __restrict__ vpsi,
                                                float* __restrict__ chiout) {
  int bx = blockIdx.x;
  int t = threadIdx.x;
  if (bx < 256) {
    // psi chain part 1: sites 0..31 (even count), 512 threads, 8 l-groups.
    int b = bx;
    int r = t & 63, g = t >> 6;
    __shared__ float vsh[64];
    __shared__ float part[8][64];
    {
      const float* u0 = vpx + (size_t)b * 256;
      const float* pf = psi_first + r * 256 + g * 32;
      float s0 = 0.f;
      #pragma unroll
      for (int p = 0; p < 32; ++p) s0 += pf[p] * u0[g * 32 + p];
      part[g][r] = s0;
      __syncthreads();
      if (g == 0) {
        float sv = 0.f;
        #pragma unroll
        for (int k = 0; k < 8; ++k) sv += part[k][r];
        vsh[r] = sv;
      }
      __syncthreads();
    }
    #define QLOAD(buf, sc) do {                                                \
      const float* Mb = M + ((size_t)(sc) * 256 + b) * 4096 + r;               \
      _Pragma("unroll")                                                        \
      for (int j = 0; j < 8; ++j) buf[j] = Mb[(size_t)(g * 8 + j) * 64];       \
    } while (0)
    #define QSTEP(buf) do {                                                    \
      float sum = 0.f;                                                         \
      _Pragma("unroll")                                                        \
      for (int j = 0; j < 8; ++j) sum += vsh[g * 8 + j] * buf[j];              \
      part[g][r] = sum;                                                        \
      __syncthreads();                                                         \
      if (g == 0) {                                                            \
        float sv = 0.f;                                                        \
        _Pragma("unroll")                                                      \
        for (int k = 0; k < 8; ++k) sv += part[k][r];                          \
        vsh[r] = sv;                                                           \
      }                                                                        \
      __syncthreads();                                                         \
    } while (0)
    float bufA[8], bufB[8];
    QLOAD(bufA, 0);
    #pragma unroll 1
    for (int sc = 0; sc < 32; sc += 2) {
      QLOAD(bufB, sc + 1);
      QSTEP(bufA);
      if (sc + 2 < 32) QLOAD(bufA, sc + 2);
      QSTEP(bufB);
    }
    #undef QLOAD
    #undef QSTEP
    if (g == 0) vpsi[b * 64 + r] = vsh[r];
  } else if (bx < 512) {
    // chi chain (full 62 sites), 1 wave, reg+shfl, no barriers.
    if (t >= 64) return;
    int b = bx - 256;
    int lane = t;
    int r = lane & 31, h = lane >> 5;
    float v;
    {
      const float* u0 = vch + (size_t)b * 16;    // site 0
      const float* cf = chi_first + r * 16;
      float s0 = 0.f;
      #pragma unroll
      for (int c = 0; c < 16; ++c) s0 += cf[c] * u0[c];
      v = s0;                                    // same in both halves
    }
    #define CLOADX(buf, sc) do {                                               \
      const float* Mb = Tc + ((size_t)(sc) * 256 + b) * 1024 + r * 32 + h * 16; \
      *(float4*)&buf[0]  = *(const float4*)(Mb);                               \
      *(float4*)&buf[4]  = *(const float4*)(Mb + 4);                           \
      *(float4*)&buf[8]  = *(const float4*)(Mb + 8);                           \
      *(float4*)&buf[12] = *(const float4*)(Mb + 12);                          \
    } while (0)
    #define CSTEPX(buf) do {                                                   \
      float s0 = 0.f, s1 = 0.f;                                                \
      _Pragma("unroll")                                                        \
      for (int j = 0; j < 8; ++j) {                                            \
        s0 += __shfl(v, h * 16 + 2 * j)     * buf[2 * j];                      \
        s1 += __shfl(v, h * 16 + 2 * j + 1) * buf[2 * j + 1];                  \
      }                                                                        \
      float sum = s0 + s1;                                                     \
      sum += __shfl_xor(sum, 32);                                              \
      v = sum;                                                                 \
    } while (0)
    {
      float mjA[16], mjB[16];
      CLOADX(mjA, 0);
      #pragma unroll 1
      for (int sc = 0; sc < 62; sc += 2) {
        CLOADX(mjB, sc + 1);
        CSTEPX(mjA);
        if (sc + 2 < 62) CLOADX(mjA, sc + 2);
        CSTEPX(mjB);
      }
    }
    #undef CLOADX
    #undef CSTEPX
    const float* u63 = vch + ((size_t)63 * 256 + b) * 16;
    float uc[16];
    #pragma unroll
    for (int c = 0; c < 16; ++c) uc[c] = u63[c];
    for (int o = 0; o < 10; ++o) {
      const float* cl = chi_last + r * 16 * 10 + o;
      float wv = 0.f;
      #pragma unroll
      for (int c = 0; c < 16; ++c) wv += cl[c * 10] * uc[c];
      float p = v * wv;                          // duplicated across halves
      #pragma unroll
      for (int m = 32; m > 0; m >>= 1) p += __shfl_xor(p, m);
      if (lane == 0) chiout[b * 10 + o] = p * 0.5f;
    }
  } else {
    int idx = bx - 512;
    int z = 32 + (idx >> 6);        // site 32..61
    int lr0 = (idx & 63) * 64;
    __shared__ __align__(16) unsigned char smem[32768];
    psi_gemm_tile(psi_mid + (size_t)z * 4096 * 256,
                  vpxf_hi + (size_t)(z + 1) * 65536,
                  vpxf_lo + (size_t)(z + 1) * 65536,
                  M + (size_t)z * 256 * 4096, lr0, t, smem);
  }
}

// ---------------------------------------------------------------------------
// K4: psi chain part 2 (sites 32..61, deep 64x2 register prefetch) + fused
// combine epilogue (out = chiout * psiv * phiv). 256 blocks x 64 threads.
__global__ __launch_bounds__(64) void k_chain_tail(const float* __restrict__ M,
                                                   const float* __restrict__ vpx,
                                                   const float* __restrict__ psi_last,
                                                   const float* __restrict__ chiout,
                                                   const float* __restrict__ phiv,
                                                   const float* __restrict__ vpsi,
                                                   float* __restrict__ out) {
  int b = blockIdx.x;
  int lane = threadIdx.x;
  float v = vpsi[b * 64 + lane];
  #define MLOAD(buf, sc) do {                                                \
    const float* Mb = M + ((size_t)(32 + (sc)) * 256 + b) * 4096 + lane;     \
    _Pragma("unroll")                                                        \
    for (int l = 0; l < 64; ++l) buf[l] = Mb[(size_t)l * 64];                \
  } while (0)
  #define MSTEP(buf) do {                                                    \
    float s0 = 0.f, s1 = 0.f, s2 = 0.f, s3 = 0.f;                            \
    _Pragma("unroll")                                                        \
    for (int l = 0; l < 16; ++l) {                                           \
      s0 += __shfl(v, 4 * l + 0) * buf[4 * l + 0];                           \
      s1 += __shfl(v, 4 * l + 1) * buf[4 * l + 1];                           \
      s2 += __shfl(v, 4 * l + 2) * buf[4 * l + 2];                           \
      s3 += __shfl(v, 4 * l + 3) * buf[4 * l + 3];                           \
    }                                                                        \
    v = (s0 + s1) + (s2 + s3);                                               \
  } while (0)
  {
    float mvA[64], mvB[64];
    MLOAD(mvA, 0);
    #pragma unroll 1
    for (int sc = 0; sc < 30; sc += 2) {      // 30 even: pairs complete
      MLOAD(mvB, sc + 1);
      MSTEP(mvA);
      if (sc + 2 < 30) MLOAD(mvA, sc + 2);
      MSTEP(mvB);
    }
  }
  #undef MLOAD
  #undef MSTEP
  // psi_val = sum_p (sum_l v[l] psi_last[l][p]) * vpx[63][b][p]
  float acc_p = 0.f;
  #pragma unroll
  for (int pp = 0; pp < 4; ++pp) {
    int p = pp * 64 + lane;
    float pl[64];
    #pragma unroll
    for (int l = 0; l < 64; ++l) pl[l] = psi_last[l * 256 + p];
    float s0 = 0.f, s1 = 0.f, s2 = 0.f, s3 = 0.f;
    #pragma unroll
    for (int l = 0; l < 16; ++l) {
      s0 += __shfl(v, 4 * l + 0) * pl[4 * l + 0];
      s1 += __shfl(v, 4 * l + 1) * pl[4 * l + 1];
      s2 += __shfl(v, 4 * l + 2) * pl[4 * l + 2];
      s3 += __shfl(v, 4 * l + 3) * pl[4 * l + 3];
    }
    float wv = (s0 + s1) + (s2 + s3);
    acc_p += wv * vpx[((size_t)63 * 256 + b) * 256 + p];
  }
  #pragma unroll
  for (int m = 32; m > 0; m >>= 1) acc_p += __shfl_xor(acc_p, m);
  // fused combine: acc_p (psiv) is in all lanes
  if (lane < 10) out[b * 10 + lane] = chiout[b * 10 + lane] * acc_p * phiv[0];
}

// ---------------------------------------------------------------------------
// ===== Fallback tier (smaller workspace): r7 chunked pipeline, barriered =====
__global__ __launch_bounds__(512) void k_psi_gemm(const float* __restrict__ psi_mid,
                                                  const unsigned short* __restrict__ vpxf_hi,
                                                  const unsigned short* __restrict__ vpxf_lo,
                                                  float* __restrict__ M, int s0) {
  int z = blockIdx.z;
  int s = s0 + z;
  int lr0 = blockIdx.x * 64;
  __shared__ __align__(16) unsigned char smem[32768];
  psi_gemm_tile(psi_mid + (size_t)s * 4096 * 256,
                vpxf_hi + (size_t)(s + 1) * 65536,
                vpxf_lo + (size_t)(s + 1) * 65536,
                M + (size_t)z * 256 * 4096, lr0, threadIdx.x, smem);
}

__global__ __launch_bounds__(256) void k_psi_chain(const float* __restrict__ M,
                                                   const float* __restrict__ vpx,
                                                   const float* __restrict__ psi_first,
                                                   const float* __restrict__ psi_last,
                                                   float* __restrict__ vpsi,
                                                   float* __restrict__ psiv,
                                                   int nS, int isFirst, int isLast) {
  int b = blockIdx.x;
  int t = threadIdx.x;
  int r = t & 63, g = t >> 6;
  __shared__ float v[64];
  __shared__ float part[4][64];
  __shared__ float red[256];
  if (isFirst) {
    const float* u0 = vpx + (size_t)b * 256;
    float s0 = 0.f;
    for (int p = g * 64; p < g * 64 + 64; ++p) s0 += psi_first[r * 256 + p] * u0[p];
    part[g][r] = s0;
    __syncthreads();
    if (g == 0) v[r] = part[0][r] + part[1][r] + part[2][r] + part[3][r];
    __syncthreads();
  } else {
    if (g == 0) v[r] = vpsi[b * 64 + r];
    __syncthreads();
  }
  for (int sc = 0; sc < nS; ++sc) {
    const float* Mb = M + ((size_t)sc * 256 + b) * 4096;
    float sum = 0.f;
    #pragma unroll
    for (int j = 0; j < 16; ++j) {
      int l = g * 16 + j;
      sum += v[l] * Mb[l * 64 + r];
    }
    part[g][r] = sum;
    __syncthreads();
    if (g == 0) v[r] = part[0][r] + part[1][r] + part[2][r] + part[3][r];
    __syncthreads();
  }
  if (isLast) {
    float qv = 0.f;
    for (int l = 0; l < 64; ++l) qv += v[l] * psi_last[l * 256 + t];
    red[t] = qv * vpx[((size_t)63 * 256 + b) * 256 + t];
    __syncthreads();
    for (int off = 128; off > 0; off >>= 1) {
      if (t < off) red[t] += red[t + off];
      __syncthreads();
    }
    if (t == 0) psiv[b] = red[0];
  } else {
    if (g == 0) vpsi[b * 64 + r] = v[r];
  }
}

__device__ __forceinline__ void phi_chain_body(const float* __restrict__ slices,
                                               const float* __restrict__ phi_first,
                                               const float* __restrict__ phi_last,
                                               float* __restrict__ phiv) {
  int t = threadIdx.x;
  int r = t & 63, g = t >> 6;
  __shared__ float u[64];
  __shared__ float part[4][64];
  __shared__ float red[64];
  if (t < 64) u[t] = phi_first[t * 64];
  __syncthreads();
  for (int i = 0; i < 62; ++i) {
    float sum = 0.f;
    #pragma unroll
    for (int j = 0; j < 16; ++j) {
      int l = g * 16 + j;
      sum += u[l] * slices[(size_t)i * 4096 + l * 64 + r];
    }
    part[g][r] = sum;
    __syncthreads();
    if (g == 0) u[r] = part[0][r] + part[1][r] + part[2][r] + part[3][r];
    __syncthreads();
  }
  if (t < 64) red[t] = u[t] * phi_last[t * 64 + 63];
  __syncthreads();
  if (t == 0) {
    float s = 0.f;
    for (int l = 0; l < 64; ++l) s += red[l];
    *phiv = s;
  }
}

__global__ __launch_bounds__(256) void k_phi_chain(const float* __restrict__ slices,
                                                   const float* __restrict__ phi_first,
                                                   const float* __restrict__ phi_last,
                                                   float* __restrict__ phiv) {
  phi_chain_body(slices, phi_first, phi_last, phiv);
}

__global__ __launch_bounds__(256) void k_chi_gemm(const float* __restrict__ chi_mid,
                                                  const float* __restrict__ vch,
                                                  float* __restrict__ Tc, int s0,
                                                  int phiBlock,
                                                  const float* __restrict__ slices,
                                                  const float* __restrict__ phi_first,
                                                  const float* __restrict__ phi_last,
                                                  float* __restrict__ phiv) {
  if ((int)blockIdx.x == phiBlock) {
    if (blockIdx.y == 0) phi_chain_body(slices, phi_first, phi_last, phiv);
    return;
  }
  int z = blockIdx.x;
  int s = s0 + z;
  int b0 = blockIdx.y * 32;
  int t = threadIdx.x;
  __shared__ float uv[32][16];
  if (t < 128) {
    int idx = t * 4;
    int b = idx >> 4, c = idx & 15;
    *(float4*)&uv[b][c] = *(const float4*)(vch + ((size_t)(s + 1) * 256 + b0 + b) * 16 + c);
  }
  __syncthreads();
  #pragma unroll
  for (int k = 0; k < 4; ++k) {
    int idx = t + k * 256;
    int r = idx >> 5, l = idx & 31;
    const float* Wp = chi_mid + ((size_t)s * 1024 + l * 32 + r) * 16;
    float4 w0 = *(const float4*)(Wp);
    float4 w1 = *(const float4*)(Wp + 4);
    float4 w2 = *(const float4*)(Wp + 8);
    float4 w3 = *(const float4*)(Wp + 12);
    for (int b = 0; b < 32; ++b) {
      const float* u = uv[b];
      float d = w0.x * u[0] + w0.y * u[1] + w0.z * u[2] + w0.w * u[3]
              + w1.x * u[4] + w1.y * u[5] + w1.z * u[6] + w1.w * u[7]
              + w2.x * u[8] + w2.y * u[9] + w2.z * u[10] + w2.w * u[11]
              + w3.x * u[12] + w3.y * u[13] + w3.z * u[14] + w3.w * u[15];
      Tc[((size_t)z * 256 + b0 + b) * 1024 + idx] = d;
    }
  }
}

__global__ __launch_bounds__(64) void k_chi_chain(const float* __restrict__ Tc,
                                                  const float* __restrict__ chi_first,
                                                  const float* __restrict__ chi_last,
                                                  const float* __restrict__ vch,
                                                  const float* __restrict__ psiv,
                                                  const float* __restrict__ phiv,
                                                  float* __restrict__ vchi,
                                                  float* __restrict__ out,
                                                  int nS, int isFirst, int isLast) {
  int b = blockIdx.x;
  int lane = threadIdx.x;
  int r = lane & 31, h = lane >> 5;
  __shared__ float v[32];
  if (isFirst) {
    if (h == 0) {
      const float* u0 = vch + (size_t)b * 16;
      const float* cf = chi_first + r * 16;
      float s0 = 0.f;
      #pragma unroll
      for (int c = 0; c < 16; ++c) s0 += cf[c] * u0[c];
      v[r] = s0;
    }
  } else {
    if (h == 0) v[r] = vchi[b * 32 + r];
  }
  __syncthreads();
  for (int sc = 0; sc < nS; ++sc) {
    const float* Mb = Tc + ((size_t)sc * 256 + b) * 1024 + r * 32 + h * 16;
    float4 m0 = *(const float4*)(Mb);
    float4 m1 = *(const float4*)(Mb + 4);
    float4 m2 = *(const float4*)(Mb + 8);
    float4 m3 = *(const float4*)(Mb + 12);
    const float* vv = &v[h * 16];
    float sum = m0.x * vv[0] + m0.y * vv[1] + m0.z * vv[2] + m0.w * vv[3]
              + m1.x * vv[4] + m1.y * vv[5] + m1.z * vv[6] + m1.w * vv[7]
              + m2.x * vv[8] + m2.y * vv[9] + m2.z * vv[10] + m2.w * vv[11]
              + m3.x * vv[12] + m3.y * vv[13] + m3.z * vv[14] + m3.w * vv[15];
    sum += __shfl_xor(sum, 32);
    __syncthreads();
    if (h == 0) v[r] = sum;
    __syncthreads();
  }
  if (isLast) {
    const float* u63 = vch + ((size_t)63 * 256 + b) * 16;
    float uc[16];
    #pragma unroll
    for (int c = 0; c < 16; ++c) uc[c] = u63[c];
    float scale = 0.5f * psiv[b] * phiv[0];
    for (int o = 0; o < 10; ++o) {
      const float* cl = chi_last + r * 16 * 10 + o;
      float w = 0.f;
      #pragma unroll
      for (int c = 0; c < 16; ++c) w += cl[c * 10] * uc[c];
      float p = v[r] * w;
      #pragma unroll
      for (int m = 32; m > 0; m >>= 1) p += __shfl_xor(p, m);
      if (lane == 0) out[b * 10 + o] = p * scale;
    }
  } else {
    if (h == 0) vchi[b * 32 + r] = v[r];
  }
}

__global__ __launch_bounds__(256) void k_chi_fused(const float* __restrict__ chi_first,
                                                   const float* __restrict__ chi_mid,
                                                   const float* __restrict__ chi_last,
                                                   const float* __restrict__ vch,
                                                   const float* __restrict__ psiv,
                                                   const float* __restrict__ phiv,
                                                   float* __restrict__ out) {
  int t = threadIdx.x;
  int bl = t >> 6, lg = (t >> 5) & 1, r = t & 31;
  int b = blockIdx.x * 4 + bl;
  __shared__ float v[4][32];
  __shared__ float part[4][2][32];
  if (lg == 0) {
    const float* u0 = vch + (size_t)b * 16;
    float s0 = 0.f;
    #pragma unroll
    for (int c = 0; c < 16; ++c) s0 += chi_first[r * 16 + c] * u0[c];
    v[bl][r] = s0;
  }
  __syncthreads();
  for (int s = 0; s < 62; ++s) {
    const float* u = vch + ((size_t)(s + 1) * 256 + b) * 16;
    float uc[16];
    #pragma unroll
    for (int c = 0; c < 16; ++c) uc[c] = u[c];
    const float* W = chi_mid + (size_t)s * 32 * 32 * 16;
    float sum = 0.f;
    #pragma unroll
    for (int j = 0; j < 16; ++j) {
      int l = lg * 16 + j;
      const float* Wl = W + ((size_t)l * 32 + r) * 16;
      float tt = 0.f;
      #pragma unroll
      for (int c = 0; c < 16; ++c) tt += Wl[c] * uc[c];
      sum += v[bl][l] * tt;
    }
    part[bl][lg][r] = sum;
    __syncthreads();
    if (lg == 0) v[bl][r] = part[bl][0][r] + part[bl][1][r];
    __syncthreads();
  }
  const float* u63 = vch + ((size_t)63 * 256 + b) * 16;
  float uc[16];
  #pragma unroll
  for (int c = 0; c < 16; ++c) uc[c] = u63[c];
  if (r < 10) {
    float acc = 0.f;
    #pragma unroll
    for (int j = 0; j < 16; ++j) {
      int l = lg * 16 + j;
      const float* cl = chi_last + (size_t)l * 16 * 10;
      float tt = 0.f;
      #pragma unroll
      for (int c = 0; c < 16; ++c) tt += cl[c * 10 + r] * uc[c];
      acc += v[bl][l] * tt;
    }
    part[bl][lg][r] = acc;
  }
  __syncthreads();
  if (lg == 0 && r < 10)
    out[b * 10 + r] = (part[bl][0][r] + part[bl][1][r]) * psiv[b] * phiv[0];
}

__global__ __launch_bounds__(256) void k_psi_direct(const float* __restrict__ x,
                                                    const float* __restrict__ psi_mid,
                                                    const float* __restrict__ psi_first,
                                                    const float* __restrict__ psi_last,
                                                    float* __restrict__ psiv) {
  int b = blockIdx.x;
  int t = threadIdx.x;
  int r = t & 63, g = t >> 6;
  __shared__ float u[256];
  __shared__ float v[64];
  __shared__ float part[4][64];
  __shared__ float red[256];
  const float* xb = x + ((size_t)b << 18);
  {
    const float* rw = xb + (size_t)0 * 4096 + t * 16;
    float sm = 0.f;
    #pragma unroll
    for (int c = 0; c < 16; ++c) sm += rw[c];
    u[t] = sm * (1.0f / 16.0f);
  }
  __syncthreads();
  {
    float s0 = 0.f;
    for (int p = g * 64; p < g * 64 + 64; ++p) s0 += psi_first[r * 256 + p] * u[p];
    part[g][r] = s0;
    __syncthreads();
    if (g == 0) v[r] = part[0][r] + part[1][r] + part[2][r] + part[3][r];
  }
  __syncthreads();
  for (int s = 0; s < 62; ++s) {
    __syncthreads();
    {
      const float* rw = xb + (size_t)(s + 1) * 4096 + t * 16;
      float sm = 0.f;
      #pragma unroll
      for (int c = 0; c < 16; ++c) sm += rw[c];
      u[t] = sm * (1.0f / 16.0f);
    }
    __syncthreads();
    const float* W = psi_mid + (size_t)s * 4096 * 256;
    float sum = 0.f;
    for (int l = 0; l < 64; ++l) {
      const float* Wl = W + ((size_t)(l * 64 + r)) * 256 + g * 64;
      float tt = 0.f;
      #pragma unroll 8
      for (int k = 0; k < 64; ++k) tt += Wl[k] * u[g * 64 + k];
      sum += v[l] * tt;
    }
    part[g][r] = sum;
    __syncthreads();
    if (g == 0) v[r] = part[0][r] + part[1][r] + part[2][r] + part[3][r];
    __syncthreads();
  }
  __syncthreads();
  {
    const float* rw = xb + (size_t)63 * 4096 + t * 16;
    float sm = 0.f;
    #pragma unroll
    for (int c = 0; c < 16; ++c) sm += rw[c];
    u[t] = sm * (1.0f / 16.0f);
  }
  __syncthreads();
  float qv = 0.f;
  for (int l = 0; l < 64; ++l) qv += v[l] * psi_last[l * 256 + t];
  red[t] = qv * u[t];
  __syncthreads();
  for (int off = 128; off > 0; off >>= 1) {
    if (t < off) red[t] += red[t + off];
    __syncthreads();
  }
  if (t == 0) psiv[b] = red[0];
}

// ---------------------------------------------------------------------------
extern "C" void kernel_launch(void* const* d_in, const int* in_sizes, int n_in,
                              void* d_out, int out_size, void* d_ws, size_t ws_size,
                              hipStream_t stream) {
  const float* x         = (const float*)d_in[0];
  const float* chi_first = (const float*)d_in[1];
  const float* chi_mid   = (const float*)d_in[2];
  const float* chi_last  = (const float*)d_in[3];
  const float* psi_first = (const float*)d_in[4];
  const float* psi_mid   = (const float*)d_in[5];
  const float* psi_last  = (const float*)d_in[6];
  const float* phi_first = (const float*)d_in[7];
  const float* phi_mid   = (const float*)d_in[8];
  const float* phi_last  = (const float*)d_in[9];
  float* out = (float*)d_out;
  float* ws  = (float*)d_ws;

  size_t wsf = ws_size / 4;
  size_t off = 0;
  float* vch    = ws + off; off += (size_t)64 * 256 * 16;     // 262144
  float* psiv   = ws + off; off += 256;
  float* chiout = ws + off; off += 2560;
  float* phisl  = ws + off; off += (size_t)62 * 64 * 64;      // 253952
  float* phiv   = ws + off; off += 16;
  float* vpsi   = ws + off; off += (size_t)64 * 256;          // 16384
  float* vchi   = ws + off; off += (size_t)32 * 256;          // 8192
  float* vpx    = ws + off; off += (size_t)64 * 256 * 256;    // 4194304
  unsigned short* vpxf_hi = (unsigned short*)(ws + off); off += (size_t)64 * 65536 / 2;
  unsigned short* vpxf_lo = (unsigned short*)(ws + off); off += (size_t)64 * 65536 / 2;
  float* Mbuf   = ws + off;
  size_t mfloats = (wsf > off) ? (wsf - off) : 0;
  size_t needM  = (size_t)62 * 256 * 4096;                    // 65,011,712
  size_t needTc = (size_t)62 * 256 * 1024;                    // 16,252,928
  float* Tcbuf  = Mbuf + needM;

  if (mfloats >= needM + needTc) {
    // ===== Pipelined path: reduce -> [gemmA+chiGemm+phi] -> [gemmB || chains] -> tail
    k_reduce_x<<<16384 + 62, 256, 0, stream>>>(x, vch, vpx, vpxf_hi, vpxf_lo,
                                               phi_mid, phisl);
    k_mega_A<<<497 + 2048, 512, 0, stream>>>(psi_mid, vpxf_hi, vpxf_lo, Mbuf,
                                             chi_mid, vch, Tcbuf,
                                             phisl, phi_first, phi_last, phiv);
    k_mega_B<<<512 + 1920, 512, 0, stream>>>(psi_mid, vpxf_hi, vpxf_lo, Mbuf,
                                             Tcbuf, vpx, vch, psi_first,
                                             chi_first, chi_last, vpsi, chiout);
    k_chain_tail<<<256, 64, 0, stream>>>(Mbuf, vpx, psi_last, chiout, phiv,
                                         vpsi, out);
  } else {
    int C = (int)(mfloats / ((size_t)256 * 4096));
    if (C > 62) C = 62;
    int Cc = (int)(mfloats / ((size_t)256 * 1024));
    if (Cc > 62) Cc = 62;
    if (C >= 1) {
      k_reduce_x<<<16384 + 62, 256, 0, stream>>>(x, vch, vpx, vpxf_hi, vpxf_lo,
                                                 phi_mid, phisl);
      int done = 0;
      while (done < 62) {
        int c = imin(C, 62 - done);
        k_psi_gemm<<<dim3(64, 1, c), 512, 0, stream>>>(psi_mid, vpxf_hi, vpxf_lo, Mbuf, done);
        k_psi_chain<<<256, 256, 0, stream>>>(Mbuf, vpx, psi_first, psi_last,
                                             vpsi, psiv, c, (done == 0) ? 1 : 0,
                                             (done + c == 62) ? 1 : 0);
        done += c;
      }
      done = 0;
      while (done < 62) {
        int c = imin(Cc, 62 - done);
        int phiBlk = (done == 0) ? c : -1;
        int gx = (done == 0) ? (c + 1) : c;
        k_chi_gemm<<<dim3(gx, 8), 256, 0, stream>>>(chi_mid, vch, Mbuf, done, phiBlk,
                                                    phisl, phi_first, phi_last, phiv);
        k_chi_chain<<<256, 64, 0, stream>>>(Mbuf, chi_first, chi_last, vch,
                                            psiv, phiv, vchi, out, c,
                                            (done == 0) ? 1 : 0,
                                            (done + c == 62) ? 1 : 0);
        done += c;
      }
    } else {
      k_reduce_x<<<16384 + 62, 256, 0, stream>>>(x, vch, nullptr, nullptr, nullptr,
                                                 phi_mid, phisl);
      k_psi_direct<<<256, 256, 0, stream>>>(x, psi_mid, psi_first, psi_last, psiv);
      k_phi_chain<<<1, 256, 0, stream>>>(phisl, phi_first, phi_last, phiv);
      k_chi_fused<<<64, 256, 0, stream>>>(chi_first, chi_mid, chi_last, vch, psiv, phiv, out);
    }
  }
}

// Round 13
// 289.171 us; speedup vs baseline: 6.0209x; 1.0429x over previous
//
#include <hip/hip_runtime.h>

// dims: L=64, CH=16, PIX=256, PAT=64, RC=32, BD=64, OUT=10, B=256
// inputs: 0=x(256,64,256,16) 1=chi_first(32,16) 2=chi_mid(62,32,32,16)
// 3=chi_last(32,16,10) 4=psi_first(64,256) 5=psi_mid(62,64,64,256)
// 6=psi_last(64,256) 7=phi_first(64,64) 8=phi_mid(62,64,64,64) 9=phi_last(64,64)

static inline int imin(int a, int b) { return a < b ? a : b; }

typedef __attribute__((ext_vector_type(8))) short bf16x8;          // 8 bf16 (4 VGPR)
typedef __attribute__((ext_vector_type(8))) unsigned short us8;
typedef __attribute__((ext_vector_type(4))) float f32x4;
typedef _Float16 f16;
typedef __attribute__((ext_vector_type(8))) _Float16 f16x8;

__device__ __forceinline__ unsigned short f2bf(float v) {
  union { float f; unsigned int u; } c; c.f = v;
  unsigned int u = c.u;
  unsigned int r = (u + 0x7fffu + ((u >> 16) & 1u)) >> 16;  // RTN-even
  return (unsigned short)r;
}
__device__ __forceinline__ float bf2f(unsigned short h) {
  union { unsigned int u; float f; } c; c.u = ((unsigned int)h) << 16;
  return c.f;
}

// ---------------------------------------------------------------------------
// K1: vpx means + bf16 hi/lo fragment emit + phi slice gather (bx >= 16384).
__global__ __launch_bounds__(256) void k_reduce_x(const float* __restrict__ x,
                                                  float* __restrict__ vch,
                                                  float* __restrict__ vpx,
                                                  unsigned short* __restrict__ vpxf_hi,
                                                  unsigned short* __restrict__ vpxf_lo,
                                                  const float* __restrict__ phi_mid,
                                                  float* __restrict__ slices) {
  if (blockIdx.x >= 16384) {                 // phi gather block
    int i = blockIdx.x - 16384;              // 0..61
    int t = threadIdx.x;
    #pragma unroll
    for (int k = 0; k < 16; ++k) {
      int idx = t + k * 256;                 // l*64 + r
      slices[(size_t)i * 4096 + idx] = phi_mid[((size_t)i * 4096 + idx) * 64 + (i + 1)];
    }
    return;
  }
  int bp = blockIdx.x;             // b*64 + s
  int b = bp >> 6, s = bp & 63;
  int q = threadIdx.x;             // = p
  const float* row = x + ((size_t)bp << 12) + q * 16;
  float4 r0 = *(const float4*)(row);
  float4 r1 = *(const float4*)(row + 4);
  float4 r2 = *(const float4*)(row + 8);
  float4 r3 = *(const float4*)(row + 12);
  float csum = r0.x + r0.y + r0.z + r0.w + r1.x + r1.y + r1.z + r1.w
             + r2.x + r2.y + r2.z + r2.w + r3.x + r3.y + r3.z + r3.w;
  float val = csum * (1.0f / 16.0f);
  if (vpx && (s == 0 || s == 63)) vpx[((size_t)s * 256 + b) * 256 + q] = val;
  if (vpxf_hi && s >= 1 && s <= 62) {
    unsigned short hb = f2bf(val);
    unsigned short lb = f2bf(val - bf2f(hb));
    size_t fa = (size_t)s * 65536
              + (((size_t)(q >> 5) * 16 + (b >> 4)) * 64 + (((q >> 3) & 3) * 16 + (b & 15))) * 8
              + (q & 7);
    vpxf_hi[fa] = hb;
    vpxf_lo[fa] = lb;
  }

  __shared__ float sc[256][20];
  *(float4*)&sc[q][0]  = r0;
  *(float4*)&sc[q][4]  = r1;
  *(float4*)&sc[q][8]  = r2;
  *(float4*)&sc[q][12] = r3;
  __syncthreads();
  int c = q & 15, g = q >> 4;
  float ps = 0.f;
  #pragma unroll
  for (int k = 0; k < 16; ++k) ps += sc[g * 16 + k][c];
  __shared__ float p2[16][17];
  p2[g][c] = ps;
  __syncthreads();
  if (q < 16) {
    float s2 = 0.f;
    #pragma unroll
    for (int k = 0; k < 16; ++k) s2 += p2[k][q];
    vch[((size_t)s * 256 + b) * 16 + q] = s2 * (1.0f / 256.0f);
  }
}

// ---------------------------------------------------------------------------
// psi gemm tile body (512 threads): site's W slab x A fragments -> M tile
// (fp16 output), padded-LDS transpose epilogue for 16B-coalesced stores.
__device__ __forceinline__ void psi_gemm_tile(const float* __restrict__ W,
                                              const unsigned short* __restrict__ Ahg,
                                              const unsigned short* __restrict__ Alg,
                                              f16* __restrict__ Mz,   // M + z*256*4096
                                              int lr0, int t,
                                              unsigned char* smem) {
  typedef unsigned short BArr[2][2][4][64][8];          // 16 KB each
  BArr& Bh = *reinterpret_cast<BArr*>(smem);
  BArr& Bl = *reinterpret_cast<BArr*>(smem + 16384);
  int lane = t & 63, w = t >> 6;
  int row = t >> 3, kg = t & 7;
  float4 sv0, sv1;

  #define LOADP(p) do {                                                      \
    const float* src = W + (size_t)(lr0 + row) * 256 + ((p) << 6) + kg * 8;  \
    sv0 = *(const float4*)src;                                               \
    sv1 = *(const float4*)(src + 4);                                         \
  } while (0)
  #define WRITEP(d) do {                                                     \
    float xs[8] = {sv0.x, sv0.y, sv0.z, sv0.w, sv1.x, sv1.y, sv1.z, sv1.w};  \
    us8 hv, lv;                                                              \
    _Pragma("unroll")                                                        \
    for (int i = 0; i < 8; ++i) {                                            \
      unsigned short hb = f2bf(xs[i]);                                       \
      hv[i] = hb;                                                            \
      lv[i] = f2bf(xs[i] - bf2f(hb));                                        \
    }                                                                        \
    int ck = kg >> 2, nt = row >> 4, ln = ((kg & 3) << 4) | (row & 15);      \
    *(us8*)&Bh[d][ck][nt][ln][0] = hv;                                       \
    *(us8*)&Bl[d][ck][nt][ln][0] = lv;                                       \
  } while (0)
  #define LOADA(slot, chunk) do {                                            \
    _Pragma("unroll")                                                        \
    for (int mi = 0; mi < 2; ++mi) {                                         \
      size_t fo = ((size_t)(chunk) * 16 + (w * 2 + mi)) * 512 + (size_t)lane * 8; \
      Ah[slot][mi] = *(const bf16x8*)(Ahg + fo);                             \
      Al[slot][mi] = *(const bf16x8*)(Alg + fo);                             \
    }                                                                        \
  } while (0)

  f32x4 acc[2][4];
  #pragma unroll
  for (int i = 0; i < 2; ++i)
    #pragma unroll
    for (int j = 0; j < 4; ++j) acc[i][j] = (f32x4){0.f, 0.f, 0.f, 0.f};
  bf16x8 Ah[2][2], Al[2][2];

  LOADA(0, 0);
  LOADP(0);
  WRITEP(0);
  __syncthreads();
  #pragma unroll
  for (int p = 0; p < 4; ++p) {
    if (p < 3) LOADP(p + 1);
    #pragma unroll
    for (int c = 0; c < 2; ++c) {
      const int chunk = p * 2 + c;
      const int cur = chunk & 1, nxt = (chunk + 1) & 1;
      if (chunk < 7) LOADA(nxt, chunk + 1);
      #pragma unroll
      for (int n = 0; n < 4; ++n) {
        bf16x8 bh = *(const bf16x8*)&Bh[p & 1][c][n][lane][0];
        bf16x8 bl = *(const bf16x8*)&Bl[p & 1][c][n][lane][0];
        #pragma unroll
        for (int mi = 0; mi < 2; ++mi) {
          acc[mi][n] = __builtin_amdgcn_mfma_f32_16x16x32_bf16(Ah[cur][mi], bh, acc[mi][n], 0, 0, 0);
          acc[mi][n] = __builtin_amdgcn_mfma_f32_16x16x32_bf16(Al[cur][mi], bh, acc[mi][n], 0, 0, 0);
          acc[mi][n] = __builtin_amdgcn_mfma_f32_16x16x32_bf16(Ah[cur][mi], bl, acc[mi][n], 0, 0, 0);
        }
      }
    }
    if (p < 3) WRITEP((p + 1) & 1);
    __syncthreads();
  }
  #undef LOADP
  #undef WRITEP
  #undef LOADA

  // transpose epilogue: acc -> LDS T[128][72] f16 (padded rows, 144B = 9x16B
  // so f16x8 loads stay 16B-aligned) -> coalesced f16x8 global stores.
  int rg = lane >> 4, cidx = lane & 15;
  f16 (*T)[72] = reinterpret_cast<f16 (*)[72]>(smem);   // 18432 B
  #pragma unroll
  for (int pass = 0; pass < 2; ++pass) {
    if ((w >> 2) == pass) {
      #pragma unroll
      for (int mi = 0; mi < 2; ++mi) {
        int rowb = (((w & 3) * 2 + mi) * 16) + rg * 4;
        #pragma unroll
        for (int n = 0; n < 4; ++n) {
          #pragma unroll
          for (int r = 0; r < 4; ++r) {
            T[rowb + r][n * 16 + cidx] = (f16)acc[mi][n][r];
          }
        }
      }
    }
    __syncthreads();
    int boff = pass * 128;
    #pragma unroll
    for (int k = 0; k < 2; ++k) {
      int f = t + k * 512;            // f16x8 unit 0..1023
      int b2 = f >> 3;                // 0..127
      int l8 = (f & 7) * 8;           // 0..56
      *(f16x8*)(Mz + ((size_t)(boff + b2)) * 4096 + lr0 + l8) =
          *(const f16x8*)&T[b2][l8];
    }
    __syncthreads();
  }
}

// ---------------------------------------------------------------------------
// K2 (mega_A): bx==0 phi chain; bx 1..496 chi gemm; bx>=497 psi gemm sites 0..31.
__global__ __launch_bounds__(512) void k_mega_A(const float* __restrict__ psi_mid,
                                                const unsigned short* __restrict__ vpxf_hi,
                                                const unsigned short* __restrict__ vpxf_lo,
                                                f16* __restrict__ M,
                                                const float* __restrict__ chi_mid,
                                                const float* __restrict__ vch,
                                                float* __restrict__ Tc,
                                                const float* __restrict__ slices,
                                                const float* __restrict__ phi_first,
                                                const float* __restrict__ phi_last,
                                                float* __restrict__ phiv) {
  int bx = blockIdx.x;
  int t = threadIdx.x;
  if (bx == 0) {
    // phi chain (512-thread, barriered)
    int r = t & 63, g = t >> 6;
    __shared__ float u[64];
    __shared__ float part[8][64];
    __shared__ float red[64];
    if (t < 64) u[t] = phi_first[t * 64];
    __syncthreads();
    for (int i2 = 0; i2 < 62; ++i2) {
      float sum = 0.f;
      #pragma unroll
      for (int j = 0; j < 8; ++j) {
        int l = g * 8 + j;
        sum += u[l] * slices[(size_t)i2 * 4096 + l * 64 + r];
      }
      part[g][r] = sum;
      __syncthreads();
      if (g == 0) u[r] = part[0][r] + part[1][r] + part[2][r] + part[3][r]
                       + part[4][r] + part[5][r] + part[6][r] + part[7][r];
      __syncthreads();
    }
    if (t < 64) red[t] = u[t] * phi_last[t * 64 + 63];
    __syncthreads();
    if (t == 0) {
      float s = 0.f;
      for (int l = 0; l < 64; ++l) s += red[l];
      *phiv = s;
    }
  } else if (bx <= 496) {
    // chi gemm: Tc[z][b][r*32+l] (fp32)
    int i = bx - 1;
    int z = i >> 3;                 // site 0..61
    int b0 = (i & 7) * 32;
    __shared__ float uv[32][16];
    if (t < 128) {
      int idx = t * 4;
      int b = idx >> 4, c = idx & 15;
      *(float4*)&uv[b][c] = *(const float4*)(vch + ((size_t)(z + 1) * 256 + b0 + b) * 16 + c);
    }
    __syncthreads();
    #pragma unroll
    for (int k = 0; k < 2; ++k) {
      int idx = t + k * 512;         // output index = r*32 + l
      int r = idx >> 5, l = idx & 31;
      const float* Wp = chi_mid + ((size_t)z * 1024 + l * 32 + r) * 16;
      float4 w0 = *(const float4*)(Wp);
      float4 w1 = *(const float4*)(Wp + 4);
      float4 w2 = *(const float4*)(Wp + 8);
      float4 w3 = *(const float4*)(Wp + 12);
      for (int b = 0; b < 32; ++b) {
        const float* u = uv[b];
        float d = w0.x * u[0] + w0.y * u[1] + w0.z * u[2] + w0.w * u[3]
                + w1.x * u[4] + w1.y * u[5] + w1.z * u[6] + w1.w * u[7]
                + w2.x * u[8] + w2.y * u[9] + w2.z * u[10] + w2.w * u[11]
                + w3.x * u[12] + w3.y * u[13] + w3.z * u[14] + w3.w * u[15];
        Tc[((size_t)z * 256 + b0 + b) * 1024 + idx] = d;
      }
    }
  } else {
    int idx = bx - 497;
    int z = idx >> 6;               // site 0..31
    int lr0 = (idx & 63) * 64;
    __shared__ __align__(16) unsigned char smem[32768];
    psi_gemm_tile(psi_mid + (size_t)z * 4096 * 256,
                  vpxf_hi + (size_t)(z + 1) * 65536,
                  vpxf_lo + (size_t)(z + 1) * 65536,
                  M + (size_t)z * 256 * 4096, lr0, t, smem);
  }
}

// ---------------------------------------------------------------------------
// K3 (mega_B): bx<256 psi chain part1 (sites 0..31, LDS-grouped, low-VGPR);
// bx 256..511 chi chain full; bx>=512 psi gemm sites 32..61.
__global__ __launch_bounds__(512) void k_mega_B(const float* __restrict__ psi_mid,
                                                const unsigned short* __restrict__ vpxf_hi,
                                                const unsigned short* __restrict__ vpxf_lo,
                                                f16* __restrict__ M,
                                                const float* __restrict__ Tc,
                                                const float* __restrict__ vpx,
                                                const float* __restrict__ vch,
                                                const float* __restrict__ psi_first,
                                                const float* __restrict__ chi_first,
                                                const float* __restrict__ chi_last,
                                                float* __restrict__ vpsi,
                                                float* __restrict__ chiout) {
  int bx = blockIdx.x;
  int t = threadIdx.x;
  if (bx < 256) {
    // psi chain part 1: sites 0..31 (even count), 512 threads, 8 l-groups.
    int b = bx;
    int r = t & 63, g = t >> 6;
    __shared__ float vsh[64];
    __shared__ float part[8][64];
    {
      const float* u0 = vpx + (size_t)b * 256;
      const float* pf = psi_first + r * 256 + g * 32;
      float s0 = 0.f;
      #pragma unroll
      for (int p = 0; p < 32; ++p) s0 += pf[p] * u0[g * 32 + p];
      part[g][r] = s0;
      __syncthreads();
      if (g == 0) {
        float sv = 0.f;
        #pragma unroll
        for (int k = 0; k < 8; ++k) sv += part[k][r];
        vsh[r] = sv;
      }
      __syncthreads();
    }
    #define QLOAD(buf, sc) do {                                                \
      const f16* Mb = M + ((size_t)(sc) * 256 + b) * 4096 + r;                 \
      _Pragma("unroll")                                                        \
      for (int j = 0; j < 8; ++j) buf[j] = (float)Mb[(size_t)(g * 8 + j) * 64]; \
    } while (0)
    #define QSTEP(buf) do {                                                    \
      float sum = 0.f;                                                         \
      _Pragma("unroll")                                                        \
      for (int j = 0; j < 8; ++j) sum += vsh[g * 8 + j] * buf[j];              \
      part[g][r] = sum;                                                        \
      __syncthreads();                                                         \
      if (g == 0) {                                                            \
        float sv = 0.f;                                                        \
        _Pragma("unroll")                                                      \
        for (int k = 0; k < 8; ++k) sv += part[k][r];                          \
        vsh[r] = sv;                                                           \
      }                                                                        \
      __syncthreads();                                                         \
    } while (0)
    float bufA[8], bufB[8];
    QLOAD(bufA, 0);
    #pragma unroll 1
    for (int sc = 0; sc < 32; sc += 2) {
      QLOAD(bufB, sc + 1);
      QSTEP(bufA);
      if (sc + 2 < 32) QLOAD(bufA, sc + 2);
      QSTEP(bufB);
    }
    #undef QLOAD
    #undef QSTEP
    if (g == 0) vpsi[b * 64 + r] = vsh[r];
  } else if (bx < 512) {
    // chi chain (full 62 sites), 1 wave, reg+shfl, no barriers.
    if (t >= 64) return;
    int b = bx - 256;
    int lane = t;
    int r = lane & 31, h = lane >> 5;
    float v;
    {
      const float* u0 = vch + (size_t)b * 16;    // site 0
      const float* cf = chi_first + r * 16;
      float s0 = 0.f;
      #pragma unroll
      for (int c = 0; c < 16; ++c) s0 += cf[c] * u0[c];
      v = s0;                                    // same in both halves
    }
    #define CLOADX(buf, sc) do {                                               \
      const float* Mb = Tc + ((size_t)(sc) * 256 + b) * 1024 + r * 32 + h * 16; \
      *(float4*)&buf[0]  = *(const float4*)(Mb);                               \
      *(float4*)&buf[4]  = *(const float4*)(Mb + 4);                           \
      *(float4*)&buf[8]  = *(const float4*)(Mb + 8);                           \
      *(float4*)&buf[12] = *(const float4*)(Mb + 12);                          \
    } while (0)
    #define CSTEPX(buf) do {                                                   \
      float s0 = 0.f, s1 = 0.f;                                                \
      _Pragma("unroll")                                                        \
      for (int j = 0; j < 8; ++j) {                                            \
        s0 += __shfl(v, h * 16 + 2 * j)     * buf[2 * j];                      \
        s1 += __shfl(v, h * 16 + 2 * j + 1) * buf[2 * j + 1];                  \
      }                                                                        \
      float sum = s0 + s1;                                                     \
      sum += __shfl_xor(sum, 32);                                              \
      v = sum;                                                                 \
    } while (0)
    {
      float mjA[16], mjB[16];
      CLOADX(mjA, 0);
      #pragma unroll 1
      for (int sc = 0; sc < 62; sc += 2) {
        CLOADX(mjB, sc + 1);
        CSTEPX(mjA);
        if (sc + 2 < 62) CLOADX(mjA, sc + 2);
        CSTEPX(mjB);
      }
    }
    #undef CLOADX
    #undef CSTEPX
    const float* u63 = vch + ((size_t)63 * 256 + b) * 16;
    float uc[16];
    #pragma unroll
    for (int c = 0; c < 16; ++c) uc[c] = u63[c];
    for (int o = 0; o < 10; ++o) {
      const float* cl = chi_last + r * 16 * 10 + o;
      float wv = 0.f;
      #pragma unroll
      for (int c = 0; c < 16; ++c) wv += cl[c * 10] * uc[c];
      float p = v * wv;                          // duplicated across halves
      #pragma unroll
      for (int m = 32; m > 0; m >>= 1) p += __shfl_xor(p, m);
      if (lane == 0) chiout[b * 10 + o] = p * 0.5f;
    }
  } else {
    int idx = bx - 512;
    int z = 32 + (idx >> 6);        // site 32..61
    int lr0 = (idx & 63) * 64;
    __shared__ __align__(16) unsigned char smem[32768];
    psi_gemm_tile(psi_mid + (size_t)z * 4096 * 256,
                  vpxf_hi + (size_t)(z + 1) * 65536,
                  vpxf_lo + (size_t)(z + 1) * 65536,
                  M + (size_t)z * 256 * 4096, lr0, t, smem);
  }
}

// ---------------------------------------------------------------------------
// K4: psi chain part 2 (sites 32..61, deep 64x2 register prefetch) + fused
// combine epilogue (out = chiout * psiv * phiv). 256 blocks x 64 threads.
__global__ __launch_bounds__(64) void k_chain_tail(const f16* __restrict__ M,
                                                   const float* __restrict__ vpx,
                                                   const float* __restrict__ psi_last,
                                                   const float* __restrict__ chiout,
                                                   const float* __restrict__ phiv,
                                                   const float* __restrict__ vpsi,
                                                   float* __restrict__ out) {
  int b = blockIdx.x;
  int lane = threadIdx.x;
  float v = vpsi[b * 64 + lane];
  #define MLOAD(buf, sc) do {                                                \
    const f16* Mb = M + ((size_t)(32 + (sc)) * 256 + b) * 4096 + lane;       \
    _Pragma("unroll")                                                        \
    for (int l = 0; l < 64; ++l) buf[l] = (float)Mb[(size_t)l * 64];         \
  } while (0)
  #define MSTEP(buf) do {                                                    \
    float s0 = 0.f, s1 = 0.f, s2 = 0.f, s3 = 0.f;                            \
    _Pragma("unroll")                                                        \
    for (int l = 0; l < 16; ++l) {                                           \
      s0 += __shfl(v, 4 * l + 0) * buf[4 * l + 0];                           \
      s1 += __shfl(v, 4 * l + 1) * buf[4 * l + 1];                           \
      s2 += __shfl(v, 4 * l + 2) * buf[4 * l + 2];                           \
      s3 += __shfl(v, 4 * l + 3) * buf[4 * l + 3];                           \
    }                                                                        \
    v = (s0 + s1) + (s2 + s3);                                               \
  } while (0)
  {
    float mvA[64], mvB[64];
    MLOAD(mvA, 0);
    #pragma unroll 1
    for (int sc = 0; sc < 30; sc += 2) {      // 30 even: pairs complete
      MLOAD(mvB, sc + 1);
      MSTEP(mvA);
      if (sc + 2 < 30) MLOAD(mvA, sc + 2);
      MSTEP(mvB);
    }
  }
  #undef MLOAD
  #undef MSTEP
  // psi_val = sum_p (sum_l v[l] psi_last[l][p]) * vpx[63][b][p]
  float acc_p = 0.f;
  #pragma unroll
  for (int pp = 0; pp < 4; ++pp) {
    int p = pp * 64 + lane;
    float pl[64];
    #pragma unroll
    for (int l = 0; l < 64; ++l) pl[l] = psi_last[l * 256 + p];
    float s0 = 0.f, s1 = 0.f, s2 = 0.f, s3 = 0.f;
    #pragma unroll
    for (int l = 0; l < 16; ++l) {
      s0 += __shfl(v, 4 * l + 0) * pl[4 * l + 0];
      s1 += __shfl(v, 4 * l + 1) * pl[4 * l + 1];
      s2 += __shfl(v, 4 * l + 2) * pl[4 * l + 2];
      s3 += __shfl(v, 4 * l + 3) * pl[4 * l + 3];
    }
    float wv = (s0 + s1) + (s2 + s3);
    acc_p += wv * vpx[((size_t)63 * 256 + b) * 256 + p];
  }
  #pragma unroll
  for (int m = 32; m > 0; m >>= 1) acc_p += __shfl_xor(acc_p, m);
  // fused combine: acc_p (psiv) is in all lanes
  if (lane < 10) out[b * 10 + lane] = chiout[b * 10 + lane] * acc_p * phiv[0];
}

// ---------------------------------------------------------------------------
// ===== Fallback tier (smaller workspace): chunked pipeline, fp16 M =====
__global__ __launch_bounds__(512) void k_psi_gemm(const float* __restrict__ psi_mid,
                                                  const unsigned short* __restrict__ vpxf_hi,
                                                  const unsigned short* __restrict__ vpxf_lo,
                                                  f16* __restrict__ M, int s0) {
  int z = blockIdx.z;
  int s = s0 + z;
  int lr0 = blockIdx.x * 64;
  __shared__ __align__(16) unsigned char smem[32768];
  psi_gemm_tile(psi_mid + (size_t)s * 4096 * 256,
                vpxf_hi + (size_t)(s + 1) * 65536,
                vpxf_lo + (size_t)(s + 1) * 65536,
                M + (size_t)z * 256 * 4096, lr0, threadIdx.x, smem);
}

__global__ __launch_bounds__(256) void k_psi_chain(const f16* __restrict__ M,
                                                   const float* __restrict__ vpx,
                                                   const float* __restrict__ psi_first,
                                                   const float* __restrict__ psi_last,
                                                   float* __restrict__ vpsi,
                                                   float* __restrict__ psiv,
                                                   int nS, int isFirst, int isLast) {
  int b = blockIdx.x;
  int t = threadIdx.x;
  int r = t & 63, g = t >> 6;
  __shared__ float v[64];
  __shared__ float part[4][64];
  __shared__ float red[256];
  if (isFirst) {
    const float* u0 = vpx + (size_t)b * 256;
    float s0 = 0.f;
    for (int p = g * 64; p < g * 64 + 64; ++p) s0 += psi_first[r * 256 + p] * u0[p];
    part[g][r] = s0;
    __syncthreads();
    if (g == 0) v[r] = part[0][r] + part[1][r] + part[2][r] + part[3][r];
    __syncthreads();
  } else {
    if (g == 0) v[r] = vpsi[b * 64 + r];
    __syncthreads();
  }
  for (int sc = 0; sc < nS; ++sc) {
    const f16* Mb = M + ((size_t)sc * 256 + b) * 4096;
    float sum = 0.f;
    #pragma unroll
    for (int j = 0; j < 16; ++j) {
      int l = g * 16 + j;
      sum += v[l] * (float)Mb[l * 64 + r];
    }
    part[g][r] = sum;
    __syncthreads();
    if (g == 0) v[r] = part[0][r] + part[1][r] + part[2][r] + part[3][r];
    __syncthreads();
  }
  if (isLast) {
    float qv = 0.f;
    for (int l = 0; l < 64; ++l) qv += v[l] * psi_last[l * 256 + t];
    red[t] = qv * vpx[((size_t)63 * 256 + b) * 256 + t];
    __syncthreads();
    for (int off = 128; off > 0; off >>= 1) {
      if (t < off) red[t] += red[t + off];
      __syncthreads();
    }
    if (t == 0) psiv[b] = red[0];
  } else {
    if (g == 0) vpsi[b * 64 + r] = v[r];
  }
}

__device__ __forceinline__ void phi_chain_body(const float* __restrict__ slices,
                                               const float* __restrict__ phi_first,
                                               const float* __restrict__ phi_last,
                                               float* __restrict__ phiv) {
  int t = threadIdx.x;
  int r = t & 63, g = t >> 6;
  __shared__ float u[64];
  __shared__ float part[4][64];
  __shared__ float red[64];
  if (t < 64) u[t] = phi_first[t * 64];
  __syncthreads();
  for (int i = 0; i < 62; ++i) {
    float sum = 0.f;
    #pragma unroll
    for (int j = 0; j < 16; ++j) {
      int l = g * 16 + j;
      sum += u[l] * slices[(size_t)i * 4096 + l * 64 + r];
    }
    part[g][r] = sum;
    __syncthreads();
    if (g == 0) u[r] = part[0][r] + part[1][r] + part[2][r] + part[3][r];
    __syncthreads();
  }
  if (t < 64) red[t] = u[t] * phi_last[t * 64 + 63];
  __syncthreads();
  if (t == 0) {
    float s = 0.f;
    for (int l = 0; l < 64; ++l) s += red[l];
    *phiv = s;
  }
}

__global__ __launch_bounds__(256) void k_phi_chain(const float* __restrict__ slices,
                                                   const float* __restrict__ phi_first,
                                                   const float* __restrict__ phi_last,
                                                   float* __restrict__ phiv) {
  phi_chain_body(slices, phi_first, phi_last, phiv);
}

__global__ __launch_bounds__(256) void k_chi_gemm(const float* __restrict__ chi_mid,
                                                  const float* __restrict__ vch,
                                                  float* __restrict__ Tc, int s0,
                                                  int phiBlock,
                                                  const float* __restrict__ slices,
                                                  const float* __restrict__ phi_first,
                                                  const float* __restrict__ phi_last,
                                                  float* __restrict__ phiv) {
  if ((int)blockIdx.x == phiBlock) {
    if (blockIdx.y == 0) phi_chain_body(slices, phi_first, phi_last, phiv);
    return;
  }
  int z = blockIdx.x;
  int s = s0 + z;
  int b0 = blockIdx.y * 32;
  int t = threadIdx.x;
  __shared__ float uv[32][16];
  if (t < 128) {
    int idx = t * 4;
    int b = idx >> 4, c = idx & 15;
    *(float4*)&uv[b][c] = *(const float4*)(vch + ((size_t)(s + 1) * 256 + b0 + b) * 16 + c);
  }
  __syncthreads();
  #pragma unroll
  for (int k = 0; k < 4; ++k) {
    int idx = t + k * 256;
    int r = idx >> 5, l = idx & 31;
    const float* Wp = chi_mid + ((size_t)s * 1024 + l * 32 + r) * 16;
    float4 w0 = *(const float4*)(Wp);
    float4 w1 = *(const float4*)(Wp + 4);
    float4 w2 = *(const float4*)(Wp + 8);
    float4 w3 = *(const float4*)(Wp + 12);
    for (int b = 0; b < 32; ++b) {
      const float* u = uv[b];
      float d = w0.x * u[0] + w0.y * u[1] + w0.z * u[2] + w0.w * u[3]
              + w1.x * u[4] + w1.y * u[5] + w1.z * u[6] + w1.w * u[7]
              + w2.x * u[8] + w2.y * u[9] + w2.z * u[10] + w2.w * u[11]
              + w3.x * u[12] + w3.y * u[13] + w3.z * u[14] + w3.w * u[15];
      Tc[((size_t)z * 256 + b0 + b) * 1024 + idx] = d;
    }
  }
}

__global__ __launch_bounds__(64) void k_chi_chain(const float* __restrict__ Tc,
                                                  const float* __restrict__ chi_first,
                                                  const float* __restrict__ chi_last,
                                                  const float* __restrict__ vch,
                                                  const float* __restrict__ psiv,
                                                  const float* __restrict__ phiv,
                                                  float* __restrict__ vchi,
                                                  float* __restrict__ out,
                                                  int nS, int isFirst, int isLast) {
  int b = blockIdx.x;
  int lane = threadIdx.x;
  int r = lane & 31, h = lane >> 5;
  __shared__ float v[32];
  if (isFirst) {
    if (h == 0) {
      const float* u0 = vch + (size_t)b * 16;
      const float* cf = chi_first + r * 16;
      float s0 = 0.f;
      #pragma unroll
      for (int c = 0; c < 16; ++c) s0 += cf[c] * u0[c];
      v[r] = s0;
    }
  } else {
    if (h == 0) v[r] = vchi[b * 32 + r];
  }
  __syncthreads();
  for (int sc = 0; sc < nS; ++sc) {
    const float* Mb = Tc + ((size_t)sc * 256 + b) * 1024 + r * 32 + h * 16;
    float4 m0 = *(const float4*)(Mb);
    float4 m1 = *(const float4*)(Mb + 4);
    float4 m2 = *(const float4*)(Mb + 8);
    float4 m3 = *(const float4*)(Mb + 12);
    const float* vv = &v[h * 16];
    float sum = m0.x * vv[0] + m0.y * vv[1] + m0.z * vv[2] + m0.w * vv[3]
              + m1.x * vv[4] + m1.y * vv[5] + m1.z * vv[6] + m1.w * vv[7]
              + m2.x * vv[8] + m2.y * vv[9] + m2.z * vv[10] + m2.w * vv[11]
              + m3.x * vv[12] + m3.y * vv[13] + m3.z * vv[14] + m3.w * vv[15];
    sum += __shfl_xor(sum, 32);
    __syncthreads();
    if (h == 0) v[r] = sum;
    __syncthreads();
  }
  if (isLast) {
    const float* u63 = vch + ((size_t)63 * 256 + b) * 16;
    float uc[16];
    #pragma unroll
    for (int c = 0; c < 16; ++c) uc[c] = u63[c];
    float scale = 0.5f * psiv[b] * phiv[0];
    for (int o = 0; o < 10; ++o) {
      const float* cl = chi_last + r * 16 * 10 + o;
      float w = 0.f;
      #pragma unroll
      for (int c = 0; c < 16; ++c) w += cl[c * 10] * uc[c];
      float p = v[r] * w;
      #pragma unroll
      for (int m = 32; m > 0; m >>= 1) p += __shfl_xor(p, m);
      if (lane == 0) out[b * 10 + o] = p * scale;
    }
  } else {
    if (h == 0) vchi[b * 32 + r] = v[r];
  }
}

__global__ __launch_bounds__(256) void k_chi_fused(const float* __restrict__ chi_first,
                                                   const float* __restrict__ chi_mid,
                                                   const float* __restrict__ chi_last,
                                                   const float* __restrict__ vch,
                                                   const float* __restrict__ psiv,
                                                   const float* __restrict__ phiv,
                                                   float* __restrict__ out) {
  int t = threadIdx.x;
  int bl = t >> 6, lg = (t >> 5) & 1, r = t & 31;
  int b = blockIdx.x * 4 + bl;
  __shared__ float v[4][32];
  __shared__ float part[4][2][32];
  if (lg == 0) {
    const float* u0 = vch + (size_t)b * 16;
    float s0 = 0.f;
    #pragma unroll
    for (int c = 0; c < 16; ++c) s0 += chi_first[r * 16 + c] * u0[c];
    v[bl][r] = s0;
  }
  __syncthreads();
  for (int s = 0; s < 62; ++s) {
    const float* u = vch + ((size_t)(s + 1) * 256 + b) * 16;
    float uc[16];
    #pragma unroll
    for (int c = 0; c < 16; ++c) uc[c] = u[c];
    const float* W = chi_mid + (size_t)s * 32 * 32 * 16;
    float sum = 0.f;
    #pragma unroll
    for (int j = 0; j < 16; ++j) {
      int l = lg * 16 + j;
      const float* Wl = W + ((size_t)l * 32 + r) * 16;
      float tt = 0.f;
      #pragma unroll
      for (int c = 0; c < 16; ++c) tt += Wl[c] * uc[c];
      sum += v[bl][l] * tt;
    }
    part[bl][lg][r] = sum;
    __syncthreads();
    if (lg == 0) v[bl][r] = part[bl][0][r] + part[bl][1][r];
    __syncthreads();
  }
  const float* u63 = vch + ((size_t)63 * 256 + b) * 16;
  float uc[16];
  #pragma unroll
  for (int c = 0; c < 16; ++c) uc[c] = u63[c];
  if (r < 10) {
    float acc = 0.f;
    #pragma unroll
    for (int j = 0; j < 16; ++j) {
      int l = lg * 16 + j;
      const float* cl = chi_last + (size_t)l * 16 * 10;
      float tt = 0.f;
      #pragma unroll
      for (int c = 0; c < 16; ++c) tt += cl[c * 10 + r] * uc[c];
      acc += v[bl][l] * tt;
    }
    part[bl][lg][r] = acc;
  }
  __syncthreads();
  if (lg == 0 && r < 10)
    out[b * 10 + r] = (part[bl][0][r] + part[bl][1][r]) * psiv[b] * phiv[0];
}

__global__ __launch_bounds__(256) void k_psi_direct(const float* __restrict__ x,
                                                    const float* __restrict__ psi_mid,
                                                    const float* __restrict__ psi_first,
                                                    const float* __restrict__ psi_last,
                                                    float* __restrict__ psiv) {
  int b = blockIdx.x;
  int t = threadIdx.x;
  int r = t & 63, g = t >> 6;
  __shared__ float u[256];
  __shared__ float v[64];
  __shared__ float part[4][64];
  __shared__ float red[256];
  const float* xb = x + ((size_t)b << 18);
  {
    const float* rw = xb + (size_t)0 * 4096 + t * 16;
    float sm = 0.f;
    #pragma unroll
    for (int c = 0; c < 16; ++c) sm += rw[c];
    u[t] = sm * (1.0f / 16.0f);
  }
  __syncthreads();
  {
    float s0 = 0.f;
    for (int p = g * 64; p < g * 64 + 64; ++p) s0 += psi_first[r * 256 + p] * u[p];
    part[g][r] = s0;
    __syncthreads();
    if (g == 0) v[r] = part[0][r] + part[1][r] + part[2][r] + part[3][r];
  }
  __syncthreads();
  for (int s = 0; s < 62; ++s) {
    __syncthreads();
    {
      const float* rw = xb + (size_t)(s + 1) * 4096 + t * 16;
      float sm = 0.f;
      #pragma unroll
      for (int c = 0; c < 16; ++c) sm += rw[c];
      u[t] = sm * (1.0f / 16.0f);
    }
    __syncthreads();
    const float* W = psi_mid + (size_t)s * 4096 * 256;
    float sum = 0.f;
    for (int l = 0; l < 64; ++l) {
      const float* Wl = W + ((size_t)(l * 64 + r)) * 256 + g * 64;
      float tt = 0.f;
      #pragma unroll 8
      for (int k = 0; k < 64; ++k) tt += Wl[k] * u[g * 64 + k];
      sum += v[l] * tt;
    }
    part[g][r] = sum;
    __syncthreads();
    if (g == 0) v[r] = part[0][r] + part[1][r] + part[2][r] + part[3][r];
    __syncthreads();
  }
  __syncthreads();
  {
    const float* rw = xb + (size_t)63 * 4096 + t * 16;
    float sm = 0.f;
    #pragma unroll
    for (int c = 0; c < 16; ++c) sm += rw[c];
    u[t] = sm * (1.0f / 16.0f);
  }
  __syncthreads();
  float qv = 0.f;
  for (int l = 0; l < 64; ++l) qv += v[l] * psi_last[l * 256 + t];
  red[t] = qv * u[t];
  __syncthreads();
  for (int off = 128; off > 0; off >>= 1) {
    if (t < off) red[t] += red[t + off];
    __syncthreads();
  }
  if (t == 0) psiv[b] = red[0];
}

// ---------------------------------------------------------------------------
extern "C" void kernel_launch(void* const* d_in, const int* in_sizes, int n_in,
                              void* d_out, int out_size, void* d_ws, size_t ws_size,
                              hipStream_t stream) {
  const float* x         = (const float*)d_in[0];
  const float* chi_first = (const float*)d_in[1];
  const float* chi_mid   = (const float*)d_in[2];
  const float* chi_last  = (const float*)d_in[3];
  const float* psi_first = (const float*)d_in[4];
  const float* psi_mid   = (const float*)d_in[5];
  const float* psi_last  = (const float*)d_in[6];
  const float* phi_first = (const float*)d_in[7];
  const float* phi_mid   = (const float*)d_in[8];
  const float* phi_last  = (const float*)d_in[9];
  float* out = (float*)d_out;
  float* ws  = (float*)d_ws;

  size_t wsf = ws_size / 4;
  size_t off = 0;
  float* vch    = ws + off; off += (size_t)64 * 256 * 16;     // 262144
  float* psiv   = ws + off; off += 256;
  float* chiout = ws + off; off += 2560;
  float* phisl  = ws + off; off += (size_t)62 * 64 * 64;      // 253952
  float* phiv   = ws + off; off += 16;
  float* vpsi   = ws + off; off += (size_t)64 * 256;          // 16384
  float* vchi   = ws + off; off += (size_t)32 * 256;          // 8192
  float* vpx    = ws + off; off += (size_t)64 * 256 * 256;    // 4194304
  unsigned short* vpxf_hi = (unsigned short*)(ws + off); off += (size_t)64 * 65536 / 2;
  unsigned short* vpxf_lo = (unsigned short*)(ws + off); off += (size_t)64 * 65536 / 2;
  f16* Mbuf = (f16*)(ws + off);                               // fp16 M
  size_t needMh  = (size_t)62 * 256 * 4096;                   // halves
  float* Tcbuf = (float*)(Mbuf + needMh);
  size_t needTc = (size_t)62 * 256 * 1024;                    // floats
  size_t bytes_needed = off * 4 + needMh * 2 + needTc * 4;

  if (ws_size >= bytes_needed) {
    // ===== Pipelined path: reduce -> [gemmA+chiGemm+phi] -> [gemmB || chains] -> tail
    k_reduce_x<<<16384 + 62, 256, 0, stream>>>(x, vch, vpx, vpxf_hi, vpxf_lo,
                                               phi_mid, phisl);
    k_mega_A<<<497 + 2048, 512, 0, stream>>>(psi_mid, vpxf_hi, vpxf_lo, Mbuf,
                                             chi_mid, vch, Tcbuf,
                                             phisl, phi_first, phi_last, phiv);
    k_mega_B<<<512 + 1920, 512, 0, stream>>>(psi_mid, vpxf_hi, vpxf_lo, Mbuf,
                                             Tcbuf, vpx, vch, psi_first,
                                             chi_first, chi_last, vpsi, chiout);
    k_chain_tail<<<256, 64, 0, stream>>>(Mbuf, vpx, psi_last, chiout, phiv,
                                         vpsi, out);
  } else {
    size_t avail_b = (ws_size > off * 4) ? ws_size - off * 4 : 0;
    int C = (int)(avail_b / ((size_t)256 * 4096 * 2));        // fp16 M sites
    if (C > 62) C = 62;
    int Cc = (int)(avail_b / ((size_t)256 * 1024 * 4));       // fp32 Tc sites
    if (Cc > 62) Cc = 62;
    if (C >= 1) {
      k_reduce_x<<<16384 + 62, 256, 0, stream>>>(x, vch, vpx, vpxf_hi, vpxf_lo,
                                                 phi_mid, phisl);
      int done = 0;
      while (done < 62) {
        int c = imin(C, 62 - done);
        k_psi_gemm<<<dim3(64, 1, c), 512, 0, stream>>>(psi_mid, vpxf_hi, vpxf_lo, Mbuf, done);
        k_psi_chain<<<256, 256, 0, stream>>>(Mbuf, vpx, psi_first, psi_last,
                                             vpsi, psiv, c, (done == 0) ? 1 : 0,
                                             (done + c == 62) ? 1 : 0);
        done += c;
      }
      done = 0;
      while (done < 62) {
        int c = imin(Cc, 62 - done);
        int phiBlk = (done == 0) ? c : -1;
        int gx = (done == 0) ? (c + 1) : c;
        k_chi_gemm<<<dim3(gx, 8), 256, 0, stream>>>(chi_mid, vch, (float*)Mbuf, done, phiBlk,
                                                    phisl, phi_first, phi_last, phiv);
        k_chi_chain<<<256, 64, 0, stream>>>((float*)Mbuf, chi_first, chi_last, vch,
                                            psiv, phiv, vchi, out, c,
                                            (done == 0) ? 1 : 0,
                                            (done + c == 62) ? 1 : 0);
        done += c;
      }
    } else {
      k_reduce_x<<<16384 + 62, 256, 0, stream>>>(x, vch, nullptr, nullptr, nullptr,
                                                 phi_mid, phisl);
      k_psi_direct<<<256, 256, 0, stream>>>(x, psi_mid, psi_first, psi_last, psiv);
      k_phi_chain<<<1, 256, 0, stream>>>(phisl, phi_first, phi_last, phiv);
      k_chi_fused<<<64, 256, 0, stream>>>(chi_first, chi_mid, chi_last, vch, psiv, phiv, out);
    }
  }
}

// Round 14
// 253.736 us; speedup vs baseline: 6.8617x; 1.1397x over previous
//
#include <hip/hip_runtime.h>

// dims: L=64, CH=16, PIX=256, PAT=64, RC=32, BD=64, OUT=10, B=256
// inputs: 0=x(256,64,256,16) 1=chi_first(32,16) 2=chi_mid(62,32,32,16)
// 3=chi_last(32,16,10) 4=psi_first(64,256) 5=psi_mid(62,64,64,256)
// 6=psi_last(64,256) 7=phi_first(64,64) 8=phi_mid(62,64,64,64) 9=phi_last(64,64)

static inline int imin(int a, int b) { return a < b ? a : b; }

typedef __attribute__((ext_vector_type(4))) float f32x4;
typedef _Float16 f16;
typedef __attribute__((ext_vector_type(8))) _Float16 f16x8;

// ---------------------------------------------------------------------------
// K1: vpx means + f16 fragment emit + phi slice gather (bx >= 16384).
__global__ __launch_bounds__(256) void k_reduce_x(const float* __restrict__ x,
                                                  float* __restrict__ vch,
                                                  float* __restrict__ vpx,
                                                  f16* __restrict__ vpxf,
                                                  const float* __restrict__ phi_mid,
                                                  float* __restrict__ slices) {
  if (blockIdx.x >= 16384) {                 // phi gather block
    int i = blockIdx.x - 16384;              // 0..61
    int t = threadIdx.x;
    #pragma unroll
    for (int k = 0; k < 16; ++k) {
      int idx = t + k * 256;                 // l*64 + r
      slices[(size_t)i * 4096 + idx] = phi_mid[((size_t)i * 4096 + idx) * 64 + (i + 1)];
    }
    return;
  }
  int bp = blockIdx.x;             // b*64 + s
  int b = bp >> 6, s = bp & 63;
  int q = threadIdx.x;             // = p
  const float* row = x + ((size_t)bp << 12) + q * 16;
  float4 r0 = *(const float4*)(row);
  float4 r1 = *(const float4*)(row + 4);
  float4 r2 = *(const float4*)(row + 8);
  float4 r3 = *(const float4*)(row + 12);
  float csum = r0.x + r0.y + r0.z + r0.w + r1.x + r1.y + r1.z + r1.w
             + r2.x + r2.y + r2.z + r2.w + r3.x + r3.y + r3.z + r3.w;
  float val = csum * (1.0f / 16.0f);
  if (vpx && (s == 0 || s == 63)) vpx[((size_t)s * 256 + b) * 256 + q] = val;
  if (vpxf && s >= 1 && s <= 62) {
    size_t fa = (size_t)s * 65536
              + (((size_t)(q >> 5) * 16 + (b >> 4)) * 64 + (((q >> 3) & 3) * 16 + (b & 15))) * 8
              + (q & 7);
    vpxf[fa] = (f16)val;
  }

  __shared__ float sc[256][20];
  *(float4*)&sc[q][0]  = r0;
  *(float4*)&sc[q][4]  = r1;
  *(float4*)&sc[q][8]  = r2;
  *(float4*)&sc[q][12] = r3;
  __syncthreads();
  int c = q & 15, g = q >> 4;
  float ps = 0.f;
  #pragma unroll
  for (int k = 0; k < 16; ++k) ps += sc[g * 16 + k][c];
  __shared__ float p2[16][17];
  p2[g][c] = ps;
  __syncthreads();
  if (q < 16) {
    float s2 = 0.f;
    #pragma unroll
    for (int k = 0; k < 16; ++k) s2 += p2[k][q];
    vch[((size_t)s * 256 + b) * 16 + q] = s2 * (1.0f / 256.0f);
  }
}

// ---------------------------------------------------------------------------
// psi gemm tile body (512 threads), SINGLE-PASS f16 MFMA: site's W slab x A
// fragments -> fp16 M tile. 8 MFMA per chunk-pair (was 24 with bf16 hi/lo);
// one f16 LDS staging buffer (16 KB dbuf); padded-LDS fp16 transpose epilogue.
__device__ __forceinline__ void psi_gemm_tile(const float* __restrict__ W,
                                              const f16* __restrict__ Afg,
                                              f16* __restrict__ Mz,   // M + z*256*4096
                                              int lr0, int t,
                                              unsigned char* smem) {
  typedef f16 BArr[2][2][4][64][8];                     // 8 KB each dbuf half
  BArr& Bf = *reinterpret_cast<BArr*>(smem);            // 16 KB total
  int lane = t & 63, w = t >> 6;
  int row = t >> 3, kg = t & 7;
  float4 sv0, sv1;

  #define LOADP(p) do {                                                      \
    const float* src = W + (size_t)(lr0 + row) * 256 + ((p) << 6) + kg * 8;  \
    sv0 = *(const float4*)src;                                               \
    sv1 = *(const float4*)(src + 4);                                         \
  } while (0)
  #define WRITEP(d) do {                                                     \
    float xs[8] = {sv0.x, sv0.y, sv0.z, sv0.w, sv1.x, sv1.y, sv1.z, sv1.w};  \
    f16x8 fv;                                                                \
    _Pragma("unroll")                                                        \
    for (int i = 0; i < 8; ++i) fv[i] = (f16)xs[i];                          \
    int ck = kg >> 2, nt = row >> 4, ln = ((kg & 3) << 4) | (row & 15);      \
    *(f16x8*)&Bf[d][ck][nt][ln][0] = fv;                                     \
  } while (0)
  #define LOADA(slot, chunk) do {                                            \
    _Pragma("unroll")                                                        \
    for (int mi = 0; mi < 2; ++mi) {                                         \
      size_t fo = ((size_t)(chunk) * 16 + (w * 2 + mi)) * 512 + (size_t)lane * 8; \
      Af[slot][mi] = *(const f16x8*)(Afg + fo);                              \
    }                                                                        \
  } while (0)

  f32x4 acc[2][4];
  #pragma unroll
  for (int i = 0; i < 2; ++i)
    #pragma unroll
    for (int j = 0; j < 4; ++j) acc[i][j] = (f32x4){0.f, 0.f, 0.f, 0.f};
  f16x8 Af[2][2];

  LOADA(0, 0);
  LOADP(0);
  WRITEP(0);
  __syncthreads();
  #pragma unroll
  for (int p = 0; p < 4; ++p) {
    if (p < 3) LOADP(p + 1);
    #pragma unroll
    for (int c = 0; c < 2; ++c) {
      const int chunk = p * 2 + c;
      const int cur = chunk & 1, nxt = (chunk + 1) & 1;
      if (chunk < 7) LOADA(nxt, chunk + 1);
      #pragma unroll
      for (int n = 0; n < 4; ++n) {
        f16x8 bf = *(const f16x8*)&Bf[p & 1][c][n][lane][0];
        #pragma unroll
        for (int mi = 0; mi < 2; ++mi) {
          acc[mi][n] = __builtin_amdgcn_mfma_f32_16x16x32_f16(Af[cur][mi], bf, acc[mi][n], 0, 0, 0);
        }
      }
    }
    if (p < 3) WRITEP((p + 1) & 1);
    __syncthreads();
  }
  #undef LOADP
  #undef WRITEP
  #undef LOADA

  // transpose epilogue: acc -> LDS T[128][72] f16 (padded rows, 144B = 9x16B
  // so f16x8 accesses stay 16B-aligned) -> coalesced f16x8 global stores.
  int rg = lane >> 4, cidx = lane & 15;
  f16 (*T)[72] = reinterpret_cast<f16 (*)[72]>(smem);   // 18432 B
  #pragma unroll
  for (int pass = 0; pass < 2; ++pass) {
    if ((w >> 2) == pass) {
      #pragma unroll
      for (int mi = 0; mi < 2; ++mi) {
        int rowb = (((w & 3) * 2 + mi) * 16) + rg * 4;
        #pragma unroll
        for (int n = 0; n < 4; ++n) {
          #pragma unroll
          for (int r = 0; r < 4; ++r) {
            T[rowb + r][n * 16 + cidx] = (f16)acc[mi][n][r];
          }
        }
      }
    }
    __syncthreads();
    int boff = pass * 128;
    #pragma unroll
    for (int k = 0; k < 2; ++k) {
      int f = t + k * 512;            // f16x8 unit 0..1023
      int b2 = f >> 3;                // 0..127
      int l8 = (f & 7) * 8;           // 0..56
      *(f16x8*)(Mz + ((size_t)(boff + b2)) * 4096 + lr0 + l8) =
          *(const f16x8*)&T[b2][l8];
    }
    __syncthreads();
  }
}

// ---------------------------------------------------------------------------
// K2 (mega_A): bx==0 phi chain; bx 1..496 chi gemm; bx>=497 psi gemm sites 0..31.
__global__ __launch_bounds__(512) void k_mega_A(const float* __restrict__ psi_mid,
                                                const f16* __restrict__ vpxf,
                                                f16* __restrict__ M,
                                                const float* __restrict__ chi_mid,
                                                const float* __restrict__ vch,
                                                float* __restrict__ Tc,
                                                const float* __restrict__ slices,
                                                const float* __restrict__ phi_first,
                                                const float* __restrict__ phi_last,
                                                float* __restrict__ phiv) {
  int bx = blockIdx.x;
  int t = threadIdx.x;
  if (bx == 0) {
    // phi chain (512-thread, barriered)
    int r = t & 63, g = t >> 6;
    __shared__ float u[64];
    __shared__ float part[8][64];
    __shared__ float red[64];
    if (t < 64) u[t] = phi_first[t * 64];
    __syncthreads();
    for (int i2 = 0; i2 < 62; ++i2) {
      float sum = 0.f;
      #pragma unroll
      for (int j = 0; j < 8; ++j) {
        int l = g * 8 + j;
        sum += u[l] * slices[(size_t)i2 * 4096 + l * 64 + r];
      }
      part[g][r] = sum;
      __syncthreads();
      if (g == 0) u[r] = part[0][r] + part[1][r] + part[2][r] + part[3][r]
                       + part[4][r] + part[5][r] + part[6][r] + part[7][r];
      __syncthreads();
    }
    if (t < 64) red[t] = u[t] * phi_last[t * 64 + 63];
    __syncthreads();
    if (t == 0) {
      float s = 0.f;
      for (int l = 0; l < 64; ++l) s += red[l];
      *phiv = s;
    }
  } else if (bx <= 496) {
    // chi gemm: Tc[z][b][r*32+l] (fp32)
    int i = bx - 1;
    int z = i >> 3;                 // site 0..61
    int b0 = (i & 7) * 32;
    __shared__ float uv[32][16];
    if (t < 128) {
      int idx = t * 4;
      int b = idx >> 4, c = idx & 15;
      *(float4*)&uv[b][c] = *(const float4*)(vch + ((size_t)(z + 1) * 256 + b0 + b) * 16 + c);
    }
    __syncthreads();
    #pragma unroll
    for (int k = 0; k < 2; ++k) {
      int idx = t + k * 512;         // output index = r*32 + l
      int r = idx >> 5, l = idx & 31;
      const float* Wp = chi_mid + ((size_t)z * 1024 + l * 32 + r) * 16;
      float4 w0 = *(const float4*)(Wp);
      float4 w1 = *(const float4*)(Wp + 4);
      float4 w2 = *(const float4*)(Wp + 8);
      float4 w3 = *(const float4*)(Wp + 12);
      for (int b = 0; b < 32; ++b) {
        const float* u = uv[b];
        float d = w0.x * u[0] + w0.y * u[1] + w0.z * u[2] + w0.w * u[3]
                + w1.x * u[4] + w1.y * u[5] + w1.z * u[6] + w1.w * u[7]
                + w2.x * u[8] + w2.y * u[9] + w2.z * u[10] + w2.w * u[11]
                + w3.x * u[12] + w3.y * u[13] + w3.z * u[14] + w3.w * u[15];
        Tc[((size_t)z * 256 + b0 + b) * 1024 + idx] = d;
      }
    }
  } else {
    int idx = bx - 497;
    int z = idx >> 6;               // site 0..31
    int lr0 = (idx & 63) * 64;
    __shared__ __align__(16) unsigned char smem[18432];
    psi_gemm_tile(psi_mid + (size_t)z * 4096 * 256,
                  vpxf + (size_t)(z + 1) * 65536,
                  M + (size_t)z * 256 * 4096, lr0, t, smem);
  }
}

// ---------------------------------------------------------------------------
// K3 (mega_B): bx<256 psi chain part1 (sites 0..31, LDS-grouped, low-VGPR);
// bx 256..511 chi chain full; bx>=512 psi gemm sites 32..61.
__global__ __launch_bounds__(512) void k_mega_B(const float* __restrict__ psi_mid,
                                                const f16* __restrict__ vpxf,
                                                f16* __restrict__ M,
                                                const float* __restrict__ Tc,
                                                const float* __restrict__ vpx,
                                                const float* __restrict__ vch,
                                                const float* __restrict__ psi_first,
                                                const float* __restrict__ chi_first,
                                                const float* __restrict__ chi_last,
                                                float* __restrict__ vpsi,
                                                float* __restrict__ chiout) {
  int bx = blockIdx.x;
  int t = threadIdx.x;
  if (bx < 256) {
    // psi chain part 1: sites 0..31 (even count), 512 threads, 8 l-groups.
    int b = bx;
    int r = t & 63, g = t >> 6;
    __shared__ float vsh[64];
    __shared__ float part[8][64];
    {
      const float* u0 = vpx + (size_t)b * 256;
      const float* pf = psi_first + r * 256 + g * 32;
      float s0 = 0.f;
      #pragma unroll
      for (int p = 0; p < 32; ++p) s0 += pf[p] * u0[g * 32 + p];
      part[g][r] = s0;
      __syncthreads();
      if (g == 0) {
        float sv = 0.f;
        #pragma unroll
        for (int k = 0; k < 8; ++k) sv += part[k][r];
        vsh[r] = sv;
      }
      __syncthreads();
    }
    #define QLOAD(buf, sc) do {                                                \
      const f16* Mb = M + ((size_t)(sc) * 256 + b) * 4096 + r;                 \
      _Pragma("unroll")                                                        \
      for (int j = 0; j < 8; ++j) buf[j] = (float)Mb[(size_t)(g * 8 + j) * 64]; \
    } while (0)
    #define QSTEP(buf) do {                                                    \
      float sum = 0.f;                                                         \
      _Pragma("unroll")                                                        \
      for (int j = 0; j < 8; ++j) sum += vsh[g * 8 + j] * buf[j];              \
      part[g][r] = sum;                                                        \
      __syncthreads();                                                         \
      if (g == 0) {                                                            \
        float sv = 0.f;                                                        \
        _Pragma("unroll")                                                      \
        for (int k = 0; k < 8; ++k) sv += part[k][r];                          \
        vsh[r] = sv;                                                           \
      }                                                                        \
      __syncthreads();                                                         \
    } while (0)
    float bufA[8], bufB[8];
    QLOAD(bufA, 0);
    #pragma unroll 1
    for (int sc = 0; sc < 32; sc += 2) {
      QLOAD(bufB, sc + 1);
      QSTEP(bufA);
      if (sc + 2 < 32) QLOAD(bufA, sc + 2);
      QSTEP(bufB);
    }
    #undef QLOAD
    #undef QSTEP
    if (g == 0) vpsi[b * 64 + r] = vsh[r];
  } else if (bx < 512) {
    // chi chain (full 62 sites), 1 wave, reg+shfl, no barriers.
    if (t >= 64) return;
    int b = bx - 256;
    int lane = t;
    int r = lane & 31, h = lane >> 5;
    float v;
    {
      const float* u0 = vch + (size_t)b * 16;    // site 0
      const float* cf = chi_first + r * 16;
      float s0 = 0.f;
      #pragma unroll
      for (int c = 0; c < 16; ++c) s0 += cf[c] * u0[c];
      v = s0;                                    // same in both halves
    }
    #define CLOADX(buf, sc) do {                                               \
      const float* Mb = Tc + ((size_t)(sc) * 256 + b) * 1024 + r * 32 + h * 16; \
      *(float4*)&buf[0]  = *(const float4*)(Mb);                               \
      *(float4*)&buf[4]  = *(const float4*)(Mb + 4);                           \
      *(float4*)&buf[8]  = *(const float4*)(Mb + 8);                           \
      *(float4*)&buf[12] = *(const float4*)(Mb + 12);                          \
    } while (0)
    #define CSTEPX(buf) do {                                                   \
      float s0 = 0.f, s1 = 0.f;                                                \
      _Pragma("unroll")                                                        \
      for (int j = 0; j < 8; ++j) {                                            \
        s0 += __shfl(v, h * 16 + 2 * j)     * buf[2 * j];                      \
        s1 += __shfl(v, h * 16 + 2 * j + 1) * buf[2 * j + 1];                  \
      }                                                                        \
      float sum = s0 + s1;                                                     \
      sum += __shfl_xor(sum, 32);                                              \
      v = sum;                                                                 \
    } while (0)
    {
      float mjA[16], mjB[16];
      CLOADX(mjA, 0);
      #pragma unroll 1
      for (int sc = 0; sc < 62; sc += 2) {
        CLOADX(mjB, sc + 1);
        CSTEPX(mjA);
        if (sc + 2 < 62) CLOADX(mjA, sc + 2);
        CSTEPX(mjB);
      }
    }
    #undef CLOADX
    #undef CSTEPX
    const float* u63 = vch + ((size_t)63 * 256 + b) * 16;
    float uc[16];
    #pragma unroll
    for (int c = 0; c < 16; ++c) uc[c] = u63[c];
    for (int o = 0; o < 10; ++o) {
      const float* cl = chi_last + r * 16 * 10 + o;
      float wv = 0.f;
      #pragma unroll
      for (int c = 0; c < 16; ++c) wv += cl[c * 10] * uc[c];
      float p = v * wv;                          // duplicated across halves
      #pragma unroll
      for (int m = 32; m > 0; m >>= 1) p += __shfl_xor(p, m);
      if (lane == 0) chiout[b * 10 + o] = p * 0.5f;
    }
  } else {
    int idx = bx - 512;
    int z = 32 + (idx >> 6);        // site 32..61
    int lr0 = (idx & 63) * 64;
    __shared__ __align__(16) unsigned char smem[18432];
    psi_gemm_tile(psi_mid + (size_t)z * 4096 * 256,
                  vpxf + (size_t)(z + 1) * 65536,
                  M + (size_t)z * 256 * 4096, lr0, t, smem);
  }
}

// ---------------------------------------------------------------------------
// K4: psi chain part 2 (sites 32..61, deep 64x2 register prefetch) + fused
// combine epilogue (out = chiout * psiv * phiv). 256 blocks x 64 threads.
__global__ __launch_bounds__(64) void k_chain_tail(const f16* __restrict__ M,
                                                   const float* __restrict__ vpx,
                                                   const float* __restrict__ psi_last,
                                                   const float* __restrict__ chiout,
                                                   const float* __restrict__ phiv,
                                                   const float* __restrict__ vpsi,
                                                   float* __restrict__ out) {
  int b = blockIdx.x;
  int lane = threadIdx.x;
  float v = vpsi[b * 64 + lane];
  #define MLOAD(buf, sc) do {                                                \
    const f16* Mb = M + ((size_t)(32 + (sc)) * 256 + b) * 4096 + lane;       \
    _Pragma("unroll")                                                        \
    for (int l = 0; l < 64; ++l) buf[l] = (float)Mb[(size_t)l * 64];         \
  } while (0)
  #define MSTEP(buf) do {                                                    \
    float s0 = 0.f, s1 = 0.f, s2 = 0.f, s3 = 0.f;                            \
    _Pragma("unroll")                                                        \
    for (int l = 0; l < 16; ++l) {                                           \
      s0 += __shfl(v, 4 * l + 0) * buf[4 * l + 0];                           \
      s1 += __shfl(v, 4 * l + 1) * buf[4 * l + 1];                           \
      s2 += __shfl(v, 4 * l + 2) * buf[4 * l + 2];                           \
      s3 += __shfl(v, 4 * l + 3) * buf[4 * l + 3];                           \
    }                                                                        \
    v = (s0 + s1) + (s2 + s3);                                               \
  } while (0)
  {
    float mvA[64], mvB[64];
    MLOAD(mvA, 0);
    #pragma unroll 1
    for (int sc = 0; sc < 30; sc += 2) {      // 30 even: pairs complete
      MLOAD(mvB, sc + 1);
      MSTEP(mvA);
      if (sc + 2 < 30) MLOAD(mvA, sc + 2);
      MSTEP(mvB);
    }
  }
  #undef MLOAD
  #undef MSTEP
  // psi_val = sum_p (sum_l v[l] psi_last[l][p]) * vpx[63][b][p]
  float acc_p = 0.f;
  #pragma unroll
  for (int pp = 0; pp < 4; ++pp) {
    int p = pp * 64 + lane;
    float pl[64];
    #pragma unroll
    for (int l = 0; l < 64; ++l) pl[l] = psi_last[l * 256 + p];
    float s0 = 0.f, s1 = 0.f, s2 = 0.f, s3 = 0.f;
    #pragma unroll
    for (int l = 0; l < 16; ++l) {
      s0 += __shfl(v, 4 * l + 0) * pl[4 * l + 0];
      s1 += __shfl(v, 4 * l + 1) * pl[4 * l + 1];
      s2 += __shfl(v, 4 * l + 2) * pl[4 * l + 2];
      s3 += __shfl(v, 4 * l + 3) * pl[4 * l + 3];
    }
    float wv = (s0 + s1) + (s2 + s3);
    acc_p += wv * vpx[((size_t)63 * 256 + b) * 256 + p];
  }
  #pragma unroll
  for (int m = 32; m > 0; m >>= 1) acc_p += __shfl_xor(acc_p, m);
  // fused combine: acc_p (psiv) is in all lanes
  if (lane < 10) out[b * 10 + lane] = chiout[b * 10 + lane] * acc_p * phiv[0];
}

// ---------------------------------------------------------------------------
// ===== Fallback tier (smaller workspace): chunked pipeline, f16 M =====
__global__ __launch_bounds__(512) void k_psi_gemm(const float* __restrict__ psi_mid,
                                                  const f16* __restrict__ vpxf,
                                                  f16* __restrict__ M, int s0) {
  int z = blockIdx.z;
  int s = s0 + z;
  int lr0 = blockIdx.x * 64;
  __shared__ __align__(16) unsigned char smem[18432];
  psi_gemm_tile(psi_mid + (size_t)s * 4096 * 256,
                vpxf + (size_t)(s + 1) * 65536,
                M + (size_t)z * 256 * 4096, lr0, threadIdx.x, smem);
}

__global__ __launch_bounds__(256) void k_psi_chain(const f16* __restrict__ M,
                                                   const float* __restrict__ vpx,
                                                   const float* __restrict__ psi_first,
                                                   const float* __restrict__ psi_last,
                                                   float* __restrict__ vpsi,
                                                   float* __restrict__ psiv,
                                                   int nS, int isFirst, int isLast) {
  int b = blockIdx.x;
  int t = threadIdx.x;
  int r = t & 63, g = t >> 6;
  __shared__ float v[64];
  __shared__ float part[4][64];
  __shared__ float red[256];
  if (isFirst) {
    const float* u0 = vpx + (size_t)b * 256;
    float s0 = 0.f;
    for (int p = g * 64; p < g * 64 + 64; ++p) s0 += psi_first[r * 256 + p] * u0[p];
    part[g][r] = s0;
    __syncthreads();
    if (g == 0) v[r] = part[0][r] + part[1][r] + part[2][r] + part[3][r];
    __syncthreads();
  } else {
    if (g == 0) v[r] = vpsi[b * 64 + r];
    __syncthreads();
  }
  for (int sc = 0; sc < nS; ++sc) {
    const f16* Mb = M + ((size_t)sc * 256 + b) * 4096;
    float sum = 0.f;
    #pragma unroll
    for (int j = 0; j < 16; ++j) {
      int l = g * 16 + j;
      sum += v[l] * (float)Mb[l * 64 + r];
    }
    part[g][r] = sum;
    __syncthreads();
    if (g == 0) v[r] = part[0][r] + part[1][r] + part[2][r] + part[3][r];
    __syncthreads();
  }
  if (isLast) {
    float qv = 0.f;
    for (int l = 0; l < 64; ++l) qv += v[l] * psi_last[l * 256 + t];
    red[t] = qv * vpx[((size_t)63 * 256 + b) * 256 + t];
    __syncthreads();
    for (int off = 128; off > 0; off >>= 1) {
      if (t < off) red[t] += red[t + off];
      __syncthreads();
    }
    if (t == 0) psiv[b] = red[0];
  } else {
    if (g == 0) vpsi[b * 64 + r] = v[r];
  }
}

__device__ __forceinline__ void phi_chain_body(const float* __restrict__ slices,
                                               const float* __restrict__ phi_first,
                                               const float* __restrict__ phi_last,
                                               float* __restrict__ phiv) {
  int t = threadIdx.x;
  int r = t & 63, g = t >> 6;
  __shared__ float u[64];
  __shared__ float part[4][64];
  __shared__ float red[64];
  if (t < 64) u[t] = phi_first[t * 64];
  __syncthreads();
  for (int i = 0; i < 62; ++i) {
    float sum = 0.f;
    #pragma unroll
    for (int j = 0; j < 16; ++j) {
      int l = g * 16 + j;
      sum += u[l] * slices[(size_t)i * 4096 + l * 64 + r];
    }
    part[g][r] = sum;
    __syncthreads();
    if (g == 0) u[r] = part[0][r] + part[1][r] + part[2][r] + part[3][r];
    __syncthreads();
  }
  if (t < 64) red[t] = u[t] * phi_last[t * 64 + 63];
  __syncthreads();
  if (t == 0) {
    float s = 0.f;
    for (int l = 0; l < 64; ++l) s += red[l];
    *phiv = s;
  }
}

__global__ __launch_bounds__(256) void k_phi_chain(const float* __restrict__ slices,
                                                   const float* __restrict__ phi_first,
                                                   const float* __restrict__ phi_last,
                                                   float* __restrict__ phiv) {
  phi_chain_body(slices, phi_first, phi_last, phiv);
}

__global__ __launch_bounds__(256) void k_chi_gemm(const float* __restrict__ chi_mid,
                                                  const float* __restrict__ vch,
                                                  float* __restrict__ Tc, int s0,
                                                  int phiBlock,
                                                  const float* __restrict__ slices,
                                                  const float* __restrict__ phi_first,
                                                  const float* __restrict__ phi_last,
                                                  float* __restrict__ phiv) {
  if ((int)blockIdx.x == phiBlock) {
    if (blockIdx.y == 0) phi_chain_body(slices, phi_first, phi_last, phiv);
    return;
  }
  int z = blockIdx.x;
  int s = s0 + z;
  int b0 = blockIdx.y * 32;
  int t = threadIdx.x;
  __shared__ float uv[32][16];
  if (t < 128) {
    int idx = t * 4;
    int b = idx >> 4, c = idx & 15;
    *(float4*)&uv[b][c] = *(const float4*)(vch + ((size_t)(s + 1) * 256 + b0 + b) * 16 + c);
  }
  __syncthreads();
  #pragma unroll
  for (int k = 0; k < 4; ++k) {
    int idx = t + k * 256;
    int r = idx >> 5, l = idx & 31;
    const float* Wp = chi_mid + ((size_t)s * 1024 + l * 32 + r) * 16;
    float4 w0 = *(const float4*)(Wp);
    float4 w1 = *(const float4*)(Wp + 4);
    float4 w2 = *(const float4*)(Wp + 8);
    float4 w3 = *(const float4*)(Wp + 12);
    for (int b = 0; b < 32; ++b) {
      const float* u = uv[b];
      float d = w0.x * u[0] + w0.y * u[1] + w0.z * u[2] + w0.w * u[3]
              + w1.x * u[4] + w1.y * u[5] + w1.z * u[6] + w1.w * u[7]
              + w2.x * u[8] + w2.y * u[9] + w2.z * u[10] + w2.w * u[11]
              + w3.x * u[12] + w3.y * u[13] + w3.z * u[14] + w3.w * u[15];
      Tc[((size_t)z * 256 + b0 + b) * 1024 + idx] = d;
    }
  }
}

__global__ __launch_bounds__(64) void k_chi_chain(const float* __restrict__ Tc,
                                                  const float* __restrict__ chi_first,
                                                  const float* __restrict__ chi_last,
                                                  const float* __restrict__ vch,
                                                  const float* __restrict__ psiv,
                                                  const float* __restrict__ phiv,
                                                  float* __restrict__ vchi,
                                                  float* __restrict__ out,
                                                  int nS, int isFirst, int isLast) {
  int b = blockIdx.x;
  int lane = threadIdx.x;
  int r = lane & 31, h = lane >> 5;
  __shared__ float v[32];
  if (isFirst) {
    if (h == 0) {
      const float* u0 = vch + (size_t)b * 16;
      const float* cf = chi_first + r * 16;
      float s0 = 0.f;
      #pragma unroll
      for (int c = 0; c < 16; ++c) s0 += cf[c] * u0[c];
      v[r] = s0;
    }
  } else {
    if (h == 0) v[r] = vchi[b * 32 + r];
  }
  __syncthreads();
  for (int sc = 0; sc < nS; ++sc) {
    const float* Mb = Tc + ((size_t)sc * 256 + b) * 1024 + r * 32 + h * 16;
    float4 m0 = *(const float4*)(Mb);
    float4 m1 = *(const float4*)(Mb + 4);
    float4 m2 = *(const float4*)(Mb + 8);
    float4 m3 = *(const float4*)(Mb + 12);
    const float* vv = &v[h * 16];
    float sum = m0.x * vv[0] + m0.y * vv[1] + m0.z * vv[2] + m0.w * vv[3]
              + m1.x * vv[4] + m1.y * vv[5] + m1.z * vv[6] + m1.w * vv[7]
              + m2.x * vv[8] + m2.y * vv[9] + m2.z * vv[10] + m2.w * vv[11]
              + m3.x * vv[12] + m3.y * vv[13] + m3.z * vv[14] + m3.w * vv[15];
    sum += __shfl_xor(sum, 32);
    __syncthreads();
    if (h == 0) v[r] = sum;
    __syncthreads();
  }
  if (isLast) {
    const float* u63 = vch + ((size_t)63 * 256 + b) * 16;
    float uc[16];
    #pragma unroll
    for (int c = 0; c < 16; ++c) uc[c] = u63[c];
    float scale = 0.5f * psiv[b] * phiv[0];
    for (int o = 0; o < 10; ++o) {
      const float* cl = chi_last + r * 16 * 10 + o;
      float w = 0.f;
      #pragma unroll
      for (int c = 0; c < 16; ++c) w += cl[c * 10] * uc[c];
      float p = v[r] * w;
      #pragma unroll
      for (int m = 32; m > 0; m >>= 1) p += __shfl_xor(p, m);
      if (lane == 0) out[b * 10 + o] = p * scale;
    }
  } else {
    if (h == 0) vchi[b * 32 + r] = v[r];
  }
}

__global__ __launch_bounds__(256) void k_chi_fused(const float* __restrict__ chi_first,
                                                   const float* __restrict__ chi_mid,
                                                   const float* __restrict__ chi_last,
                                                   const float* __restrict__ vch,
                                                   const float* __restrict__ psiv,
                                                   const float* __restrict__ phiv,
                                                   float* __restrict__ out) {
  int t = threadIdx.x;
  int bl = t >> 6, lg = (t >> 5) & 1, r = t & 31;
  int b = blockIdx.x * 4 + bl;
  __shared__ float v[4][32];
  __shared__ float part[4][2][32];
  if (lg == 0) {
    const float* u0 = vch + (size_t)b * 16;
    float s0 = 0.f;
    #pragma unroll
    for (int c = 0; c < 16; ++c) s0 += chi_first[r * 16 + c] * u0[c];
    v[bl][r] = s0;
  }
  __syncthreads();
  for (int s = 0; s < 62; ++s) {
    const float* u = vch + ((size_t)(s + 1) * 256 + b) * 16;
    float uc[16];
    #pragma unroll
    for (int c = 0; c < 16; ++c) uc[c] = u[c];
    const float* W = chi_mid + (size_t)s * 32 * 32 * 16;
    float sum = 0.f;
    #pragma unroll
    for (int j = 0; j < 16; ++j) {
      int l = lg * 16 + j;
      const float* Wl = W + ((size_t)l * 32 + r) * 16;
      float tt = 0.f;
      #pragma unroll
      for (int c = 0; c < 16; ++c) tt += Wl[c] * uc[c];
      sum += v[bl][l] * tt;
    }
    part[bl][lg][r] = sum;
    __syncthreads();
    if (lg == 0) v[bl][r] = part[bl][0][r] + part[bl][1][r];
    __syncthreads();
  }
  const float* u63 = vch + ((size_t)63 * 256 + b) * 16;
  float uc[16];
  #pragma unroll
  for (int c = 0; c < 16; ++c) uc[c] = u63[c];
  if (r < 10) {
    float acc = 0.f;
    #pragma unroll
    for (int j = 0; j < 16; ++j) {
      int l = lg * 16 + j;
      const float* cl = chi_last + (size_t)l * 16 * 10;
      float tt = 0.f;
      #pragma unroll
      for (int c = 0; c < 16; ++c) tt += cl[c * 10 + r] * uc[c];
      acc += v[bl][l] * tt;
    }
    part[bl][lg][r] = acc;
  }
  __syncthreads();
  if (lg == 0 && r < 10)
    out[b * 10 + r] = (part[bl][0][r] + part[bl][1][r]) * psiv[b] * phiv[0];
}

__global__ __launch_bounds__(256) void k_psi_direct(const float* __restrict__ x,
                                                    const float* __restrict__ psi_mid,
                                                    const float* __restrict__ psi_first,
                                                    const float* __restrict__ psi_last,
                                                    float* __restrict__ psiv) {
  int b = blockIdx.x;
  int t = threadIdx.x;
  int r = t & 63, g = t >> 6;
  __shared__ float u[256];
  __shared__ float v[64];
  __shared__ float part[4][64];
  __shared__ float red[256];
  const float* xb = x + ((size_t)b << 18);
  {
    const float* rw = xb + (size_t)0 * 4096 + t * 16;
    float sm = 0.f;
    #pragma unroll
    for (int c = 0; c < 16; ++c) sm += rw[c];
    u[t] = sm * (1.0f / 16.0f);
  }
  __syncthreads();
  {
    float s0 = 0.f;
    for (int p = g * 64; p < g * 64 + 64; ++p) s0 += psi_first[r * 256 + p] * u[p];
    part[g][r] = s0;
    __syncthreads();
    if (g == 0) v[r] = part[0][r] + part[1][r] + part[2][r] + part[3][r];
  }
  __syncthreads();
  for (int s = 0; s < 62; ++s) {
    __syncthreads();
    {
      const float* rw = xb + (size_t)(s + 1) * 4096 + t * 16;
      float sm = 0.f;
      #pragma unroll
      for (int c = 0; c < 16; ++c) sm += rw[c];
      u[t] = sm * (1.0f / 16.0f);
    }
    __syncthreads();
    const float* W = psi_mid + (size_t)s * 4096 * 256;
    float sum = 0.f;
    for (int l = 0; l < 64; ++l) {
      const float* Wl = W + ((size_t)(l * 64 + r)) * 256 + g * 64;
      float tt = 0.f;
      #pragma unroll 8
      for (int k = 0; k < 64; ++k) tt += Wl[k] * u[g * 64 + k];
      sum += v[l] * tt;
    }
    part[g][r] = sum;
    __syncthreads();
    if (g == 0) v[r] = part[0][r] + part[1][r] + part[2][r] + part[3][r];
    __syncthreads();
  }
  __syncthreads();
  {
    const float* rw = xb + (size_t)63 * 4096 + t * 16;
    float sm = 0.f;
    #pragma unroll
    for (int c = 0; c < 16; ++c) sm += rw[c];
    u[t] = sm * (1.0f / 16.0f);
  }
  __syncthreads();
  float qv = 0.f;
  for (int l = 0; l < 64; ++l) qv += v[l] * psi_last[l * 256 + t];
  red[t] = qv * u[t];
  __syncthreads();
  for (int off = 128; off > 0; off >>= 1) {
    if (t < off) red[t] += red[t + off];
    __syncthreads();
  }
  if (t == 0) psiv[b] = red[0];
}

// ---------------------------------------------------------------------------
extern "C" void kernel_launch(void* const* d_in, const int* in_sizes, int n_in,
                              void* d_out, int out_size, void* d_ws, size_t ws_size,
                              hipStream_t stream) {
  const float* x         = (const float*)d_in[0];
  const float* chi_first = (const float*)d_in[1];
  const float* chi_mid   = (const float*)d_in[2];
  const float* chi_last  = (const float*)d_in[3];
  const float* psi_first = (const float*)d_in[4];
  const float* psi_mid   = (const float*)d_in[5];
  const float* psi_last  = (const float*)d_in[6];
  const float* phi_first = (const float*)d_in[7];
  const float* phi_mid   = (const float*)d_in[8];
  const float* phi_last  = (const float*)d_in[9];
  float* out = (float*)d_out;
  float* ws  = (float*)d_ws;

  size_t wsf = ws_size / 4;
  size_t off = 0;
  float* vch    = ws + off; off += (size_t)64 * 256 * 16;     // 262144
  float* psiv   = ws + off; off += 256;
  float* chiout = ws + off; off += 2560;
  float* phisl  = ws + off; off += (size_t)62 * 64 * 64;      // 253952
  float* phiv   = ws + off; off += 16;
  float* vpsi   = ws + off; off += (size_t)64 * 256;          // 16384
  float* vchi   = ws + off; off += (size_t)32 * 256;          // 8192
  float* vpx    = ws + off; off += (size_t)64 * 256 * 256;    // 4194304
  f16* vpxf = (f16*)(ws + off); off += (size_t)64 * 65536 / 2;  // f16 frags
  f16* Mbuf = (f16*)(ws + off);                               // fp16 M
  size_t needMh  = (size_t)62 * 256 * 4096;                   // halves
  float* Tcbuf = (float*)(Mbuf + needMh);
  size_t needTc = (size_t)62 * 256 * 1024;                    // floats
  size_t bytes_needed = off * 4 + needMh * 2 + needTc * 4;

  if (ws_size >= bytes_needed) {
    // ===== Pipelined path: reduce -> [gemmA+chiGemm+phi] -> [gemmB || chains] -> tail
    k_reduce_x<<<16384 + 62, 256, 0, stream>>>(x, vch, vpx, vpxf,
                                               phi_mid, phisl);
    k_mega_A<<<497 + 2048, 512, 0, stream>>>(psi_mid, vpxf, Mbuf,
                                             chi_mid, vch, Tcbuf,
                                             phisl, phi_first, phi_last, phiv);
    k_mega_B<<<512 + 1920, 512, 0, stream>>>(psi_mid, vpxf, Mbuf,
                                             Tcbuf, vpx, vch, psi_first,
                                             chi_first, chi_last, vpsi, chiout);
    k_chain_tail<<<256, 64, 0, stream>>>(Mbuf, vpx, psi_last, chiout, phiv,
                                         vpsi, out);
  } else {
    size_t avail_b = (ws_size > off * 4) ? ws_size - off * 4 : 0;
    int C = (int)(avail_b / ((size_t)256 * 4096 * 2));        // fp16 M sites
    if (C > 62) C = 62;
    int Cc = (int)(avail_b / ((size_t)256 * 1024 * 4));       // fp32 Tc sites
    if (Cc > 62) Cc = 62;
    if (C >= 1) {
      k_reduce_x<<<16384 + 62, 256, 0, stream>>>(x, vch, vpx, vpxf,
                                                 phi_mid, phisl);
      int done = 0;
      while (done < 62) {
        int c = imin(C, 62 - done);
        k_psi_gemm<<<dim3(64, 1, c), 512, 0, stream>>>(psi_mid, vpxf, Mbuf, done);
        k_psi_chain<<<256, 256, 0, stream>>>(Mbuf, vpx, psi_first, psi_last,
                                             vpsi, psiv, c, (done == 0) ? 1 : 0,
                                             (done + c == 62) ? 1 : 0);
        done += c;
      }
      done = 0;
      while (done < 62) {
        int c = imin(Cc, 62 - done);
        int phiBlk = (done == 0) ? c : -1;
        int gx = (done == 0) ? (c + 1) : c;
        k_chi_gemm<<<dim3(gx, 8), 256, 0, stream>>>(chi_mid, vch, (float*)Mbuf, done, phiBlk,
                                                    phisl, phi_first, phi_last, phiv);
        k_chi_chain<<<256, 64, 0, stream>>>((float*)Mbuf, chi_first, chi_last, vch,
                                            psiv, phiv, vchi, out, c,
                                            (done == 0) ? 1 : 0,
                                            (done + c == 62) ? 1 : 0);
        done += c;
      }
    } else {
      k_reduce_x<<<16384 + 62, 256, 0, stream>>>(x, vch, nullptr, nullptr,
                                                 phi_mid, phisl);
      k_psi_direct<<<256, 256, 0, stream>>>(x, psi_mid, psi_first, psi_last, psiv);
      k_phi_chain<<<1, 256, 0, stream>>>(phisl, phi_first, phi_last, phiv);
      k_chi_fused<<<64, 256, 0, stream>>>(chi_first, chi_mid, chi_last, vch, psiv, phiv, out);
    }
  }
}

// Round 15
// 247.664 us; speedup vs baseline: 7.0300x; 1.0245x over previous
//
#include <hip/hip_runtime.h>

// dims: L=64, CH=16, PIX=256, PAT=64, RC=32, BD=64, OUT=10, B=256
// inputs: 0=x(256,64,256,16) 1=chi_first(32,16) 2=chi_mid(62,32,32,16)
// 3=chi_last(32,16,10) 4=psi_first(64,256) 5=psi_mid(62,64,64,256)
// 6=psi_last(64,256) 7=phi_first(64,64) 8=phi_mid(62,64,64,64) 9=phi_last(64,64)

static inline int imin(int a, int b) { return a < b ? a : b; }

typedef __attribute__((ext_vector_type(4))) float f32x4;
typedef _Float16 f16;
typedef __attribute__((ext_vector_type(8))) _Float16 f16x8;

// ---------------------------------------------------------------------------
// K1: vpx means + f16 fragment emit + phi slice gather (bx >= 16384).
__global__ __launch_bounds__(256) void k_reduce_x(const float* __restrict__ x,
                                                  float* __restrict__ vch,
                                                  float* __restrict__ vpx,
                                                  f16* __restrict__ vpxf,
                                                  const float* __restrict__ phi_mid,
                                                  float* __restrict__ slices) {
  if (blockIdx.x >= 16384) {                 // phi gather block
    int i = blockIdx.x - 16384;              // 0..61
    int t = threadIdx.x;
    #pragma unroll
    for (int k = 0; k < 16; ++k) {
      int idx = t + k * 256;                 // l*64 + r
      slices[(size_t)i * 4096 + idx] = phi_mid[((size_t)i * 4096 + idx) * 64 + (i + 1)];
    }
    return;
  }
  int bp = blockIdx.x;             // b*64 + s
  int b = bp >> 6, s = bp & 63;
  int q = threadIdx.x;             // = p
  const float* row = x + ((size_t)bp << 12) + q * 16;
  float4 r0 = *(const float4*)(row);
  float4 r1 = *(const float4*)(row + 4);
  float4 r2 = *(const float4*)(row + 8);
  float4 r3 = *(const float4*)(row + 12);
  float csum = r0.x + r0.y + r0.z + r0.w + r1.x + r1.y + r1.z + r1.w
             + r2.x + r2.y + r2.z + r2.w + r3.x + r3.y + r3.z + r3.w;
  float val = csum * (1.0f / 16.0f);
  if (vpx && (s == 0 || s == 63)) vpx[((size_t)s * 256 + b) * 256 + q] = val;
  if (vpxf && s >= 1 && s <= 62) {
    size_t fa = (size_t)s * 65536
              + (((size_t)(q >> 5) * 16 + (b >> 4)) * 64 + (((q >> 3) & 3) * 16 + (b & 15))) * 8
              + (q & 7);
    vpxf[fa] = (f16)val;
  }

  __shared__ float sc[256][20];
  *(float4*)&sc[q][0]  = r0;
  *(float4*)&sc[q][4]  = r1;
  *(float4*)&sc[q][8]  = r2;
  *(float4*)&sc[q][12] = r3;
  __syncthreads();
  int c = q & 15, g = q >> 4;
  float ps = 0.f;
  #pragma unroll
  for (int k = 0; k < 16; ++k) ps += sc[g * 16 + k][c];
  __shared__ float p2[16][17];
  p2[g][c] = ps;
  __syncthreads();
  if (q < 16) {
    float s2 = 0.f;
    #pragma unroll
    for (int k = 0; k < 16; ++k) s2 += p2[k][q];
    vch[((size_t)s * 256 + b) * 16 + q] = s2 * (1.0f / 256.0f);
  }
}

// ---------------------------------------------------------------------------
// psi gemm tile body (512 threads), single-pass f16 MFMA with 2-DEEP W
// register prefetch: panel p+2's global loads issue at the start of phase p
// (two named register sets svA/svB), consumed at the end of phase p+1 —
// ~2 compute phases of HBM-latency hiding vs <1 before.
__device__ __forceinline__ void psi_gemm_tile(const float* __restrict__ W,
                                              const f16* __restrict__ Afg,
                                              f16* __restrict__ Mz,   // M + z*256*4096
                                              int lr0, int t,
                                              unsigned char* smem) {
  typedef f16 BArr[2][2][4][64][8];                     // 8 KB each dbuf half
  BArr& Bf = *reinterpret_cast<BArr*>(smem);            // 16 KB total
  int lane = t & 63, w = t >> 6;
  int row = t >> 3, kg = t & 7;
  float4 svA0, svA1, svB0, svB1;                        // two W panel reg sets

  #define LOADPA(p) do {                                                     \
    const float* src = W + (size_t)(lr0 + row) * 256 + ((p) << 6) + kg * 8;  \
    svA0 = *(const float4*)src;                                              \
    svA1 = *(const float4*)(src + 4);                                        \
  } while (0)
  #define LOADPB(p) do {                                                     \
    const float* src = W + (size_t)(lr0 + row) * 256 + ((p) << 6) + kg * 8;  \
    svB0 = *(const float4*)src;                                              \
    svB1 = *(const float4*)(src + 4);                                        \
  } while (0)
  #define WRITEPA(d) do {                                                    \
    float xs[8] = {svA0.x, svA0.y, svA0.z, svA0.w, svA1.x, svA1.y, svA1.z, svA1.w}; \
    f16x8 fv;                                                                \
    _Pragma("unroll")                                                        \
    for (int i = 0; i < 8; ++i) fv[i] = (f16)xs[i];                          \
    int ck = kg >> 2, nt = row >> 4, ln = ((kg & 3) << 4) | (row & 15);      \
    *(f16x8*)&Bf[d][ck][nt][ln][0] = fv;                                     \
  } while (0)
  #define WRITEPB(d) do {                                                    \
    float xs[8] = {svB0.x, svB0.y, svB0.z, svB0.w, svB1.x, svB1.y, svB1.z, svB1.w}; \
    f16x8 fv;                                                                \
    _Pragma("unroll")                                                        \
    for (int i = 0; i < 8; ++i) fv[i] = (f16)xs[i];                          \
    int ck = kg >> 2, nt = row >> 4, ln = ((kg & 3) << 4) | (row & 15);      \
    *(f16x8*)&Bf[d][ck][nt][ln][0] = fv;                                     \
  } while (0)
  #define LOADA(slot, chunk) do {                                            \
    _Pragma("unroll")                                                        \
    for (int mi = 0; mi < 2; ++mi) {                                         \
      size_t fo = ((size_t)(chunk) * 16 + (w * 2 + mi)) * 512 + (size_t)lane * 8; \
      Af[slot][mi] = *(const f16x8*)(Afg + fo);                              \
    }                                                                        \
  } while (0)
  #define COMPUTE(p) do {                                                    \
    _Pragma("unroll")                                                        \
    for (int c = 0; c < 2; ++c) {                                            \
      const int chunk = (p) * 2 + c;                                         \
      const int cur = chunk & 1, nxt = (chunk + 1) & 1;                      \
      if (chunk < 7) LOADA(nxt, chunk + 1);                                  \
      _Pragma("unroll")                                                      \
      for (int n = 0; n < 4; ++n) {                                          \
        f16x8 bf = *(const f16x8*)&Bf[(p) & 1][c][n][lane][0];               \
        _Pragma("unroll")                                                    \
        for (int mi = 0; mi < 2; ++mi) {                                     \
          acc[mi][n] = __builtin_amdgcn_mfma_f32_16x16x32_f16(Af[cur][mi], bf, acc[mi][n], 0, 0, 0); \
        }                                                                    \
      }                                                                      \
    }                                                                        \
  } while (0)

  f32x4 acc[2][4];
  #pragma unroll
  for (int i = 0; i < 2; ++i)
    #pragma unroll
    for (int j = 0; j < 4; ++j) acc[i][j] = (f32x4){0.f, 0.f, 0.f, 0.f};
  f16x8 Af[2][2];

  LOADA(0, 0);
  LOADPA(0);
  LOADPB(1);               // panel 1 in flight during panel-0 convert stall
  WRITEPA(0);              // panel 0 -> buf 0 (waits its loads)
  __syncthreads();
  LOADPA(2);               // prefetch panel 2 (consumed end of phase 1)
  COMPUTE(0);
  WRITEPB(1);              // panel 1 -> buf 1
  __syncthreads();
  LOADPB(3);               // prefetch panel 3 (consumed end of phase 2)
  COMPUTE(1);
  WRITEPA(0);              // panel 2 -> buf 0
  __syncthreads();
  COMPUTE(2);
  WRITEPB(1);              // panel 3 -> buf 1
  __syncthreads();
  COMPUTE(3);
  __syncthreads();
  #undef LOADPA
  #undef LOADPB
  #undef WRITEPA
  #undef WRITEPB
  #undef LOADA
  #undef COMPUTE

  // transpose epilogue: acc -> LDS T[128][72] f16 (padded rows, 144B = 9x16B
  // so f16x8 accesses stay 16B-aligned) -> coalesced f16x8 global stores.
  int rg = lane >> 4, cidx = lane & 15;
  f16 (*T)[72] = reinterpret_cast<f16 (*)[72]>(smem);   // 18432 B
  #pragma unroll
  for (int pass = 0; pass < 2; ++pass) {
    if ((w >> 2) == pass) {
      #pragma unroll
      for (int mi = 0; mi < 2; ++mi) {
        int rowb = (((w & 3) * 2 + mi) * 16) + rg * 4;
        #pragma unroll
        for (int n = 0; n < 4; ++n) {
          #pragma unroll
          for (int r = 0; r < 4; ++r) {
            T[rowb + r][n * 16 + cidx] = (f16)acc[mi][n][r];
          }
        }
      }
    }
    __syncthreads();
    int boff = pass * 128;
    #pragma unroll
    for (int k = 0; k < 2; ++k) {
      int f = t + k * 512;            // f16x8 unit 0..1023
      int b2 = f >> 3;                // 0..127
      int l8 = (f & 7) * 8;           // 0..56
      *(f16x8*)(Mz + ((size_t)(boff + b2)) * 4096 + lr0 + l8) =
          *(const f16x8*)&T[b2][l8];
    }
    __syncthreads();
  }
}

// ---------------------------------------------------------------------------
// K2 (mega_A): bx==0 phi chain; bx 1..496 chi gemm; bx>=497 psi gemm sites 0..35.
__global__ __launch_bounds__(512) void k_mega_A(const float* __restrict__ psi_mid,
                                                const f16* __restrict__ vpxf,
                                                f16* __restrict__ M,
                                                const float* __restrict__ chi_mid,
                                                const float* __restrict__ vch,
                                                float* __restrict__ Tc,
                                                const float* __restrict__ slices,
                                                const float* __restrict__ phi_first,
                                                const float* __restrict__ phi_last,
                                                float* __restrict__ phiv) {
  int bx = blockIdx.x;
  int t = threadIdx.x;
  if (bx == 0) {
    // phi chain (512-thread, barriered)
    int r = t & 63, g = t >> 6;
    __shared__ float u[64];
    __shared__ float part[8][64];
    __shared__ float red[64];
    if (t < 64) u[t] = phi_first[t * 64];
    __syncthreads();
    for (int i2 = 0; i2 < 62; ++i2) {
      float sum = 0.f;
      #pragma unroll
      for (int j = 0; j < 8; ++j) {
        int l = g * 8 + j;
        sum += u[l] * slices[(size_t)i2 * 4096 + l * 64 + r];
      }
      part[g][r] = sum;
      __syncthreads();
      if (g == 0) u[r] = part[0][r] + part[1][r] + part[2][r] + part[3][r]
                       + part[4][r] + part[5][r] + part[6][r] + part[7][r];
      __syncthreads();
    }
    if (t < 64) red[t] = u[t] * phi_last[t * 64 + 63];
    __syncthreads();
    if (t == 0) {
      float s = 0.f;
      for (int l = 0; l < 64; ++l) s += red[l];
      *phiv = s;
    }
  } else if (bx <= 496) {
    // chi gemm: Tc[z][b][r*32+l] (fp32)
    int i = bx - 1;
    int z = i >> 3;                 // site 0..61
    int b0 = (i & 7) * 32;
    __shared__ float uv[32][16];
    if (t < 128) {
      int idx = t * 4;
      int b = idx >> 4, c = idx & 15;
      *(float4*)&uv[b][c] = *(const float4*)(vch + ((size_t)(z + 1) * 256 + b0 + b) * 16 + c);
    }
    __syncthreads();
    #pragma unroll
    for (int k = 0; k < 2; ++k) {
      int idx = t + k * 512;         // output index = r*32 + l
      int r = idx >> 5, l = idx & 31;
      const float* Wp = chi_mid + ((size_t)z * 1024 + l * 32 + r) * 16;
      float4 w0 = *(const float4*)(Wp);
      float4 w1 = *(const float4*)(Wp + 4);
      float4 w2 = *(const float4*)(Wp + 8);
      float4 w3 = *(const float4*)(Wp + 12);
      for (int b = 0; b < 32; ++b) {
        const float* u = uv[b];
        float d = w0.x * u[0] + w0.y * u[1] + w0.z * u[2] + w0.w * u[3]
                + w1.x * u[4] + w1.y * u[5] + w1.z * u[6] + w1.w * u[7]
                + w2.x * u[8] + w2.y * u[9] + w2.z * u[10] + w2.w * u[11]
                + w3.x * u[12] + w3.y * u[13] + w3.z * u[14] + w3.w * u[15];
        Tc[((size_t)z * 256 + b0 + b) * 1024 + idx] = d;
      }
    }
  } else {
    int idx = bx - 497;
    int z = idx >> 6;               // site 0..35
    int lr0 = (idx & 63) * 64;
    __shared__ __align__(16) unsigned char smem[18432];
    psi_gemm_tile(psi_mid + (size_t)z * 4096 * 256,
                  vpxf + (size_t)(z + 1) * 65536,
                  M + (size_t)z * 256 * 4096, lr0, t, smem);
  }
}

// ---------------------------------------------------------------------------
// K3 (mega_B): bx<256 psi chain part1 (sites 0..35, LDS-grouped, low-VGPR);
// bx 256..511 chi chain full; bx>=512 psi gemm sites 36..61.
__global__ __launch_bounds__(512) void k_mega_B(const float* __restrict__ psi_mid,
                                                const f16* __restrict__ vpxf,
                                                f16* __restrict__ M,
                                                const float* __restrict__ Tc,
                                                const float* __restrict__ vpx,
                                                const float* __restrict__ vch,
                                                const float* __restrict__ psi_first,
                                                const float* __restrict__ chi_first,
                                                const float* __restrict__ chi_last,
                                                float* __restrict__ vpsi,
                                                float* __restrict__ chiout) {
  int bx = blockIdx.x;
  int t = threadIdx.x;
  if (bx < 256) {
    // psi chain part 1: sites 0..35 (even count), 512 threads, 8 l-groups.
    int b = bx;
    int r = t & 63, g = t >> 6;
    __shared__ float vsh[64];
    __shared__ float part[8][64];
    {
      const float* u0 = vpx + (size_t)b * 256;
      const float* pf = psi_first + r * 256 + g * 32;
      float s0 = 0.f;
      #pragma unroll
      for (int p = 0; p < 32; ++p) s0 += pf[p] * u0[g * 32 + p];
      part[g][r] = s0;
      __syncthreads();
      if (g == 0) {
        float sv = 0.f;
        #pragma unroll
        for (int k = 0; k < 8; ++k) sv += part[k][r];
        vsh[r] = sv;
      }
      __syncthreads();
    }
    #define QLOAD(buf, sc) do {                                                \
      const f16* Mb = M + ((size_t)(sc) * 256 + b) * 4096 + r;                 \
      _Pragma("unroll")                                                        \
      for (int j = 0; j < 8; ++j) buf[j] = (float)Mb[(size_t)(g * 8 + j) * 64]; \
    } while (0)
    #define QSTEP(buf) do {                                                    \
      float sum = 0.f;                                                         \
      _Pragma("unroll")                                                        \
      for (int j = 0; j < 8; ++j) sum += vsh[g * 8 + j] * buf[j];              \
      part[g][r] = sum;                                                        \
      __syncthreads();                                                         \
      if (g == 0) {                                                            \
        float sv = 0.f;                                                        \
        _Pragma("unroll")                                                      \
        for (int k = 0; k < 8; ++k) sv += part[k][r];                          \
        vsh[r] = sv;                                                           \
      }                                                                        \
      __syncthreads();                                                         \
    } while (0)
    float bufA[8], bufB[8];
    QLOAD(bufA, 0);
    #pragma unroll 1
    for (int sc = 0; sc < 36; sc += 2) {
      QLOAD(bufB, sc + 1);
      QSTEP(bufA);
      if (sc + 2 < 36) QLOAD(bufA, sc + 2);
      QSTEP(bufB);
    }
    #undef QLOAD
    #undef QSTEP
    if (g == 0) vpsi[b * 64 + r] = vsh[r];
  } else if (bx < 512) {
    // chi chain (full 62 sites), 1 wave, reg+shfl, no barriers.
    if (t >= 64) return;
    int b = bx - 256;
    int lane = t;
    int r = lane & 31, h = lane >> 5;
    float v;
    {
      const float* u0 = vch + (size_t)b * 16;    // site 0
      const float* cf = chi_first + r * 16;
      float s0 = 0.f;
      #pragma unroll
      for (int c = 0; c < 16; ++c) s0 += cf[c] * u0[c];
      v = s0;                                    // same in both halves
    }
    #define CLOADX(buf, sc) do {                                               \
      const float* Mb = Tc + ((size_t)(sc) * 256 + b) * 1024 + r * 32 + h * 16; \
      *(float4*)&buf[0]  = *(const float4*)(Mb);                               \
      *(float4*)&buf[4]  = *(const float4*)(Mb + 4);                           \
      *(float4*)&buf[8]  = *(const float4*)(Mb + 8);                           \
      *(float4*)&buf[12] = *(const float4*)(Mb + 12);                          \
    } while (0)
    #define CSTEPX(buf) do {                                                   \
      float s0 = 0.f, s1 = 0.f;                                                \
      _Pragma("unroll")                                                        \
      for (int j = 0; j < 8; ++j) {                                            \
        s0 += __shfl(v, h * 16 + 2 * j)     * buf[2 * j];                      \
        s1 += __shfl(v, h * 16 + 2 * j + 1) * buf[2 * j + 1];                  \
      }                                                                        \
      float sum = s0 + s1;                                                     \
      sum += __shfl_xor(sum, 32);                                              \
      v = sum;                                                                 \
    } while (0)
    {
      float mjA[16], mjB[16];
      CLOADX(mjA, 0);
      #pragma unroll 1
      for (int sc = 0; sc < 62; sc += 2) {
        CLOADX(mjB, sc + 1);
        CSTEPX(mjA);
        if (sc + 2 < 62) CLOADX(mjA, sc + 2);
        CSTEPX(mjB);
      }
    }
    #undef CLOADX
    #undef CSTEPX
    const float* u63 = vch + ((size_t)63 * 256 + b) * 16;
    float uc[16];
    #pragma unroll
    for (int c = 0; c < 16; ++c) uc[c] = u63[c];
    for (int o = 0; o < 10; ++o) {
      const float* cl = chi_last + r * 16 * 10 + o;
      float wv = 0.f;
      #pragma unroll
      for (int c = 0; c < 16; ++c) wv += cl[c * 10] * uc[c];
      float p = v * wv;                          // duplicated across halves
      #pragma unroll
      for (int m = 32; m > 0; m >>= 1) p += __shfl_xor(p, m);
      if (lane == 0) chiout[b * 10 + o] = p * 0.5f;
    }
  } else {
    int idx = bx - 512;
    int z = 36 + (idx >> 6);        // site 36..61
    int lr0 = (idx & 63) * 64;
    __shared__ __align__(16) unsigned char smem[18432];
    psi_gemm_tile(psi_mid + (size_t)z * 4096 * 256,
                  vpxf + (size_t)(z + 1) * 65536,
                  M + (size_t)z * 256 * 4096, lr0, t, smem);
  }
}

// ---------------------------------------------------------------------------
// K4: psi chain part 2 (sites 36..61, deep 64x2 register prefetch) + fused
// combine epilogue (out = chiout * psiv * phiv). 256 blocks x 64 threads.
__global__ __launch_bounds__(64) void k_chain_tail(const f16* __restrict__ M,
                                                   const float* __restrict__ vpx,
                                                   const float* __restrict__ psi_last,
                                                   const float* __restrict__ chiout,
                                                   const float* __restrict__ phiv,
                                                   const float* __restrict__ vpsi,
                                                   float* __restrict__ out) {
  int b = blockIdx.x;
  int lane = threadIdx.x;
  float v = vpsi[b * 64 + lane];
  #define MLOAD(buf, sc) do {                                                \
    const f16* Mb = M + ((size_t)(36 + (sc)) * 256 + b) * 4096 + lane;       \
    _Pragma("unroll")                                                        \
    for (int l = 0; l < 64; ++l) buf[l] = (float)Mb[(size_t)l * 64];         \
  } while (0)
  #define MSTEP(buf) do {                                                    \
    float s0 = 0.f, s1 = 0.f, s2 = 0.f, s3 = 0.f;                            \
    _Pragma("unroll")                                                        \
    for (int l = 0; l < 16; ++l) {                                           \
      s0 += __shfl(v, 4 * l + 0) * buf[4 * l + 0];                           \
      s1 += __shfl(v, 4 * l + 1) * buf[4 * l + 1];                           \
      s2 += __shfl(v, 4 * l + 2) * buf[4 * l + 2];                           \
      s3 += __shfl(v, 4 * l + 3) * buf[4 * l + 3];                           \
    }                                                                        \
    v = (s0 + s1) + (s2 + s3);                                               \
  } while (0)
  {
    float mvA[64], mvB[64];
    MLOAD(mvA, 0);
    #pragma unroll 1
    for (int sc = 0; sc < 26; sc += 2) {      // 26 even: pairs complete
      MLOAD(mvB, sc + 1);
      MSTEP(mvA);
      if (sc + 2 < 26) MLOAD(mvA, sc + 2);
      MSTEP(mvB);
    }
  }
  #undef MLOAD
  #undef MSTEP
  // psi_val = sum_p (sum_l v[l] psi_last[l][p]) * vpx[63][b][p]
  float acc_p = 0.f;
  #pragma unroll
  for (int pp = 0; pp < 4; ++pp) {
    int p = pp * 64 + lane;
    float pl[64];
    #pragma unroll
    for (int l = 0; l < 64; ++l) pl[l] = psi_last[l * 256 + p];
    float s0 = 0.f, s1 = 0.f, s2 = 0.f, s3 = 0.f;
    #pragma unroll
    for (int l = 0; l < 16; ++l) {
      s0 += __shfl(v, 4 * l + 0) * pl[4 * l + 0];
      s1 += __shfl(v, 4 * l + 1) * pl[4 * l + 1];
      s2 += __shfl(v, 4 * l + 2) * pl[4 * l + 2];
      s3 += __shfl(v, 4 * l + 3) * pl[4 * l + 3];
    }
    float wv = (s0 + s1) + (s2 + s3);
    acc_p += wv * vpx[((size_t)63 * 256 + b) * 256 + p];
  }
  #pragma unroll
  for (int m = 32; m > 0; m >>= 1) acc_p += __shfl_xor(acc_p, m);
  // fused combine: acc_p (psiv) is in all lanes
  if (lane < 10) out[b * 10 + lane] = chiout[b * 10 + lane] * acc_p * phiv[0];
}

// ---------------------------------------------------------------------------
// ===== Fallback tier (smaller workspace): chunked pipeline, f16 M =====
__global__ __launch_bounds__(512) void k_psi_gemm(const float* __restrict__ psi_mid,
                                                  const f16* __restrict__ vpxf,
                                                  f16* __restrict__ M, int s0) {
  int z = blockIdx.z;
  int s = s0 + z;
  int lr0 = blockIdx.x * 64;
  __shared__ __align__(16) unsigned char smem[18432];
  psi_gemm_tile(psi_mid + (size_t)s * 4096 * 256,
                vpxf + (size_t)(s + 1) * 65536,
                M + (size_t)z * 256 * 4096, lr0, threadIdx.x, smem);
}

__global__ __launch_bounds__(256) void k_psi_chain(const f16* __restrict__ M,
                                                   const float* __restrict__ vpx,
                                                   const float* __restrict__ psi_first,
                                                   const float* __restrict__ psi_last,
                                                   float* __restrict__ vpsi,
                                                   float* __restrict__ psiv,
                                                   int nS, int isFirst, int isLast) {
  int b = blockIdx.x;
  int t = threadIdx.x;
  int r = t & 63, g = t >> 6;
  __shared__ float v[64];
  __shared__ float part[4][64];
  __shared__ float red[256];
  if (isFirst) {
    const float* u0 = vpx + (size_t)b * 256;
    float s0 = 0.f;
    for (int p = g * 64; p < g * 64 + 64; ++p) s0 += psi_first[r * 256 + p] * u0[p];
    part[g][r] = s0;
    __syncthreads();
    if (g == 0) v[r] = part[0][r] + part[1][r] + part[2][r] + part[3][r];
    __syncthreads();
  } else {
    if (g == 0) v[r] = vpsi[b * 64 + r];
    __syncthreads();
  }
  for (int sc = 0; sc < nS; ++sc) {
    const f16* Mb = M + ((size_t)sc * 256 + b) * 4096;
    float sum = 0.f;
    #pragma unroll
    for (int j = 0; j < 16; ++j) {
      int l = g * 16 + j;
      sum += v[l] * (float)Mb[l * 64 + r];
    }
    part[g][r] = sum;
    __syncthreads();
    if (g == 0) v[r] = part[0][r] + part[1][r] + part[2][r] + part[3][r];
    __syncthreads();
  }
  if (isLast) {
    float qv = 0.f;
    for (int l = 0; l < 64; ++l) qv += v[l] * psi_last[l * 256 + t];
    red[t] = qv * vpx[((size_t)63 * 256 + b) * 256 + t];
    __syncthreads();
    for (int off = 128; off > 0; off >>= 1) {
      if (t < off) red[t] += red[t + off];
      __syncthreads();
    }
    if (t == 0) psiv[b] = red[0];
  } else {
    if (g == 0) vpsi[b * 64 + r] = v[r];
  }
}

__device__ __forceinline__ void phi_chain_body(const float* __restrict__ slices,
                                               const float* __restrict__ phi_first,
                                               const float* __restrict__ phi_last,
                                               float* __restrict__ phiv) {
  int t = threadIdx.x;
  int r = t & 63, g = t >> 6;
  __shared__ float u[64];
  __shared__ float part[4][64];
  __shared__ float red[64];
  if (t < 64) u[t] = phi_first[t * 64];
  __syncthreads();
  for (int i = 0; i < 62; ++i) {
    float sum = 0.f;
    #pragma unroll
    for (int j = 0; j < 16; ++j) {
      int l = g * 16 + j;
      sum += u[l] * slices[(size_t)i * 4096 + l * 64 + r];
    }
    part[g][r] = sum;
    __syncthreads();
    if (g == 0) u[r] = part[0][r] + part[1][r] + part[2][r] + part[3][r];
    __syncthreads();
  }
  if (t < 64) red[t] = u[t] * phi_last[t * 64 + 63];
  __syncthreads();
  if (t == 0) {
    float s = 0.f;
    for (int l = 0; l < 64; ++l) s += red[l];
    *phiv = s;
  }
}

__global__ __launch_bounds__(256) void k_phi_chain(const float* __restrict__ slices,
                                                   const float* __restrict__ phi_first,
                                                   const float* __restrict__ phi_last,
                                                   float* __restrict__ phiv) {
  phi_chain_body(slices, phi_first, phi_last, phiv);
}

__global__ __launch_bounds__(256) void k_chi_gemm(const float* __restrict__ chi_mid,
                                                  const float* __restrict__ vch,
                                                  float* __restrict__ Tc, int s0,
                                                  int phiBlock,
                                                  const float* __restrict__ slices,
                                                  const float* __restrict__ phi_first,
                                                  const float* __restrict__ phi_last,
                                                  float* __restrict__ phiv) {
  if ((int)blockIdx.x == phiBlock) {
    if (blockIdx.y == 0) phi_chain_body(slices, phi_first, phi_last, phiv);
    return;
  }
  int z = blockIdx.x;
  int s = s0 + z;
  int b0 = blockIdx.y * 32;
  int t = threadIdx.x;
  __shared__ float uv[32][16];
  if (t < 128) {
    int idx = t * 4;
    int b = idx >> 4, c = idx & 15;
    *(float4*)&uv[b][c] = *(const float4*)(vch + ((size_t)(s + 1) * 256 + b0 + b) * 16 + c);
  }
  __syncthreads();
  #pragma unroll
  for (int k = 0; k < 4; ++k) {
    int idx = t + k * 256;
    int r = idx >> 5, l = idx & 31;
    const float* Wp = chi_mid + ((size_t)s * 1024 + l * 32 + r) * 16;
    float4 w0 = *(const float4*)(Wp);
    float4 w1 = *(const float4*)(Wp + 4);
    float4 w2 = *(const float4*)(Wp + 8);
    float4 w3 = *(const float4*)(Wp + 12);
    for (int b = 0; b < 32; ++b) {
      const float* u = uv[b];
      float d = w0.x * u[0] + w0.y * u[1] + w0.z * u[2] + w0.w * u[3]
              + w1.x * u[4] + w1.y * u[5] + w1.z * u[6] + w1.w * u[7]
              + w2.x * u[8] + w2.y * u[9] + w2.z * u[10] + w2.w * u[11]
              + w3.x * u[12] + w3.y * u[13] + w3.z * u[14] + w3.w * u[15];
      Tc[((size_t)z * 256 + b0 + b) * 1024 + idx] = d;
    }
  }
}

__global__ __launch_bounds__(64) void k_chi_chain(const float* __restrict__ Tc,
                                                  const float* __restrict__ chi_first,
                                                  const float* __restrict__ chi_last,
                                                  const float* __restrict__ vch,
                                                  const float* __restrict__ psiv,
                                                  const float* __restrict__ phiv,
                                                  float* __restrict__ vchi,
                                                  float* __restrict__ out,
                                                  int nS, int isFirst, int isLast) {
  int b = blockIdx.x;
  int lane = threadIdx.x;
  int r = lane & 31, h = lane >> 5;
  __shared__ float v[32];
  if (isFirst) {
    if (h == 0) {
      const float* u0 = vch + (size_t)b * 16;
      const float* cf = chi_first + r * 16;
      float s0 = 0.f;
      #pragma unroll
      for (int c = 0; c < 16; ++c) s0 += cf[c] * u0[c];
      v[r] = s0;
    }
  } else {
    if (h == 0) v[r] = vchi[b * 32 + r];
  }
  __syncthreads();
  for (int sc = 0; sc < nS; ++sc) {
    const float* Mb = Tc + ((size_t)sc * 256 + b) * 1024 + r * 32 + h * 16;
    float4 m0 = *(const float4*)(Mb);
    float4 m1 = *(const float4*)(Mb + 4);
    float4 m2 = *(const float4*)(Mb + 8);
    float4 m3 = *(const float4*)(Mb + 12);
    const float* vv = &v[h * 16];
    float sum = m0.x * vv[0] + m0.y * vv[1] + m0.z * vv[2] + m0.w * vv[3]
              + m1.x * vv[4] + m1.y * vv[5] + m1.z * vv[6] + m1.w * vv[7]
              + m2.x * vv[8] + m2.y * vv[9] + m2.z * vv[10] + m2.w * vv[11]
              + m3.x * vv[12] + m3.y * vv[13] + m3.z * vv[14] + m3.w * vv[15];
    sum += __shfl_xor(sum, 32);
    __syncthreads();
    if (h == 0) v[r] = sum;
    __syncthreads();
  }
  if (isLast) {
    const float* u63 = vch + ((size_t)63 * 256 + b) * 16;
    float uc[16];
    #pragma unroll
    for (int c = 0; c < 16; ++c) uc[c] = u63[c];
    float scale = 0.5f * psiv[b] * phiv[0];
    for (int o = 0; o < 10; ++o) {
      const float* cl = chi_last + r * 16 * 10 + o;
      float w = 0.f;
      #pragma unroll
      for (int c = 0; c < 16; ++c) w += cl[c * 10] * uc[c];
      float p = v[r] * w;
      #pragma unroll
      for (int m = 32; m > 0; m >>= 1) p += __shfl_xor(p, m);
      if (lane == 0) out[b * 10 + o] = p * scale;
    }
  } else {
    if (h == 0) vchi[b * 32 + r] = v[r];
  }
}

__global__ __launch_bounds__(256) void k_chi_fused(const float* __restrict__ chi_first,
                                                   const float* __restrict__ chi_mid,
                                                   const float* __restrict__ chi_last,
                                                   const float* __restrict__ vch,
                                                   const float* __restrict__ psiv,
                                                   const float* __restrict__ phiv,
                                                   float* __restrict__ out) {
  int t = threadIdx.x;
  int bl = t >> 6, lg = (t >> 5) & 1, r = t & 31;
  int b = blockIdx.x * 4 + bl;
  __shared__ float v[4][32];
  __shared__ float part[4][2][32];
  if (lg == 0) {
    const float* u0 = vch + (size_t)b * 16;
    float s0 = 0.f;
    #pragma unroll
    for (int c = 0; c < 16; ++c) s0 += chi_first[r * 16 + c] * u0[c];
    v[bl][r] = s0;
  }
  __syncthreads();
  for (int s = 0; s < 62; ++s) {
    const float* u = vch + ((size_t)(s + 1) * 256 + b) * 16;
    float uc[16];
    #pragma unroll
    for (int c = 0; c < 16; ++c) uc[c] = u[c];
    const float* W = chi_mid + (size_t)s * 32 * 32 * 16;
    float sum = 0.f;
    #pragma unroll
    for (int j = 0; j < 16; ++j) {
      int l = lg * 16 + j;
      const float* Wl = W + ((size_t)l * 32 + r) * 16;
      float tt = 0.f;
      #pragma unroll
      for (int c = 0; c < 16; ++c) tt += Wl[c] * uc[c];
      sum += v[bl][l] * tt;
    }
    part[bl][lg][r] = sum;
    __syncthreads();
    if (lg == 0) v[bl][r] = part[bl][0][r] + part[bl][1][r];
    __syncthreads();
  }
  const float* u63 = vch + ((size_t)63 * 256 + b) * 16;
  float uc[16];
  #pragma unroll
  for (int c = 0; c < 16; ++c) uc[c] = u63[c];
  if (r < 10) {
    float acc = 0.f;
    #pragma unroll
    for (int j = 0; j < 16; ++j) {
      int l = lg * 16 + j;
      const float* cl = chi_last + (size_t)l * 16 * 10;
      float tt = 0.f;
      #pragma unroll
      for (int c = 0; c < 16; ++c) tt += cl[c * 10 + r] * uc[c];
      acc += v[bl][l] * tt;
    }
    part[bl][lg][r] = acc;
  }
  __syncthreads();
  if (lg == 0 && r < 10)
    out[b * 10 + r] = (part[bl][0][r] + part[bl][1][r]) * psiv[b] * phiv[0];
}

__global__ __launch_bounds__(256) void k_psi_direct(const float* __restrict__ x,
                                                    const float* __restrict__ psi_mid,
                                                    const float* __restrict__ psi_first,
                                                    const float* __restrict__ psi_last,
                                                    float* __restrict__ psiv) {
  int b = blockIdx.x;
  int t = threadIdx.x;
  int r = t & 63, g = t >> 6;
  __shared__ float u[256];
  __shared__ float v[64];
  __shared__ float part[4][64];
  __shared__ float red[256];
  const float* xb = x + ((size_t)b << 18);
  {
    const float* rw = xb + (size_t)0 * 4096 + t * 16;
    float sm = 0.f;
    #pragma unroll
    for (int c = 0; c < 16; ++c) sm += rw[c];
    u[t] = sm * (1.0f / 16.0f);
  }
  __syncthreads();
  {
    float s0 = 0.f;
    for (int p = g * 64; p < g * 64 + 64; ++p) s0 += psi_first[r * 256 + p] * u[p];
    part[g][r] = s0;
    __syncthreads();
    if (g == 0) v[r] = part[0][r] + part[1][r] + part[2][r] + part[3][r];
  }
  __syncthreads();
  for (int s = 0; s < 62; ++s) {
    __syncthreads();
    {
      const float* rw = xb + (size_t)(s + 1) * 4096 + t * 16;
      float sm = 0.f;
      #pragma unroll
      for (int c = 0; c < 16; ++c) sm += rw[c];
      u[t] = sm * (1.0f / 16.0f);
    }
    __syncthreads();
    const float* W = psi_mid + (size_t)s * 4096 * 256;
    float sum = 0.f;
    for (int l = 0; l < 64; ++l) {
      const float* Wl = W + ((size_t)(l * 64 + r)) * 256 + g * 64;
      float tt = 0.f;
      #pragma unroll 8
      for (int k = 0; k < 64; ++k) tt += Wl[k] * u[g * 64 + k];
      sum += v[l] * tt;
    }
    part[g][r] = sum;
    __syncthreads();
    if (g == 0) v[r] = part[0][r] + part[1][r] + part[2][r] + part[3][r];
    __syncthreads();
  }
  __syncthreads();
  {
    const float* rw = xb + (size_t)63 * 4096 + t * 16;
    float sm = 0.f;
    #pragma unroll
    for (int c = 0; c < 16; ++c) sm += rw[c];
    u[t] = sm * (1.0f / 16.0f);
  }
  __syncthreads();
  float qv = 0.f;
  for (int l = 0; l < 64; ++l) qv += v[l] * psi_last[l * 256 + t];
  red[t] = qv * u[t];
  __syncthreads();
  for (int off = 128; off > 0; off >>= 1) {
    if (t < off) red[t] += red[t + off];
    __syncthreads();
  }
  if (t == 0) psiv[b] = red[0];
}

// ---------------------------------------------------------------------------
extern "C" void kernel_launch(void* const* d_in, const int* in_sizes, int n_in,
                              void* d_out, int out_size, void* d_ws, size_t ws_size,
                              hipStream_t stream) {
  const float* x         = (const float*)d_in[0];
  const float* chi_first = (const float*)d_in[1];
  const float* chi_mid   = (const float*)d_in[2];
  const float* chi_last  = (const float*)d_in[3];
  const float* psi_first = (const float*)d_in[4];
  const float* psi_mid   = (const float*)d_in[5];
  const float* psi_last  = (const float*)d_in[6];
  const float* phi_first = (const float*)d_in[7];
  const float* phi_mid   = (const float*)d_in[8];
  const float* phi_last  = (const float*)d_in[9];
  float* out = (float*)d_out;
  float* ws  = (float*)d_ws;

  size_t wsf = ws_size / 4;
  size_t off = 0;
  float* vch    = ws + off; off += (size_t)64 * 256 * 16;     // 262144
  float* psiv   = ws + off; off += 256;
  float* chiout = ws + off; off += 2560;
  float* phisl  = ws + off; off += (size_t)62 * 64 * 64;      // 253952
  float* phiv   = ws + off; off += 16;
  float* vpsi   = ws + off; off += (size_t)64 * 256;          // 16384
  float* vchi   = ws + off; off += (size_t)32 * 256;          // 8192
  float* vpx    = ws + off; off += (size_t)64 * 256 * 256;    // 4194304
  f16* vpxf = (f16*)(ws + off); off += (size_t)64 * 65536 / 2;  // f16 frags
  f16* Mbuf = (f16*)(ws + off);                               // fp16 M
  size_t needMh  = (size_t)62 * 256 * 4096;                   // halves
  float* Tcbuf = (float*)(Mbuf + needMh);
  size_t needTc = (size_t)62 * 256 * 1024;                    // floats
  size_t bytes_needed = off * 4 + needMh * 2 + needTc * 4;

  if (ws_size >= bytes_needed) {
    // ===== Pipelined path: reduce -> [gemmA(0..35)+chiGemm+phi] ->
    //       [gemmB(36..61) || chains(0..35, chi full)] -> tail(36..61)
    k_reduce_x<<<16384 + 62, 256, 0, stream>>>(x, vch, vpx, vpxf,
                                               phi_mid, phisl);
    k_mega_A<<<497 + 2304, 512, 0, stream>>>(psi_mid, vpxf, Mbuf,
                                             chi_mid, vch, Tcbuf,
                                             phisl, phi_first, phi_last, phiv);
    k_mega_B<<<512 + 1664, 512, 0, stream>>>(psi_mid, vpxf, Mbuf,
                                             Tcbuf, vpx, vch, psi_first,
                                             chi_first, chi_last, vpsi, chiout);
    k_chain_tail<<<256, 64, 0, stream>>>(Mbuf, vpx, psi_last, chiout, phiv,
                                         vpsi, out);
  } else {
    size_t avail_b = (ws_size > off * 4) ? ws_size - off * 4 : 0;
    int C = (int)(avail_b / ((size_t)256 * 4096 * 2));        // fp16 M sites
    if (C > 62) C = 62;
    int Cc = (int)(avail_b / ((size_t)256 * 1024 * 4));       // fp32 Tc sites
    if (Cc > 62) Cc = 62;
    if (C >= 1) {
      k_reduce_x<<<16384 + 62, 256, 0, stream>>>(x, vch, vpx, vpxf,
                                                 phi_mid, phisl);
      int done = 0;
      while (done < 62) {
        int c = imin(C, 62 - done);
        k_psi_gemm<<<dim3(64, 1, c), 512, 0, stream>>>(psi_mid, vpxf, Mbuf, done);
        k_psi_chain<<<256, 256, 0, stream>>>(Mbuf, vpx, psi_first, psi_last,
                                             vpsi, psiv, c, (done == 0) ? 1 : 0,
                                             (done + c == 62) ? 1 : 0);
        done += c;
      }
      done = 0;
      while (done < 62) {
        int c = imin(Cc, 62 - done);
        int phiBlk = (done == 0) ? c : -1;
        int gx = (done == 0) ? (c + 1) : c;
        k_chi_gemm<<<dim3(gx, 8), 256, 0, stream>>>(chi_mid, vch, (float*)Mbuf, done, phiBlk,
                                                    phisl, phi_first, phi_last, phiv);
        k_chi_chain<<<256, 64, 0, stream>>>((float*)Mbuf, chi_first, chi_last, vch,
                                            psiv, phiv, vchi, out, c,
                                            (done == 0) ? 1 : 0,
                                            (done + c == 62) ? 1 : 0);
        done += c;
      }
    } else {
      k_reduce_x<<<16384 + 62, 256, 0, stream>>>(x, vch, nullptr, nullptr,
                                                 phi_mid, phisl);
      k_psi_direct<<<256, 256, 0, stream>>>(x, psi_mid, psi_first, psi_last, psiv);
      k_phi_chain<<<1, 256, 0, stream>>>(phisl, phi_first, phi_last, phiv);
      k_chi_fused<<<64, 256, 0, stream>>>(chi_first, chi_mid, chi_last, vch, psiv, phiv, out);
    }
  }
}